// Round 14
// baseline (398.876 us; speedup 1.0000x reference)
//
#include <hip/hip_runtime.h>
#include <hip/hip_bf16.h>

#define BB 8
#define CC 64
#define NPTS 32768
#define RR 32
#define RV 32768            // 32^3
#define MTOT (BB*RV)        // 262144
#define EPSV 1e-4f

// ws float offsets
#define OFF_BUFA 0u               // fsort bf16 [0:8.4M) -> y2b bf16; x2b bf16 [8.4M:16.7M)
#define OFF_BUFB 16777216u        // xb bf16 (x1 grid)
#define OFF_WB1  25165824u        // 55296 float-slots = 110592 bf16
#define OFF_WB2  25221120u        // 55296
#define OFF_ZG   25276416u        // 64 floats zero guard
#define OFF_BASE 25276480u        // 262144 uint
#define OFF_AUX  25800768u        // 256 uint
#define OFF_CELL 25801024u        // 262144 int
#define OFF_CNT  26063168u        // 262144 uint
#define OFF_MEAN 26325312u        // 24
#define OFF_PART1 26325504u       // 128 x 1024 (using 128 x 512)
#define OFF_PART2 26456576u       // 128 x 1024 (using 128 x 512)
#define OFF_SCL1 26587648u        // 64
#define OFF_SFT1 26587712u        // 64
#define OFF_SCL2 26587776u        // 64
#define OFF_SFT2 26587840u        // 64
#define OFF_WM   26587904u        // 2048 float-slots = 4096 bf16
#define OFF_PARTP 26590208u       // 128 x 4096 floats -> ends 27114496
#define OFF_SCLP 27114496u        // 64
#define OFF_SFTP 27114560u        // 64
#define OFF_NORM 33554432u        // 786432 (survives to k_final)

typedef __attribute__((ext_vector_type(8))) __bf16 bf16x8;
typedef __attribute__((ext_vector_type(8))) unsigned short u16x8;
typedef __attribute__((ext_vector_type(4))) float f32x4;

__device__ __forceinline__ float b2f(ushort u) {
    union { unsigned u; float f; } x; x.u = ((unsigned)u) << 16; return x.f;
}
__device__ __forceinline__ ushort f2b(float f) {
    __hip_bfloat16 h = __float2bfloat16(f);
    return *reinterpret_cast<ushort*>(&h);
}

// 192 blocks: (b*3+axis)*8 + chunk; partial sums via f32 atomics into mean[24]
__global__ void k_coord_mean(const float* __restrict__ coords, float* __restrict__ mean) {
    int ba = blockIdx.x >> 3, ch = blockIdx.x & 7;
    const float* src = coords + (size_t)ba * NPTS + ch * 4096;
    float s = 0.f;
    for (int i = threadIdx.x; i < 4096; i += 256) s += src[i];
    __shared__ float red[256];
    red[threadIdx.x] = s; __syncthreads();
    for (int w = 128; w > 0; w >>= 1) {
        if (threadIdx.x < w) red[threadIdx.x] += red[threadIdx.x + w];
        __syncthreads();
    }
    if (threadIdx.x == 0) atomicAdd(&mean[ba], red[0]);
}

// per point: norm, cell id, count (mean arrives as raw sums; scale by 1/NPTS here)
__global__ void k_cellid(const float* __restrict__ coords, const float* __restrict__ mean,
                         float* __restrict__ norm, int* __restrict__ cellid,
                         unsigned* __restrict__ cnt) {
    int idx = blockIdx.x * 256 + threadIdx.x;      // b*NPTS + n
    int b = idx >> 15, n = idx & (NPTS - 1);
    int flat = 0;
    #pragma unroll
    for (int a = 0; a < 3; ++a) {
        float c = coords[((size_t)(b * 3 + a)) * NPTS + n];
        float nm = (c - mean[b * 3 + a] * (1.0f / NPTS) + 1.0f) * (0.5f * RR);
        nm = fminf(fmaxf(nm, 0.0f), (float)(RR - 1));
        norm[((size_t)(b * 3 + a)) * NPTS + n] = nm;
        flat = flat * RR + (int)rintf(nm);
    }
    int cell = b * RV + flat;
    cellid[idx] = cell;
    atomicAdd(&cnt[cell], 1u);
}

// block-local exclusive scan: 256 blocks x 1024 cells
__global__ void k_scan1(const unsigned* __restrict__ cnt, unsigned* __restrict__ base,
                        unsigned* __restrict__ aux) {
    int tid = threadIdx.x;
    int c0 = blockIdx.x * 1024 + tid * 4;
    unsigned v0 = cnt[c0], v1 = cnt[c0 + 1], v2 = cnt[c0 + 2], v3 = cnt[c0 + 3];
    unsigned tot = v0 + v1 + v2 + v3;
    __shared__ unsigned sc[256];
    sc[tid] = tot; __syncthreads();
    for (int off = 1; off < 256; off <<= 1) {
        unsigned t = (tid >= off) ? sc[tid - off] : 0u;
        __syncthreads();
        sc[tid] += t;
        __syncthreads();
    }
    unsigned excl = sc[tid] - tot;
    base[c0] = excl;
    base[c0 + 1] = excl + v0;
    base[c0 + 2] = excl + v0 + v1;
    base[c0 + 3] = excl + v0 + v1 + v2;
    if (tid == 255) aux[blockIdx.x] = sc[255];
}

__global__ void k_scan2(unsigned* __restrict__ aux) {
    int tid = threadIdx.x;
    unsigned own = aux[tid];
    __shared__ unsigned sc[256];
    sc[tid] = own; __syncthreads();
    for (int off = 1; off < 256; off <<= 1) {
        unsigned t = (tid >= off) ? sc[tid - off] : 0u;
        __syncthreads();
        sc[tid] += t;
        __syncthreads();
    }
    aux[tid] = sc[tid] - own;
}

__global__ void k_scan3(unsigned* __restrict__ base, const unsigned* __restrict__ aux) {
    int i = blockIdx.x * 256 + threadIdx.x;
    base[i] += aux[i >> 10];
}

// fused transpose + feature-sort + point-MLP (MFMA) + BN-p moment partials.
__global__ __launch_bounds__(256) void k_scatfeat(
    const float* __restrict__ feats, const int* __restrict__ cellid,
    unsigned* __restrict__ base, ushort* __restrict__ fsort,
    const ushort* __restrict__ wmb, const float* __restrict__ mbias,
    ushort* __restrict__ pb, float* __restrict__ partp) {
    __shared__ float t[64 * 65];
    __shared__ unsigned spos[64];
    __shared__ float sf[512];
    int b = blockIdx.x >> 9;
    int n0 = (blockIdx.x & 511) * 64;
    int tid = threadIdx.x;
    #pragma unroll
    for (int k = 0; k < 16; ++k) {
        int idx = k * 256 + tid;
        int c = idx >> 6, nl = idx & 63;
        t[c * 65 + nl] = feats[((size_t)(b * 64 + c)) * NPTS + n0 + nl];
    }
    if (tid < 64) {
        int cell = cellid[(b << 15) + n0 + tid];
        spos[tid] = atomicAdd(&base[cell], 1u);
    }
    __syncthreads();
    // scatter sorted bf16 rows
    #pragma unroll
    for (int it = 0; it < 2; ++it) {
        int pl = it * 32 + (tid >> 3);
        int j = tid & 7;
        unsigned pos = spos[pl];
        u16x8 v;
        #pragma unroll
        for (int k = 0; k < 8; ++k) v[k] = f2b(t[(j * 8 + k) * 65 + pl]);
        *reinterpret_cast<u16x8*>(fsort + (((size_t)pos) << 6) + j * 8) = v;
    }
    // MLP: wave w handles points w*16..w*16+15
    int w = tid >> 6, l = tid & 63;
    int nl = l & 15, kg = l >> 4;
    bf16x8 Af[2];
    #pragma unroll
    for (int ks = 0; ks < 2; ++ks) {
        union { u16x8 u; bf16x8 h; } cv;
        #pragma unroll
        for (int j = 0; j < 8; ++j)
            cv.u[j] = f2b(t[(ks * 32 + kg * 8 + j) * 65 + w * 16 + nl]);
        Af[ks] = cv.h;
    }
    f32x4 acc[4];
    #pragma unroll
    for (int cb = 0; cb < 4; ++cb) acc[cb] = (f32x4){0.f, 0.f, 0.f, 0.f};
    #pragma unroll
    for (int ks = 0; ks < 2; ++ks)
        #pragma unroll
        for (int cb = 0; cb < 4; ++cb) {
            bf16x8 Bf = *reinterpret_cast<const bf16x8*>(wmb + (cb * 16 + nl) * 64 + ks * 32 + kg * 8);
            acc[cb] = __builtin_amdgcn_mfma_f32_16x16x32_bf16(Af[ks], Bf, acc[cb], 0, 0, 0);
        }
    float ss[4] = {0.f, 0.f, 0.f, 0.f}, qq[4] = {0.f, 0.f, 0.f, 0.f};
    #pragma unroll
    for (int cb = 0; cb < 4; ++cb) {
        float bsv = mbias[cb * 16 + nl];
        #pragma unroll
        for (int r = 0; r < 4; ++r) {
            float yv = acc[cb][r] + bsv;
            int pt = w * 16 + kg * 4 + r;
            pb[(((size_t)((b << 15) + n0 + pt)) << 6) + cb * 16 + nl] = f2b(yv);
            ss[cb] += yv; qq[cb] += yv * yv;
        }
    }
    #pragma unroll
    for (int cb = 0; cb < 4; ++cb) {
        ss[cb] += __shfl_xor(ss[cb], 16); ss[cb] += __shfl_xor(ss[cb], 32);
        qq[cb] += __shfl_xor(qq[cb], 16); qq[cb] += __shfl_xor(qq[cb], 32);
    }
    if (l < 16) {
        #pragma unroll
        for (int cb = 0; cb < 4; ++cb) {
            sf[w * 128 + cb * 16 + nl] = ss[cb];
            sf[w * 128 + 64 + cb * 16 + nl] = qq[cb];
        }
    }
    __syncthreads();
    if (tid < 128)
        partp[(size_t)tid * 4096 + blockIdx.x] =
            sf[tid] + sf[128 + tid] + sf[256 + tid] + sf[384 + tid];
}

// one wave per cell: rows contiguous [start, start+n), unroll x8
__global__ __launch_bounds__(256) void k_gather(
    const ushort* __restrict__ fsort, const unsigned* __restrict__ base,
    const unsigned* __restrict__ cnt, __hip_bfloat16* __restrict__ xb) {
    int cell = blockIdx.x * 4 + (threadIdx.x >> 6);
    int lane = threadIdx.x & 63;
    unsigned n = cnt[cell];
    unsigned start = base[cell] - n;
    const ushort* rows = fsort + (((size_t)start) << 6) + lane;
    float acc = 0.f;
    unsigned i = 0;
    for (; i + 8 <= n; i += 8) {
        float f0 = b2f(rows[((size_t)(i + 0)) << 6]);
        float f1 = b2f(rows[((size_t)(i + 1)) << 6]);
        float f2 = b2f(rows[((size_t)(i + 2)) << 6]);
        float f3 = b2f(rows[((size_t)(i + 3)) << 6]);
        float f4 = b2f(rows[((size_t)(i + 4)) << 6]);
        float f5 = b2f(rows[((size_t)(i + 5)) << 6]);
        float f6 = b2f(rows[((size_t)(i + 6)) << 6]);
        float f7 = b2f(rows[((size_t)(i + 7)) << 6]);
        acc += ((f0 + f1) + (f2 + f3)) + ((f4 + f5) + (f6 + f7));
    }
    for (; i < n; ++i) acc += b2f(rows[((size_t)i) << 6]);
    float inv = (n > 0) ? (1.0f / (float)n) : 0.f;
    xb[((size_t)cell << 6) + lane] = __float2bfloat16(acc * inv);
}

// conv_w (co,ci,kd,kh,kw) -> wb[tap][co][ci] bf16
__global__ void k_wb(const float* __restrict__ w, __hip_bfloat16* __restrict__ wb) {
    int i = blockIdx.x * 256 + threadIdx.x;              // CC*CC*27
    if (i >= CC * CC * 27) return;
    int tap = i % 27, t = i / 27;
    int ci = t & 63, co = t >> 6;
    wb[((size_t)(tap * 64 + co)) * 64 + ci] = __float2bfloat16(w[i]);
}

// mlp_w (co,ci) f32 -> bf16
__global__ void k_wm(const float* __restrict__ w, ushort* __restrict__ wmb) {
    int i = blockIdx.x * 256 + threadIdx.x;
    if (i < 4096) wmb[i] = f2b(w[i]);
}

// x2 = bf16(leaky(y1*scl+sft)), vectorized x8
__global__ void k_act(const ushort* __restrict__ in, const float* __restrict__ scl,
                      const float* __restrict__ sft, ushort* __restrict__ out) {
    size_t i = ((size_t)blockIdx.x * 256 + threadIdx.x) << 3;
    u16x8 v = *reinterpret_cast<const u16x8*>(in + i);
    int c0 = (int)(i & 63);
    u16x8 o;
    #pragma unroll
    for (int j = 0; j < 8; ++j) {
        float f = fmaf(b2f(v[j]), scl[c0 + j], sft[c0 + j]);
        f = f > 0.f ? f : 0.1f * f;
        o[j] = f2b(f);
    }
    *reinterpret_cast<u16x8*>(out + i) = o;
}

// implicit-GEMM conv, both operands in LDS, deep register tile.
// block: 8x8x8 output tile (512 voxels) x 64 co, 4 waves; wave = 2 d-slices (mi=8).
// halo 10x10x10 (125KB) DMA'd once; weights 1-tap double-buffered 2x8KB.
// 0.375 KB LDS-read per MFMA; per-tap addr VALU amortized over 64 MFMA.
__global__ __launch_bounds__(256, 1) void k_conv_mfma(
    const ushort* __restrict__ src, const ushort* __restrict__ wb,
    const float* __restrict__ bias, ushort* __restrict__ y,
    float* __restrict__ part, const ushort* __restrict__ zg) {
    __shared__ __align__(16) char sh[128000 + 16384];    // halo 1000 rows + 2x8KB wgt = 144384 B
    char* wsh = sh + 128000;
    int tid = threadIdx.x;
    int lane = tid & 63, wid = tid >> 6;
    int tile = ((blockIdx.x & 7) << 6) | (blockIdx.x >> 3);  // XCD-swizzled, 512 blocks
    int twi = tile & 3, thi = (tile >> 2) & 3;
    int tdi = (tile >> 4) & 3, b = tile >> 6;
    int d0 = tdi * 8, h0 = thi * 8, w0 = twi * 8;

    auto stage_wgt = [&](int t) {
        const ushort* wgrp = wb + t * 4096;              // one tap: 64 co x 64 ci
        char* wdst0 = wsh + (t & 1) * 8192;
        #pragma unroll
        for (int i = 0; i < 2; ++i) {
            int idx = i * 4 + wid;
            int c = idx * 64 + lane;
            int row = c >> 3, off = c & 7;
            const ushort* gsrc = wgrp + (((row << 3) + (off ^ (row & 7))) << 3);
            char* ldst = wdst0 + (idx << 10);
            __builtin_amdgcn_global_load_lds(
                (const __attribute__((address_space(1))) void*)gsrc,
                (__attribute__((address_space(3))) void*)ldst, 16, 0, 0);
        }
    };

    // halo DMA: 1000 rows x 8 chunks of 16B = 8000 chunks
    #pragma unroll
    for (int it = 0; it < 32; ++it) {
        int idx = it * 4 + wid;
        if (idx < 125) {
            int c = idx * 64 + lane;
            int row = c >> 3, off = c & 7;
            int dz = row / 100, rem = row - dz * 100;
            int hz = rem / 10, wz = rem - hz * 10;
            int gd = d0 - 1 + dz, gh = h0 - 1 + hz, gw = w0 - 1 + wz;
            int srcoff = off ^ (row & 7);
            const ushort* gsrc = ((unsigned)gd < 32u && (unsigned)gh < 32u && (unsigned)gw < 32u)
                ? src + ((((size_t)((b << 15) | (gd << 10) | (gh << 5) | gw)) << 6) + srcoff * 8)
                : zg;
            char* ldst = sh + (idx << 10);
            __builtin_amdgcn_global_load_lds(
                (const __attribute__((address_space(1))) void*)gsrc,
                (__attribute__((address_space(3))) void*)ldst, 16, 0, 0);
        }
    }
    stage_wgt(0);

    int nl = lane & 15, kg = lane >> 4;
    int rbase = (wid * 2) * 100 + (nl >> 3) * 10 + (nl & 7);
    int bbase[4];
    #pragma unroll
    for (int cb = 0; cb < 4; ++cb)
        bbase[cb] = (((cb * 16 + nl) << 7) + (kg << 4)) ^ ((nl & 7) << 4);

    f32x4 acc[8][4];
    #pragma unroll
    for (int mi = 0; mi < 8; ++mi)
        #pragma unroll
        for (int cb = 0; cb < 4; ++cb) acc[mi][cb] = (f32x4){0.f, 0.f, 0.f, 0.f};

    __syncthreads();                                     // halo + wgt0 ready

    #pragma unroll 1
    for (int t = 0; t < 27; ++t) {
        if (t < 26) stage_wgt(t + 1);
        const char* wlds = wsh + (t & 1) * 8192;
        int kd = t / 9, rm = t - kd * 9;
        int kh = rm / 3, kw = rm - kh * 3;
        int rt = rbase + kd * 100 + kh * 10 + kw;
        #pragma unroll
        for (int ks = 0; ks < 2; ++ks) {
            bf16x8 a[8];
            #pragma unroll
            for (int mi = 0; mi < 8; ++mi) {
                int r = rt + (mi >> 2) * 100 + (mi & 3) * 20;
                int ba = ((((r << 7) + (kg << 4)) ^ ((r & 7) << 4))) ^ (ks << 6);
                a[mi] = *reinterpret_cast<const bf16x8*>(sh + ba);
            }
            bf16x8 bf[4];
            #pragma unroll
            for (int cb = 0; cb < 4; ++cb)
                bf[cb] = *reinterpret_cast<const bf16x8*>(wlds + (bbase[cb] ^ (ks << 6)));
            #pragma unroll
            for (int mi = 0; mi < 8; ++mi)
                #pragma unroll
                for (int cb = 0; cb < 4; ++cb)
                    acc[mi][cb] = __builtin_amdgcn_mfma_f32_16x16x32_bf16(
                        a[mi], bf[cb], acc[mi][cb], 0, 0, 0);
        }
        __syncthreads();                                 // drains wgt DMA t+1; buffer flip
    }

    float bs[4];
    #pragma unroll
    for (int cb = 0; cb < 4; ++cb) bs[cb] = bias[cb * 16 + nl];
    float ss[4] = {0.f, 0.f, 0.f, 0.f}, qq[4] = {0.f, 0.f, 0.f, 0.f};
    #pragma unroll
    for (int mi = 0; mi < 8; ++mi) {
        int d = d0 + wid * 2 + (mi >> 2);
        int h = h0 + (mi & 3) * 2 + (kg >> 1);
        int w = w0 + (kg & 1) * 4;
        size_t vox = (size_t)((b << 15) | (d << 10) | (h << 5) | w);
        #pragma unroll
        for (int cb = 0; cb < 4; ++cb) {
            int co = cb * 16 + nl;
            #pragma unroll
            for (int r = 0; r < 4; ++r) {
                float yv = acc[mi][cb][r] + bs[cb];
                y[((vox + r) << 6) + co] = f2b(yv);
                ss[cb] += yv; qq[cb] += yv * yv;
            }
        }
    }
    #pragma unroll
    for (int cb = 0; cb < 4; ++cb) {
        ss[cb] += __shfl_xor(ss[cb], 16); ss[cb] += __shfl_xor(ss[cb], 32);
        qq[cb] += __shfl_xor(qq[cb], 16); qq[cb] += __shfl_xor(qq[cb], 32);
    }
    float* sf = (float*)sh;                              // halo dead; reuse
    __syncthreads();
    if (lane < 16) {
        #pragma unroll
        for (int cb = 0; cb < 4; ++cb) {
            sf[wid * 128 + cb * 16 + nl] = ss[cb];
            sf[wid * 128 + 64 + cb * 16 + nl] = qq[cb];
        }
    }
    __syncthreads();
    if (tid < 128) {
        float t = sf[tid] + sf[128 + tid] + sf[256 + tid] + sf[384 + tid];
        part[tid * 512 + blockIdx.x] = t;
    }
}

// reduce partials -> BN affine (scl, sft). 64 blocks, block = one channel.
__global__ void k_redbn(const float* __restrict__ part, const float* __restrict__ g,
                        const float* __restrict__ bb, float* __restrict__ scl,
                        float* __restrict__ sft, int cnt) {
    int c = blockIdx.x;
    float s = 0.f, q = 0.f;
    for (int i = threadIdx.x; i < cnt; i += 256) {
        s += part[(size_t)c * cnt + i];
        q += part[(size_t)(64 + c) * cnt + i];
    }
    __shared__ float rs[256], rq[256];
    rs[threadIdx.x] = s; rq[threadIdx.x] = q; __syncthreads();
    for (int w = 128; w > 0; w >>= 1) {
        if (threadIdx.x < w) { rs[threadIdx.x] += rs[threadIdx.x + w]; rq[threadIdx.x] += rq[threadIdx.x + w]; }
        __syncthreads();
    }
    if (threadIdx.x == 0) {
        float mu = rs[0] * (1.0f / MTOT);
        float var = rq[0] * (1.0f / MTOT) - mu * mu;
        float sc = g[c] * rsqrtf(var + EPSV);
        scl[c] = sc; sft[c] = bb[c] - mu * sc;
    }
}

// y2 bf16 NDHWC -> v f32 NCDHW with BN2 affine + leaky fused
__global__ void k_transpose(const ushort* __restrict__ in, const float* __restrict__ scl,
                            const float* __restrict__ sft, float* __restrict__ out) {
    __shared__ float t[64 * 65];
    size_t base = (size_t)blockIdx.x * 4096;
    int gv0 = blockIdx.x * 64;
    int b = gv0 >> 15;
    int vox0 = gv0 & 32767;
    int chl = threadIdx.x & 63;
    float sc = scl[chl], sf = sft[chl];
    #pragma unroll
    for (int k = 0; k < 16; ++k) {
        int idx = k * 256 + threadIdx.x;
        float v = fmaf(b2f(in[base + idx]), sc, sf);
        t[(idx >> 6) * 65 + (idx & 63)] = v > 0.f ? v : 0.1f * v;
    }
    __syncthreads();
    #pragma unroll
    for (int k = 0; k < 16; ++k) {
        int idx = k * 256 + threadIdx.x;
        int ch = idx >> 6, voxl = idx & 63;
        out[((size_t)(b * 64 + ch)) * RV + vox0 + voxl] = t[voxl * 65 + ch];
    }
}

// fused: phase1 per point = trilinear(y2 bf16 w/ BN2+leaky) + leaky(BNp(pb)); phase2 coalesced write.
__global__ __launch_bounds__(256) void k_final(
    float* __restrict__ out, const ushort* __restrict__ pbuf,
    const ushort* __restrict__ vraw, const float* __restrict__ norm,
    const float* __restrict__ scl, const float* __restrict__ sft,
    const float* __restrict__ sclp, const float* __restrict__ sftp) {
    __shared__ float smp[64 * 65];
    int b = blockIdx.x >> 9;                 // 512 tiles per batch
    int n0 = (blockIdx.x & 511) * 64;
    int wid = threadIdx.x >> 6, lane = threadIdx.x & 63;
    const ushort* gb = vraw + (((size_t)b) << 15) * CC;
    const float* nrm0 = norm + ((size_t)(b * 3)) * NPTS;
    float sc = scl[lane], sf = sft[lane];
    float scp = sclp[lane], sfp = sftp[lane];

    #pragma unroll 2
    for (int i = 0; i < 16; ++i) {
        int pl = wid * 16 + i;
        int n = n0 + pl;
        float v0 = nrm0[n];
        float v1 = nrm0[NPTS + n];
        float v2 = nrm0[2 * NPTS + n];
        int lx = (int)floorf(v0), ly = (int)floorf(v1), lz = (int)floorf(v2);
        float fx = v0 - (float)lx, fy = v1 - (float)ly, fz = v2 - (float)lz;
        int hx = min(lx + 1, 31), hy = min(ly + 1, 31), hz = min(lz + 1, 31);
        float gx = 1.f - fx, gy = 1.f - fy, gz = 1.f - fz;

        int i000 = ((lx * 32 + ly) * 32 + lz) << 6;
        int i001 = ((lx * 32 + ly) * 32 + hz) << 6;
        int i010 = ((lx * 32 + hy) * 32 + lz) << 6;
        int i011 = ((lx * 32 + hy) * 32 + hz) << 6;
        int i100 = ((hx * 32 + ly) * 32 + lz) << 6;
        int i101 = ((hx * 32 + ly) * 32 + hz) << 6;
        int i110 = ((hx * 32 + hy) * 32 + lz) << 6;
        int i111 = ((hx * 32 + hy) * 32 + hz) << 6;

        float w000 = gx * gy * gz, w001 = gx * gy * fz;
        float w010 = gx * fy * gz, w011 = gx * fy * fz;
        float w100 = fx * gy * gz, w101 = fx * gy * fz;
        float w110 = fx * fy * gz, w111 = fx * fy * fz;

        float r0 = fmaf(b2f(gb[i000 + lane]), sc, sf); r0 = r0 > 0.f ? r0 : 0.1f * r0;
        float r1 = fmaf(b2f(gb[i001 + lane]), sc, sf); r1 = r1 > 0.f ? r1 : 0.1f * r1;
        float r2 = fmaf(b2f(gb[i010 + lane]), sc, sf); r2 = r2 > 0.f ? r2 : 0.1f * r2;
        float r3 = fmaf(b2f(gb[i011 + lane]), sc, sf); r3 = r3 > 0.f ? r3 : 0.1f * r3;
        float r4 = fmaf(b2f(gb[i100 + lane]), sc, sf); r4 = r4 > 0.f ? r4 : 0.1f * r4;
        float r5 = fmaf(b2f(gb[i101 + lane]), sc, sf); r5 = r5 > 0.f ? r5 : 0.1f * r5;
        float r6 = fmaf(b2f(gb[i110 + lane]), sc, sf); r6 = r6 > 0.f ? r6 : 0.1f * r6;
        float r7 = fmaf(b2f(gb[i111 + lane]), sc, sf); r7 = r7 > 0.f ? r7 : 0.1f * r7;

        float s = r0 * w000 + r1 * w001 + r2 * w010 + r3 * w011
                + r4 * w100 + r5 * w101 + r6 * w110 + r7 * w111;

        float pv = fmaf(b2f(pbuf[(((size_t)((b << 15) + n)) << 6) + lane]), scp, sfp);
        pv = pv > 0.f ? pv : 0.1f * pv;
        smp[pl * 65 + lane] = s + pv;
    }
    __syncthreads();

    #pragma unroll 4
    for (int i = 0; i < 16; ++i) {
        int co = i * 4 + wid;
        out[((size_t)(b * 64 + co)) * NPTS + n0 + lane] = smp[lane * 65 + co];
    }
}

extern "C" void kernel_launch(void* const* d_in, const int* in_sizes, int n_in,
                              void* d_out, int out_size, void* d_ws, size_t ws_size,
                              hipStream_t stream) {
    const float* features = (const float*)d_in[0];
    const float* coords   = (const float*)d_in[1];
    const float* conv1_w  = (const float*)d_in[2];
    const float* conv1_b  = (const float*)d_in[3];
    const float* bn1_g    = (const float*)d_in[4];
    const float* bn1_b    = (const float*)d_in[5];
    const float* conv2_w  = (const float*)d_in[6];
    const float* conv2_b  = (const float*)d_in[7];
    const float* bn2_g    = (const float*)d_in[8];
    const float* bn2_b    = (const float*)d_in[9];
    const float* mlp_w    = (const float*)d_in[10];
    const float* mlp_b    = (const float*)d_in[11];
    const float* bnp_g    = (const float*)d_in[12];
    const float* bnp_b    = (const float*)d_in[13];

    float* ws    = (float*)d_ws;
    ushort* fsort  = (ushort*)(ws + OFF_BUFA);           // dead after k_gather
    ushort* y2b    = (ushort*)(ws + OFF_BUFA);           // conv2 out (reuses fsort region)
    ushort* x2b    = (ushort*)(ws + OFF_BUFA) + (size_t)16777216;  // x2 bf16
    __hip_bfloat16* xb  = (__hip_bfloat16*)(ws + OFF_BUFB);
    __hip_bfloat16* wb1 = (__hip_bfloat16*)(ws + OFF_WB1);
    __hip_bfloat16* wb2 = (__hip_bfloat16*)(ws + OFF_WB2);
    ushort* zg   = (ushort*)(ws + OFF_ZG);
    unsigned* base    = (unsigned*)(ws + OFF_BASE);
    unsigned* aux     = (unsigned*)(ws + OFF_AUX);
    int* cellid       = (int*)(ws + OFF_CELL);
    unsigned* cnt     = (unsigned*)(ws + OFF_CNT);
    float* mean  = ws + OFF_MEAN;
    float* part1 = ws + OFF_PART1;
    float* part2 = ws + OFF_PART2;
    float* scl1  = ws + OFF_SCL1;
    float* sft1  = ws + OFF_SFT1;
    float* scl2  = ws + OFF_SCL2;
    float* sft2  = ws + OFF_SFT2;
    ushort* wmb  = (ushort*)(ws + OFF_WM);
    float* partp = ws + OFF_PARTP;
    float* sclp  = ws + OFF_SCLP;
    float* sftp  = ws + OFF_SFTP;
    float* nrm   = ws + OFF_NORM;

    float* outF  = (float*)d_out;                       // fused output
    float* outV  = (float*)d_out + (size_t)16777216;    // v output region
    ushort* y1b  = (ushort*)outV;                       // y1 bf16 scratch: outV float-slots [0 .. 8.4M)
    ushort* pbuf = (ushort*)(outV + (size_t)8388608);   // pb bf16: outV float-slots [8.4M .. 16.7M)

    hipMemsetAsync(cnt, 0, 262144 * 4, stream);
    hipMemsetAsync(zg, 0, 256, stream);
    hipMemsetAsync(mean, 0, 24 * 4, stream);

    k_coord_mean<<<192, 256, 0, stream>>>(coords, mean);
    k_cellid<<<1024, 256, 0, stream>>>(coords, mean, nrm, cellid, cnt);
    k_scan1<<<256, 256, 0, stream>>>(cnt, base, aux);
    k_scan2<<<1, 256, 0, stream>>>(aux);
    k_scan3<<<1024, 256, 0, stream>>>(base, aux);

    k_wb<<<432, 256, 0, stream>>>(conv1_w, wb1);
    k_wb<<<432, 256, 0, stream>>>(conv2_w, wb2);
    k_wm<<<16, 256, 0, stream>>>(mlp_w, wmb);

    // fused: sort features + point-MLP (pb -> d_out scratch) + BN-p partials
    k_scatfeat<<<4096, 256, 0, stream>>>(features, cellid, base, fsort,
                                         wmb, mlp_b, pbuf, partp);
    k_redbn<<<64, 256, 0, stream>>>(partp, bnp_g, bnp_b, sclp, sftp, 4096);
    k_gather<<<65536, 256, 0, stream>>>(fsort, base, cnt, xb);

    // conv1: xb -> y1b + partials
    k_conv_mfma<<<512, 256, 0, stream>>>((const ushort*)xb, (const ushort*)wb1, conv1_b,
                                         y1b, part1, zg);
    k_redbn<<<64, 256, 0, stream>>>(part1, bn1_g, bn1_b, scl1, sft1, 512);

    // x2 = leaky(bn1(y1)) bf16
    k_act<<<8192, 256, 0, stream>>>(y1b, scl1, sft1, x2b);

    // conv2: x2b -> y2b + partials
    k_conv_mfma<<<512, 256, 0, stream>>>(x2b, (const ushort*)wb2, conv2_b,
                                         y2b, part2, zg);
    k_redbn<<<64, 256, 0, stream>>>(part2, bn2_g, bn2_b, scl2, sft2, 512);

    // fuse -> outF (reads pbuf from outV scratch; must run BEFORE k_transpose)
    k_final<<<4096, 256, 0, stream>>>(outF, pbuf, y2b, nrm, scl2, sft2, sclp, sftp);

    // v = leaky(bn2(y2)) -> d_out NCDHW f32 (overwrites y1b + pbuf scratch)
    k_transpose<<<4096, 256, 0, stream>>>(y2b, scl2, sft2, outV);
}

// Round 15
// 378.089 us; speedup vs baseline: 1.0550x; 1.0550x over previous
//
#include <hip/hip_runtime.h>
#include <hip/hip_bf16.h>

#define BB 8
#define CC 64
#define NPTS 32768
#define RR 32
#define RV 32768            // 32^3
#define MTOT (BB*RV)        // 262144
#define EPSV 1e-4f

// ws float offsets
#define OFF_BUFA 0u               // fsort bf16 [0:8.4M) -> y2b bf16; x2b bf16 [8.4M:16.7M)
#define OFF_BUFB 16777216u        // xb bf16 (x1 grid)
#define OFF_WB1  25165824u        // 55296 float-slots = 110592 bf16
#define OFF_WB2  25221120u        // 55296
#define OFF_ZG   25276416u        // 64 floats zero guard
#define OFF_BASE 25276480u        // 262144 uint
#define OFF_AUX  25800768u        // 256 uint
#define OFF_CELL 25801024u        // 262144 int
#define OFF_CNT  26063168u        // 262144 uint
#define OFF_MEAN 26325312u        // 24
#define OFF_PART1 26325504u       // 128 x 1024 (using 128 x 512)
#define OFF_PART2 26456576u       // 128 x 1024 (using 128 x 512)
#define OFF_SCL1 26587648u        // 64
#define OFF_SFT1 26587712u        // 64
#define OFF_SCL2 26587776u        // 64
#define OFF_SFT2 26587840u        // 64
#define OFF_WM   26587904u        // 2048 float-slots = 4096 bf16
#define OFF_PARTP 26590208u       // 128 x 4096 floats -> ends 27114496
#define OFF_SCLP 27114496u        // 64
#define OFF_SFTP 27114560u        // 64
#define OFF_NORM 33554432u        // 786432 (survives to k_final)

typedef __attribute__((ext_vector_type(8))) __bf16 bf16x8;
typedef __attribute__((ext_vector_type(8))) unsigned short u16x8;
typedef __attribute__((ext_vector_type(4))) float f32x4;

__device__ __forceinline__ float b2f(ushort u) {
    union { unsigned u; float f; } x; x.u = ((unsigned)u) << 16; return x.f;
}
__device__ __forceinline__ ushort f2b(float f) {
    __hip_bfloat16 h = __float2bfloat16(f);
    return *reinterpret_cast<ushort*>(&h);
}

// 192 blocks: (b*3+axis)*8 + chunk; partial sums via f32 atomics into mean[24]
__global__ void k_coord_mean(const float* __restrict__ coords, float* __restrict__ mean) {
    int ba = blockIdx.x >> 3, ch = blockIdx.x & 7;
    const float* src = coords + (size_t)ba * NPTS + ch * 4096;
    float s = 0.f;
    for (int i = threadIdx.x; i < 4096; i += 256) s += src[i];
    __shared__ float red[256];
    red[threadIdx.x] = s; __syncthreads();
    for (int w = 128; w > 0; w >>= 1) {
        if (threadIdx.x < w) red[threadIdx.x] += red[threadIdx.x + w];
        __syncthreads();
    }
    if (threadIdx.x == 0) atomicAdd(&mean[ba], red[0]);
}

// per point: norm, cell id, count (mean arrives as raw sums; scale by 1/NPTS here)
__global__ void k_cellid(const float* __restrict__ coords, const float* __restrict__ mean,
                         float* __restrict__ norm, int* __restrict__ cellid,
                         unsigned* __restrict__ cnt) {
    int idx = blockIdx.x * 256 + threadIdx.x;      // b*NPTS + n
    int b = idx >> 15, n = idx & (NPTS - 1);
    int flat = 0;
    #pragma unroll
    for (int a = 0; a < 3; ++a) {
        float c = coords[((size_t)(b * 3 + a)) * NPTS + n];
        float nm = (c - mean[b * 3 + a] * (1.0f / NPTS) + 1.0f) * (0.5f * RR);
        nm = fminf(fmaxf(nm, 0.0f), (float)(RR - 1));
        norm[((size_t)(b * 3 + a)) * NPTS + n] = nm;
        flat = flat * RR + (int)rintf(nm);
    }
    int cell = b * RV + flat;
    cellid[idx] = cell;
    atomicAdd(&cnt[cell], 1u);
}

// block-local exclusive scan: 256 blocks x 1024 cells
__global__ void k_scan1(const unsigned* __restrict__ cnt, unsigned* __restrict__ base,
                        unsigned* __restrict__ aux) {
    int tid = threadIdx.x;
    int c0 = blockIdx.x * 1024 + tid * 4;
    unsigned v0 = cnt[c0], v1 = cnt[c0 + 1], v2 = cnt[c0 + 2], v3 = cnt[c0 + 3];
    unsigned tot = v0 + v1 + v2 + v3;
    __shared__ unsigned sc[256];
    sc[tid] = tot; __syncthreads();
    for (int off = 1; off < 256; off <<= 1) {
        unsigned t = (tid >= off) ? sc[tid - off] : 0u;
        __syncthreads();
        sc[tid] += t;
        __syncthreads();
    }
    unsigned excl = sc[tid] - tot;
    base[c0] = excl;
    base[c0 + 1] = excl + v0;
    base[c0 + 2] = excl + v0 + v1;
    base[c0 + 3] = excl + v0 + v1 + v2;
    if (tid == 255) aux[blockIdx.x] = sc[255];
}

__global__ void k_scan2(unsigned* __restrict__ aux) {
    int tid = threadIdx.x;
    unsigned own = aux[tid];
    __shared__ unsigned sc[256];
    sc[tid] = own; __syncthreads();
    for (int off = 1; off < 256; off <<= 1) {
        unsigned t = (tid >= off) ? sc[tid - off] : 0u;
        __syncthreads();
        sc[tid] += t;
        __syncthreads();
    }
    aux[tid] = sc[tid] - own;
}

__global__ void k_scan3(unsigned* __restrict__ base, const unsigned* __restrict__ aux) {
    int i = blockIdx.x * 256 + threadIdx.x;
    base[i] += aux[i >> 10];
}

// fused transpose + feature-sort + point-MLP (MFMA) + BN-p moment partials.
__global__ __launch_bounds__(256) void k_scatfeat(
    const float* __restrict__ feats, const int* __restrict__ cellid,
    unsigned* __restrict__ base, ushort* __restrict__ fsort,
    const ushort* __restrict__ wmb, const float* __restrict__ mbias,
    ushort* __restrict__ pb, float* __restrict__ partp) {
    __shared__ float t[64 * 65];
    __shared__ unsigned spos[64];
    __shared__ float sf[512];
    int b = blockIdx.x >> 9;
    int n0 = (blockIdx.x & 511) * 64;
    int tid = threadIdx.x;
    #pragma unroll
    for (int k = 0; k < 16; ++k) {
        int idx = k * 256 + tid;
        int c = idx >> 6, nl = idx & 63;
        t[c * 65 + nl] = feats[((size_t)(b * 64 + c)) * NPTS + n0 + nl];
    }
    if (tid < 64) {
        int cell = cellid[(b << 15) + n0 + tid];
        spos[tid] = atomicAdd(&base[cell], 1u);
    }
    __syncthreads();
    // scatter sorted bf16 rows
    #pragma unroll
    for (int it = 0; it < 2; ++it) {
        int pl = it * 32 + (tid >> 3);
        int j = tid & 7;
        unsigned pos = spos[pl];
        u16x8 v;
        #pragma unroll
        for (int k = 0; k < 8; ++k) v[k] = f2b(t[(j * 8 + k) * 65 + pl]);
        *reinterpret_cast<u16x8*>(fsort + (((size_t)pos) << 6) + j * 8) = v;
    }
    // MLP: wave w handles points w*16..w*16+15
    int w = tid >> 6, l = tid & 63;
    int nl = l & 15, kg = l >> 4;
    bf16x8 Af[2];
    #pragma unroll
    for (int ks = 0; ks < 2; ++ks) {
        union { u16x8 u; bf16x8 h; } cv;
        #pragma unroll
        for (int j = 0; j < 8; ++j)
            cv.u[j] = f2b(t[(ks * 32 + kg * 8 + j) * 65 + w * 16 + nl]);
        Af[ks] = cv.h;
    }
    f32x4 acc[4];
    #pragma unroll
    for (int cb = 0; cb < 4; ++cb) acc[cb] = (f32x4){0.f, 0.f, 0.f, 0.f};
    #pragma unroll
    for (int ks = 0; ks < 2; ++ks)
        #pragma unroll
        for (int cb = 0; cb < 4; ++cb) {
            bf16x8 Bf = *reinterpret_cast<const bf16x8*>(wmb + (cb * 16 + nl) * 64 + ks * 32 + kg * 8);
            acc[cb] = __builtin_amdgcn_mfma_f32_16x16x32_bf16(Af[ks], Bf, acc[cb], 0, 0, 0);
        }
    float ss[4] = {0.f, 0.f, 0.f, 0.f}, qq[4] = {0.f, 0.f, 0.f, 0.f};
    #pragma unroll
    for (int cb = 0; cb < 4; ++cb) {
        float bsv = mbias[cb * 16 + nl];
        #pragma unroll
        for (int r = 0; r < 4; ++r) {
            float yv = acc[cb][r] + bsv;
            int pt = w * 16 + kg * 4 + r;
            pb[(((size_t)((b << 15) + n0 + pt)) << 6) + cb * 16 + nl] = f2b(yv);
            ss[cb] += yv; qq[cb] += yv * yv;
        }
    }
    #pragma unroll
    for (int cb = 0; cb < 4; ++cb) {
        ss[cb] += __shfl_xor(ss[cb], 16); ss[cb] += __shfl_xor(ss[cb], 32);
        qq[cb] += __shfl_xor(qq[cb], 16); qq[cb] += __shfl_xor(qq[cb], 32);
    }
    if (l < 16) {
        #pragma unroll
        for (int cb = 0; cb < 4; ++cb) {
            sf[w * 128 + cb * 16 + nl] = ss[cb];
            sf[w * 128 + 64 + cb * 16 + nl] = qq[cb];
        }
    }
    __syncthreads();
    if (tid < 128)
        partp[(size_t)tid * 4096 + blockIdx.x] =
            sf[tid] + sf[128 + tid] + sf[256 + tid] + sf[384 + tid];
}

// one wave per cell: rows contiguous [start, start+n), unroll x8
__global__ __launch_bounds__(256) void k_gather(
    const ushort* __restrict__ fsort, const unsigned* __restrict__ base,
    const unsigned* __restrict__ cnt, __hip_bfloat16* __restrict__ xb) {
    int cell = blockIdx.x * 4 + (threadIdx.x >> 6);
    int lane = threadIdx.x & 63;
    unsigned n = cnt[cell];
    unsigned start = base[cell] - n;
    const ushort* rows = fsort + (((size_t)start) << 6) + lane;
    float acc = 0.f;
    unsigned i = 0;
    for (; i + 8 <= n; i += 8) {
        float f0 = b2f(rows[((size_t)(i + 0)) << 6]);
        float f1 = b2f(rows[((size_t)(i + 1)) << 6]);
        float f2 = b2f(rows[((size_t)(i + 2)) << 6]);
        float f3 = b2f(rows[((size_t)(i + 3)) << 6]);
        float f4 = b2f(rows[((size_t)(i + 4)) << 6]);
        float f5 = b2f(rows[((size_t)(i + 5)) << 6]);
        float f6 = b2f(rows[((size_t)(i + 6)) << 6]);
        float f7 = b2f(rows[((size_t)(i + 7)) << 6]);
        acc += ((f0 + f1) + (f2 + f3)) + ((f4 + f5) + (f6 + f7));
    }
    for (; i < n; ++i) acc += b2f(rows[((size_t)i) << 6]);
    float inv = (n > 0) ? (1.0f / (float)n) : 0.f;
    xb[((size_t)cell << 6) + lane] = __float2bfloat16(acc * inv);
}

// conv_w (co,ci,kd,kh,kw) -> wb[tap][co][ci] bf16
__global__ void k_wb(const float* __restrict__ w, __hip_bfloat16* __restrict__ wb) {
    int i = blockIdx.x * 256 + threadIdx.x;              // CC*CC*27
    if (i >= CC * CC * 27) return;
    int tap = i % 27, t = i / 27;
    int ci = t & 63, co = t >> 6;
    wb[((size_t)(tap * 64 + co)) * 64 + ci] = __float2bfloat16(w[i]);
}

// mlp_w (co,ci) f32 -> bf16
__global__ void k_wm(const float* __restrict__ w, ushort* __restrict__ wmb) {
    int i = blockIdx.x * 256 + threadIdx.x;
    if (i < 4096) wmb[i] = f2b(w[i]);
}

// x2 = bf16(leaky(y1*scl+sft)), vectorized x8
__global__ void k_act(const ushort* __restrict__ in, const float* __restrict__ scl,
                      const float* __restrict__ sft, ushort* __restrict__ out) {
    size_t i = ((size_t)blockIdx.x * 256 + threadIdx.x) << 3;
    u16x8 v = *reinterpret_cast<const u16x8*>(in + i);
    int c0 = (int)(i & 63);
    u16x8 o;
    #pragma unroll
    for (int j = 0; j < 8; ++j) {
        float f = fmaf(b2f(v[j]), scl[c0 + j], sft[c0 + j]);
        f = f > 0.f ? f : 0.1f * f;
        o[j] = f2b(f);
    }
    *reinterpret_cast<u16x8*>(out + i) = o;
}

// implicit-GEMM conv, both operands in LDS, 8 waves (2/SIMD) for latency hiding.
// block: 8x8x8 output tile (512 voxels) x 64 co, 512 threads; wave = 1 d-slice (mi=4).
// halo 10x10x10 (125KB) DMA'd once; weights 2-tap double-buffered 2x16KB. LDS 160768B.
__global__ __launch_bounds__(512, 2) void k_conv_mfma(
    const ushort* __restrict__ src, const ushort* __restrict__ wb,
    const float* __restrict__ bias, ushort* __restrict__ y,
    float* __restrict__ part, const ushort* __restrict__ zg) {
    __shared__ __align__(16) char sh[128000 + 32768];    // 160768 B
    char* wsh = sh + 128000;
    int tid = threadIdx.x;
    int lane = tid & 63, wid = tid >> 6;                 // wid in [0,8)
    int tile = ((blockIdx.x & 7) << 6) | (blockIdx.x >> 3);  // XCD-swizzled, 512 blocks
    int twi = tile & 3, thi = (tile >> 2) & 3;
    int tdi = (tile >> 4) & 3, b = tile >> 6;
    int d0 = tdi * 8, h0 = thi * 8, w0 = twi * 8;

    auto stage_wgt = [&](int g) {                        // taps 2g, 2g+1 (g<14)
        const ushort* wgrp = wb + g * 8192;
        char* wdst0 = wsh + (g & 1) * 16384;
        #pragma unroll
        for (int i = 0; i < 2; ++i) {
            int idx = i * 8 + wid;                       // [0,16)
            int c = idx * 64 + lane;                     // chunk [0,1024)
            int row = c >> 3, off = c & 7;               // row [0,128)
            const ushort* gsrc = wgrp + (((row << 3) + (off ^ (row & 7))) << 3);
            char* ldst = wdst0 + (idx << 10);
            __builtin_amdgcn_global_load_lds(
                (const __attribute__((address_space(1))) void*)gsrc,
                (__attribute__((address_space(3))) void*)ldst, 16, 0, 0);
        }
    };

    // halo DMA: 1000 rows x 8 chunks of 16B = 8000 chunks; 125 wave-groups of 64
    #pragma unroll
    for (int it = 0; it < 16; ++it) {
        int idx = it * 8 + wid;
        if (idx < 125) {
            int c = idx * 64 + lane;
            int row = c >> 3, off = c & 7;
            int dz = row / 100, rem = row - dz * 100;
            int hz = rem / 10, wz = rem - hz * 10;
            int gd = d0 - 1 + dz, gh = h0 - 1 + hz, gw = w0 - 1 + wz;
            int srcoff = off ^ (row & 7);
            const ushort* gsrc = ((unsigned)gd < 32u && (unsigned)gh < 32u && (unsigned)gw < 32u)
                ? src + ((((size_t)((b << 15) | (gd << 10) | (gh << 5) | gw)) << 6) + srcoff * 8)
                : zg;
            char* ldst = sh + (idx << 10);
            __builtin_amdgcn_global_load_lds(
                (const __attribute__((address_space(1))) void*)gsrc,
                (__attribute__((address_space(3))) void*)ldst, 16, 0, 0);
        }
    }
    stage_wgt(0);

    int nl = lane & 15, kg = lane >> 4;
    int rbase = wid * 100 + (nl >> 3) * 10 + (nl & 7);
    int bswz = (nl & 7) << 4;

    f32x4 acc[4][4];
    #pragma unroll
    for (int mi = 0; mi < 4; ++mi)
        #pragma unroll
        for (int cb = 0; cb < 4; ++cb) acc[mi][cb] = (f32x4){0.f, 0.f, 0.f, 0.f};

    __syncthreads();                                     // halo + wgt0 ready

    #pragma unroll 1
    for (int g = 0; g < 14; ++g) {
        if (g < 13) stage_wgt(g + 1);
        const char* wlds = wsh + (g & 1) * 16384;
        #pragma unroll
        for (int tl = 0; tl < 2; ++tl) {
            int t = g * 2 + tl;
            if (t < 27) {
                int kd = t / 9, rm = t - kd * 9;
                int kh = rm / 3, kw = rm - kh * 3;
                int rt = rbase + kd * 100 + kh * 10 + kw;
                bf16x8 a[4][2];
                #pragma unroll
                for (int mi = 0; mi < 4; ++mi) {
                    int r = rt + mi * 20;
                    int ba = ((r << 7) + (kg << 4)) ^ ((r & 7) << 4);
                    a[mi][0] = *reinterpret_cast<const bf16x8*>(sh + ba);
                    a[mi][1] = *reinterpret_cast<const bf16x8*>(sh + (ba ^ 64));
                }
                bf16x8 bf[4][2];
                #pragma unroll
                for (int cb = 0; cb < 4; ++cb) {
                    int rowb = tl * 64 + cb * 16 + nl;
                    int bb0 = ((rowb << 7) + (kg << 4)) ^ bswz;
                    bf[cb][0] = *reinterpret_cast<const bf16x8*>(wlds + bb0);
                    bf[cb][1] = *reinterpret_cast<const bf16x8*>(wlds + (bb0 ^ 64));
                }
                #pragma unroll
                for (int ks = 0; ks < 2; ++ks)
                    #pragma unroll
                    for (int mi = 0; mi < 4; ++mi)
                        #pragma unroll
                        for (int cb = 0; cb < 4; ++cb)
                            acc[mi][cb] = __builtin_amdgcn_mfma_f32_16x16x32_bf16(
                                a[mi][ks], bf[cb][ks], acc[mi][cb], 0, 0, 0);
            }
        }
        __syncthreads();                                 // drains wgt DMA g+1; flip
    }

    int d = d0 + wid;
    float bs[4];
    #pragma unroll
    for (int cb = 0; cb < 4; ++cb) bs[cb] = bias[cb * 16 + nl];
    float ss[4] = {0.f, 0.f, 0.f, 0.f}, qq[4] = {0.f, 0.f, 0.f, 0.f};
    #pragma unroll
    for (int mi = 0; mi < 4; ++mi) {
        int h = h0 + mi * 2 + (kg >> 1);
        int w = w0 + (kg & 1) * 4;
        size_t vox = (size_t)((b << 15) | (d << 10) | (h << 5) | w);
        #pragma unroll
        for (int cb = 0; cb < 4; ++cb) {
            int co = cb * 16 + nl;
            #pragma unroll
            for (int r = 0; r < 4; ++r) {
                float yv = acc[mi][cb][r] + bs[cb];
                y[((vox + r) << 6) + co] = f2b(yv);
                ss[cb] += yv; qq[cb] += yv * yv;
            }
        }
    }
    #pragma unroll
    for (int cb = 0; cb < 4; ++cb) {
        ss[cb] += __shfl_xor(ss[cb], 16); ss[cb] += __shfl_xor(ss[cb], 32);
        qq[cb] += __shfl_xor(qq[cb], 16); qq[cb] += __shfl_xor(qq[cb], 32);
    }
    float* sf = (float*)sh;                              // halo dead; reuse
    __syncthreads();
    if (lane < 16) {
        #pragma unroll
        for (int cb = 0; cb < 4; ++cb) {
            sf[wid * 128 + cb * 16 + nl] = ss[cb];
            sf[wid * 128 + 64 + cb * 16 + nl] = qq[cb];
        }
    }
    __syncthreads();
    if (tid < 128) {
        float t = sf[tid] + sf[128 + tid] + sf[256 + tid] + sf[384 + tid]
                + sf[512 + tid] + sf[640 + tid] + sf[768 + tid] + sf[896 + tid];
        part[tid * 512 + blockIdx.x] = t;
    }
}

// reduce partials -> BN affine (scl, sft). 64 blocks, block = one channel.
__global__ void k_redbn(const float* __restrict__ part, const float* __restrict__ g,
                        const float* __restrict__ bb, float* __restrict__ scl,
                        float* __restrict__ sft, int cnt) {
    int c = blockIdx.x;
    float s = 0.f, q = 0.f;
    for (int i = threadIdx.x; i < cnt; i += 256) {
        s += part[(size_t)c * cnt + i];
        q += part[(size_t)(64 + c) * cnt + i];
    }
    __shared__ float rs[256], rq[256];
    rs[threadIdx.x] = s; rq[threadIdx.x] = q; __syncthreads();
    for (int w = 128; w > 0; w >>= 1) {
        if (threadIdx.x < w) { rs[threadIdx.x] += rs[threadIdx.x + w]; rq[threadIdx.x] += rq[threadIdx.x + w]; }
        __syncthreads();
    }
    if (threadIdx.x == 0) {
        float mu = rs[0] * (1.0f / MTOT);
        float var = rq[0] * (1.0f / MTOT) - mu * mu;
        float sc = g[c] * rsqrtf(var + EPSV);
        scl[c] = sc; sft[c] = bb[c] - mu * sc;
    }
}

// y2 bf16 NDHWC -> v f32 NCDHW with BN2 affine + leaky fused
__global__ void k_transpose(const ushort* __restrict__ in, const float* __restrict__ scl,
                            const float* __restrict__ sft, float* __restrict__ out) {
    __shared__ float t[64 * 65];
    size_t base = (size_t)blockIdx.x * 4096;
    int gv0 = blockIdx.x * 64;
    int b = gv0 >> 15;
    int vox0 = gv0 & 32767;
    int chl = threadIdx.x & 63;
    float sc = scl[chl], sf = sft[chl];
    #pragma unroll
    for (int k = 0; k < 16; ++k) {
        int idx = k * 256 + threadIdx.x;
        float v = fmaf(b2f(in[base + idx]), sc, sf);
        t[(idx >> 6) * 65 + (idx & 63)] = v > 0.f ? v : 0.1f * v;
    }
    __syncthreads();
    #pragma unroll
    for (int k = 0; k < 16; ++k) {
        int idx = k * 256 + threadIdx.x;
        int ch = idx >> 6, voxl = idx & 63;
        out[((size_t)(b * 64 + ch)) * RV + vox0 + voxl] = t[voxl * 65 + ch];
    }
}

// fused: phase1 per point = trilinear(y2 bf16 w/ BN2+leaky) + leaky(BNp(pb)); phase2 coalesced write.
__global__ __launch_bounds__(256) void k_final(
    float* __restrict__ out, const ushort* __restrict__ pbuf,
    const ushort* __restrict__ vraw, const float* __restrict__ norm,
    const float* __restrict__ scl, const float* __restrict__ sft,
    const float* __restrict__ sclp, const float* __restrict__ sftp) {
    __shared__ float smp[64 * 65];
    int b = blockIdx.x >> 9;                 // 512 tiles per batch
    int n0 = (blockIdx.x & 511) * 64;
    int wid = threadIdx.x >> 6, lane = threadIdx.x & 63;
    const ushort* gb = vraw + (((size_t)b) << 15) * CC;
    const float* nrm0 = norm + ((size_t)(b * 3)) * NPTS;
    float sc = scl[lane], sf = sft[lane];
    float scp = sclp[lane], sfp = sftp[lane];

    #pragma unroll 2
    for (int i = 0; i < 16; ++i) {
        int pl = wid * 16 + i;
        int n = n0 + pl;
        float v0 = nrm0[n];
        float v1 = nrm0[NPTS + n];
        float v2 = nrm0[2 * NPTS + n];
        int lx = (int)floorf(v0), ly = (int)floorf(v1), lz = (int)floorf(v2);
        float fx = v0 - (float)lx, fy = v1 - (float)ly, fz = v2 - (float)lz;
        int hx = min(lx + 1, 31), hy = min(ly + 1, 31), hz = min(lz + 1, 31);
        float gx = 1.f - fx, gy = 1.f - fy, gz = 1.f - fz;

        int i000 = ((lx * 32 + ly) * 32 + lz) << 6;
        int i001 = ((lx * 32 + ly) * 32 + hz) << 6;
        int i010 = ((lx * 32 + hy) * 32 + lz) << 6;
        int i011 = ((lx * 32 + hy) * 32 + hz) << 6;
        int i100 = ((hx * 32 + ly) * 32 + lz) << 6;
        int i101 = ((hx * 32 + ly) * 32 + hz) << 6;
        int i110 = ((hx * 32 + hy) * 32 + lz) << 6;
        int i111 = ((hx * 32 + hy) * 32 + hz) << 6;

        float w000 = gx * gy * gz, w001 = gx * gy * fz;
        float w010 = gx * fy * gz, w011 = gx * fy * fz;
        float w100 = fx * gy * gz, w101 = fx * gy * fz;
        float w110 = fx * fy * gz, w111 = fx * fy * fz;

        float r0 = fmaf(b2f(gb[i000 + lane]), sc, sf); r0 = r0 > 0.f ? r0 : 0.1f * r0;
        float r1 = fmaf(b2f(gb[i001 + lane]), sc, sf); r1 = r1 > 0.f ? r1 : 0.1f * r1;
        float r2 = fmaf(b2f(gb[i010 + lane]), sc, sf); r2 = r2 > 0.f ? r2 : 0.1f * r2;
        float r3 = fmaf(b2f(gb[i011 + lane]), sc, sf); r3 = r3 > 0.f ? r3 : 0.1f * r3;
        float r4 = fmaf(b2f(gb[i100 + lane]), sc, sf); r4 = r4 > 0.f ? r4 : 0.1f * r4;
        float r5 = fmaf(b2f(gb[i101 + lane]), sc, sf); r5 = r5 > 0.f ? r5 : 0.1f * r5;
        float r6 = fmaf(b2f(gb[i110 + lane]), sc, sf); r6 = r6 > 0.f ? r6 : 0.1f * r6;
        float r7 = fmaf(b2f(gb[i111 + lane]), sc, sf); r7 = r7 > 0.f ? r7 : 0.1f * r7;

        float s = r0 * w000 + r1 * w001 + r2 * w010 + r3 * w011
                + r4 * w100 + r5 * w101 + r6 * w110 + r7 * w111;

        float pv = fmaf(b2f(pbuf[(((size_t)((b << 15) + n)) << 6) + lane]), scp, sfp);
        pv = pv > 0.f ? pv : 0.1f * pv;
        smp[pl * 65 + lane] = s + pv;
    }
    __syncthreads();

    #pragma unroll 4
    for (int i = 0; i < 16; ++i) {
        int co = i * 4 + wid;
        out[((size_t)(b * 64 + co)) * NPTS + n0 + lane] = smp[lane * 65 + co];
    }
}

extern "C" void kernel_launch(void* const* d_in, const int* in_sizes, int n_in,
                              void* d_out, int out_size, void* d_ws, size_t ws_size,
                              hipStream_t stream) {
    const float* features = (const float*)d_in[0];
    const float* coords   = (const float*)d_in[1];
    const float* conv1_w  = (const float*)d_in[2];
    const float* conv1_b  = (const float*)d_in[3];
    const float* bn1_g    = (const float*)d_in[4];
    const float* bn1_b    = (const float*)d_in[5];
    const float* conv2_w  = (const float*)d_in[6];
    const float* conv2_b  = (const float*)d_in[7];
    const float* bn2_g    = (const float*)d_in[8];
    const float* bn2_b    = (const float*)d_in[9];
    const float* mlp_w    = (const float*)d_in[10];
    const float* mlp_b    = (const float*)d_in[11];
    const float* bnp_g    = (const float*)d_in[12];
    const float* bnp_b    = (const float*)d_in[13];

    float* ws    = (float*)d_ws;
    ushort* fsort  = (ushort*)(ws + OFF_BUFA);           // dead after k_gather
    ushort* y2b    = (ushort*)(ws + OFF_BUFA);           // conv2 out (reuses fsort region)
    ushort* x2b    = (ushort*)(ws + OFF_BUFA) + (size_t)16777216;  // x2 bf16
    __hip_bfloat16* xb  = (__hip_bfloat16*)(ws + OFF_BUFB);
    __hip_bfloat16* wb1 = (__hip_bfloat16*)(ws + OFF_WB1);
    __hip_bfloat16* wb2 = (__hip_bfloat16*)(ws + OFF_WB2);
    ushort* zg   = (ushort*)(ws + OFF_ZG);
    unsigned* base    = (unsigned*)(ws + OFF_BASE);
    unsigned* aux     = (unsigned*)(ws + OFF_AUX);
    int* cellid       = (int*)(ws + OFF_CELL);
    unsigned* cnt     = (unsigned*)(ws + OFF_CNT);
    float* mean  = ws + OFF_MEAN;
    float* part1 = ws + OFF_PART1;
    float* part2 = ws + OFF_PART2;
    float* scl1  = ws + OFF_SCL1;
    float* sft1  = ws + OFF_SFT1;
    float* scl2  = ws + OFF_SCL2;
    float* sft2  = ws + OFF_SFT2;
    ushort* wmb  = (ushort*)(ws + OFF_WM);
    float* partp = ws + OFF_PARTP;
    float* sclp  = ws + OFF_SCLP;
    float* sftp  = ws + OFF_SFTP;
    float* nrm   = ws + OFF_NORM;

    float* outF  = (float*)d_out;                       // fused output
    float* outV  = (float*)d_out + (size_t)16777216;    // v output region
    ushort* y1b  = (ushort*)outV;                       // y1 bf16 scratch: outV float-slots [0 .. 8.4M)
    ushort* pbuf = (ushort*)(outV + (size_t)8388608);   // pb bf16: outV float-slots [8.4M .. 16.7M)

    hipMemsetAsync(cnt, 0, 262144 * 4, stream);
    hipMemsetAsync(zg, 0, 256, stream);
    hipMemsetAsync(mean, 0, 24 * 4, stream);

    k_coord_mean<<<192, 256, 0, stream>>>(coords, mean);
    k_cellid<<<1024, 256, 0, stream>>>(coords, mean, nrm, cellid, cnt);
    k_scan1<<<256, 256, 0, stream>>>(cnt, base, aux);
    k_scan2<<<1, 256, 0, stream>>>(aux);
    k_scan3<<<1024, 256, 0, stream>>>(base, aux);

    k_wb<<<432, 256, 0, stream>>>(conv1_w, wb1);
    k_wb<<<432, 256, 0, stream>>>(conv2_w, wb2);
    k_wm<<<16, 256, 0, stream>>>(mlp_w, wmb);

    // fused: sort features + point-MLP (pb -> d_out scratch) + BN-p partials
    k_scatfeat<<<4096, 256, 0, stream>>>(features, cellid, base, fsort,
                                         wmb, mlp_b, pbuf, partp);
    k_redbn<<<64, 256, 0, stream>>>(partp, bnp_g, bnp_b, sclp, sftp, 4096);
    k_gather<<<65536, 256, 0, stream>>>(fsort, base, cnt, xb);

    // conv1: xb -> y1b + partials
    k_conv_mfma<<<512, 512, 0, stream>>>((const ushort*)xb, (const ushort*)wb1, conv1_b,
                                         y1b, part1, zg);
    k_redbn<<<64, 256, 0, stream>>>(part1, bn1_g, bn1_b, scl1, sft1, 512);

    // x2 = leaky(bn1(y1)) bf16
    k_act<<<8192, 256, 0, stream>>>(y1b, scl1, sft1, x2b);

    // conv2: x2b -> y2b + partials
    k_conv_mfma<<<512, 512, 0, stream>>>(x2b, (const ushort*)wb2, conv2_b,
                                         y2b, part2, zg);
    k_redbn<<<64, 256, 0, stream>>>(part2, bn2_g, bn2_b, scl2, sft2, 512);

    // fuse -> outF (reads pbuf from outV scratch; must run BEFORE k_transpose)
    k_final<<<4096, 256, 0, stream>>>(outF, pbuf, y2b, nrm, scl2, sft2, sclp, sftp);

    // v = leaky(bn2(y2)) -> d_out NCDHW f32 (overwrites y1b + pbuf scratch)
    k_transpose<<<4096, 256, 0, stream>>>(y2b, scl2, sft2, outV);
}

// Round 16
// 363.836 us; speedup vs baseline: 1.0963x; 1.0392x over previous
//
#include <hip/hip_runtime.h>
#include <hip/hip_bf16.h>

#define BB 8
#define CC 64
#define NPTS 32768
#define RR 32
#define RV 32768            // 32^3
#define MTOT (BB*RV)        // 262144
#define EPSV 1e-4f

// ws float offsets
#define OFF_BUFA 0u               // fsort bf16 [0:8.4M) -> y2b bf16
#define OFF_BUFB 16777216u        // xb bf16 (x1 grid)
#define OFF_WB1  25165824u        // 55296 float-slots = 110592 bf16
#define OFF_WB2  25221120u        // 55296
#define OFF_ZG   25276416u        // 64 floats zero guard
#define OFF_BASE 25276480u        // 262144 uint
#define OFF_AUX  25800768u        // 256 uint
#define OFF_CELL 25801024u        // 262144 int
#define OFF_CNT  26063168u        // 262144 uint
#define OFF_MEAN 26325312u        // 24
#define OFF_PART1 26325504u       // 128 x 1024 (using 128 x 512)
#define OFF_PART2 26456576u       // 128 x 1024 (using 128 x 512)
#define OFF_SCL1 26587648u        // 64
#define OFF_SFT1 26587712u        // 64
#define OFF_SCL2 26587776u        // 64
#define OFF_SFT2 26587840u        // 64
#define OFF_WM   26587904u        // 2048 float-slots = 4096 bf16
#define OFF_PARTP 26590208u       // 128 x 4096 floats -> ends 27114496
#define OFF_SCLP 27114496u        // 64
#define OFF_SFTP 27114560u        // 64
#define OFF_NORM 33554432u        // 786432 (survives to k_final)

typedef __attribute__((ext_vector_type(8))) __bf16 bf16x8;
typedef __attribute__((ext_vector_type(8))) unsigned short u16x8;
typedef __attribute__((ext_vector_type(4))) float f32x4;

__device__ __forceinline__ float b2f(ushort u) {
    union { unsigned u; float f; } x; x.u = ((unsigned)u) << 16; return x.f;
}
__device__ __forceinline__ ushort f2b(float f) {
    __hip_bfloat16 h = __float2bfloat16(f);
    return *reinterpret_cast<ushort*>(&h);
}

// 192 blocks: (b*3+axis)*8 + chunk; partial sums via f32 atomics into mean[24]
__global__ void k_coord_mean(const float* __restrict__ coords, float* __restrict__ mean) {
    int ba = blockIdx.x >> 3, ch = blockIdx.x & 7;
    const float* src = coords + (size_t)ba * NPTS + ch * 4096;
    float s = 0.f;
    for (int i = threadIdx.x; i < 4096; i += 256) s += src[i];
    __shared__ float red[256];
    red[threadIdx.x] = s; __syncthreads();
    for (int w = 128; w > 0; w >>= 1) {
        if (threadIdx.x < w) red[threadIdx.x] += red[threadIdx.x + w];
        __syncthreads();
    }
    if (threadIdx.x == 0) atomicAdd(&mean[ba], red[0]);
}

// per point: norm, cell id, count (mean arrives as raw sums; scale by 1/NPTS here)
__global__ void k_cellid(const float* __restrict__ coords, const float* __restrict__ mean,
                         float* __restrict__ norm, int* __restrict__ cellid,
                         unsigned* __restrict__ cnt) {
    int idx = blockIdx.x * 256 + threadIdx.x;      // b*NPTS + n
    int b = idx >> 15, n = idx & (NPTS - 1);
    int flat = 0;
    #pragma unroll
    for (int a = 0; a < 3; ++a) {
        float c = coords[((size_t)(b * 3 + a)) * NPTS + n];
        float nm = (c - mean[b * 3 + a] * (1.0f / NPTS) + 1.0f) * (0.5f * RR);
        nm = fminf(fmaxf(nm, 0.0f), (float)(RR - 1));
        norm[((size_t)(b * 3 + a)) * NPTS + n] = nm;
        flat = flat * RR + (int)rintf(nm);
    }
    int cell = b * RV + flat;
    cellid[idx] = cell;
    atomicAdd(&cnt[cell], 1u);
}

// block-local exclusive scan: 256 blocks x 1024 cells
__global__ void k_scan1(const unsigned* __restrict__ cnt, unsigned* __restrict__ base,
                        unsigned* __restrict__ aux) {
    int tid = threadIdx.x;
    int c0 = blockIdx.x * 1024 + tid * 4;
    unsigned v0 = cnt[c0], v1 = cnt[c0 + 1], v2 = cnt[c0 + 2], v3 = cnt[c0 + 3];
    unsigned tot = v0 + v1 + v2 + v3;
    __shared__ unsigned sc[256];
    sc[tid] = tot; __syncthreads();
    for (int off = 1; off < 256; off <<= 1) {
        unsigned t = (tid >= off) ? sc[tid - off] : 0u;
        __syncthreads();
        sc[tid] += t;
        __syncthreads();
    }
    unsigned excl = sc[tid] - tot;
    base[c0] = excl;
    base[c0 + 1] = excl + v0;
    base[c0 + 2] = excl + v0 + v1;
    base[c0 + 3] = excl + v0 + v1 + v2;
    if (tid == 255) aux[blockIdx.x] = sc[255];
}

__global__ void k_scan2(unsigned* __restrict__ aux) {
    int tid = threadIdx.x;
    unsigned own = aux[tid];
    __shared__ unsigned sc[256];
    sc[tid] = own; __syncthreads();
    for (int off = 1; off < 256; off <<= 1) {
        unsigned t = (tid >= off) ? sc[tid - off] : 0u;
        __syncthreads();
        sc[tid] += t;
        __syncthreads();
    }
    aux[tid] = sc[tid] - own;
}

__global__ void k_scan3(unsigned* __restrict__ base, const unsigned* __restrict__ aux) {
    int i = blockIdx.x * 256 + threadIdx.x;
    base[i] += aux[i >> 10];
}

// fused transpose + feature-sort + point-MLP (MFMA) + BN-p moment partials.
__global__ __launch_bounds__(256) void k_scatfeat(
    const float* __restrict__ feats, const int* __restrict__ cellid,
    unsigned* __restrict__ base, ushort* __restrict__ fsort,
    const ushort* __restrict__ wmb, const float* __restrict__ mbias,
    ushort* __restrict__ pb, float* __restrict__ partp) {
    __shared__ float t[64 * 65];
    __shared__ unsigned spos[64];
    __shared__ float sf[512];
    int b = blockIdx.x >> 9;
    int n0 = (blockIdx.x & 511) * 64;
    int tid = threadIdx.x;
    #pragma unroll
    for (int k = 0; k < 16; ++k) {
        int idx = k * 256 + tid;
        int c = idx >> 6, nl = idx & 63;
        t[c * 65 + nl] = feats[((size_t)(b * 64 + c)) * NPTS + n0 + nl];
    }
    if (tid < 64) {
        int cell = cellid[(b << 15) + n0 + tid];
        spos[tid] = atomicAdd(&base[cell], 1u);
    }
    __syncthreads();
    // scatter sorted bf16 rows
    #pragma unroll
    for (int it = 0; it < 2; ++it) {
        int pl = it * 32 + (tid >> 3);
        int j = tid & 7;
        unsigned pos = spos[pl];
        u16x8 v;
        #pragma unroll
        for (int k = 0; k < 8; ++k) v[k] = f2b(t[(j * 8 + k) * 65 + pl]);
        *reinterpret_cast<u16x8*>(fsort + (((size_t)pos) << 6) + j * 8) = v;
    }
    // MLP: wave w handles points w*16..w*16+15
    int w = tid >> 6, l = tid & 63;
    int nl = l & 15, kg = l >> 4;
    bf16x8 Af[2];
    #pragma unroll
    for (int ks = 0; ks < 2; ++ks) {
        union { u16x8 u; bf16x8 h; } cv;
        #pragma unroll
        for (int j = 0; j < 8; ++j)
            cv.u[j] = f2b(t[(ks * 32 + kg * 8 + j) * 65 + w * 16 + nl]);
        Af[ks] = cv.h;
    }
    f32x4 acc[4];
    #pragma unroll
    for (int cb = 0; cb < 4; ++cb) acc[cb] = (f32x4){0.f, 0.f, 0.f, 0.f};
    #pragma unroll
    for (int ks = 0; ks < 2; ++ks)
        #pragma unroll
        for (int cb = 0; cb < 4; ++cb) {
            bf16x8 Bf = *reinterpret_cast<const bf16x8*>(wmb + (cb * 16 + nl) * 64 + ks * 32 + kg * 8);
            acc[cb] = __builtin_amdgcn_mfma_f32_16x16x32_bf16(Af[ks], Bf, acc[cb], 0, 0, 0);
        }
    float ss[4] = {0.f, 0.f, 0.f, 0.f}, qq[4] = {0.f, 0.f, 0.f, 0.f};
    #pragma unroll
    for (int cb = 0; cb < 4; ++cb) {
        float bsv = mbias[cb * 16 + nl];
        #pragma unroll
        for (int r = 0; r < 4; ++r) {
            float yv = acc[cb][r] + bsv;
            int pt = w * 16 + kg * 4 + r;
            pb[(((size_t)((b << 15) + n0 + pt)) << 6) + cb * 16 + nl] = f2b(yv);
            ss[cb] += yv; qq[cb] += yv * yv;
        }
    }
    #pragma unroll
    for (int cb = 0; cb < 4; ++cb) {
        ss[cb] += __shfl_xor(ss[cb], 16); ss[cb] += __shfl_xor(ss[cb], 32);
        qq[cb] += __shfl_xor(qq[cb], 16); qq[cb] += __shfl_xor(qq[cb], 32);
    }
    if (l < 16) {
        #pragma unroll
        for (int cb = 0; cb < 4; ++cb) {
            sf[w * 128 + cb * 16 + nl] = ss[cb];
            sf[w * 128 + 64 + cb * 16 + nl] = qq[cb];
        }
    }
    __syncthreads();
    if (tid < 128)
        partp[(size_t)tid * 4096 + blockIdx.x] =
            sf[tid] + sf[128 + tid] + sf[256 + tid] + sf[384 + tid];
}

// one wave per cell: rows contiguous [start, start+n), unroll x8
__global__ __launch_bounds__(256) void k_gather(
    const ushort* __restrict__ fsort, const unsigned* __restrict__ base,
    const unsigned* __restrict__ cnt, __hip_bfloat16* __restrict__ xb) {
    int cell = blockIdx.x * 4 + (threadIdx.x >> 6);
    int lane = threadIdx.x & 63;
    unsigned n = cnt[cell];
    unsigned start = base[cell] - n;
    const ushort* rows = fsort + (((size_t)start) << 6) + lane;
    float acc = 0.f;
    unsigned i = 0;
    for (; i + 8 <= n; i += 8) {
        float f0 = b2f(rows[((size_t)(i + 0)) << 6]);
        float f1 = b2f(rows[((size_t)(i + 1)) << 6]);
        float f2 = b2f(rows[((size_t)(i + 2)) << 6]);
        float f3 = b2f(rows[((size_t)(i + 3)) << 6]);
        float f4 = b2f(rows[((size_t)(i + 4)) << 6]);
        float f5 = b2f(rows[((size_t)(i + 5)) << 6]);
        float f6 = b2f(rows[((size_t)(i + 6)) << 6]);
        float f7 = b2f(rows[((size_t)(i + 7)) << 6]);
        acc += ((f0 + f1) + (f2 + f3)) + ((f4 + f5) + (f6 + f7));
    }
    for (; i < n; ++i) acc += b2f(rows[((size_t)i) << 6]);
    float inv = (n > 0) ? (1.0f / (float)n) : 0.f;
    xb[((size_t)cell << 6) + lane] = __float2bfloat16(acc * inv);
}

// conv_w (co,ci,kd,kh,kw) -> wb[tap][co][ci] bf16
__global__ void k_wb(const float* __restrict__ w, __hip_bfloat16* __restrict__ wb) {
    int i = blockIdx.x * 256 + threadIdx.x;              // CC*CC*27
    if (i >= CC * CC * 27) return;
    int tap = i % 27, t = i / 27;
    int ci = t & 63, co = t >> 6;
    wb[((size_t)(tap * 64 + co)) * 64 + ci] = __float2bfloat16(w[i]);
}

// mlp_w (co,ci) f32 -> bf16
__global__ void k_wm(const float* __restrict__ w, ushort* __restrict__ wmb) {
    int i = blockIdx.x * 256 + threadIdx.x;
    if (i < 4096) wmb[i] = f2b(w[i]);
}

// implicit-GEMM conv, both operands in LDS, 8 waves (2/SIMD).
// block: 8x8x8 output tile (512 voxels) x 64 co, 512 threads; wave = 1 d-slice (mi=4).
// halo 10x10x10 (125KB); weights 2-tap double-buffered 2x16KB. LDS 160768B.
// MODE 0: halo via global_load_lds DMA (pre-swizzled source).
// MODE 1: halo reg-staged from raw y1 with BN1 affine + leaky applied in-register
//         (write-side swizzle = same involution; OOB stays 0 = conv zero-padding).
template<int MODE>
__global__ __launch_bounds__(512, 2) void k_conv_mfma(
    const ushort* __restrict__ src, const ushort* __restrict__ wb,
    const float* __restrict__ bias, const float* __restrict__ scl,
    const float* __restrict__ sft, ushort* __restrict__ y,
    float* __restrict__ part, const ushort* __restrict__ zg) {
    __shared__ __align__(16) char sh[128000 + 32768];    // 160768 B
    char* wsh = sh + 128000;
    int tid = threadIdx.x;
    int lane = tid & 63, wid = tid >> 6;                 // wid in [0,8)
    int tile = ((blockIdx.x & 7) << 6) | (blockIdx.x >> 3);  // XCD-swizzled, 512 blocks
    int twi = tile & 3, thi = (tile >> 2) & 3;
    int tdi = (tile >> 4) & 3, b = tile >> 6;
    int d0 = tdi * 8, h0 = thi * 8, w0 = twi * 8;

    auto stage_wgt = [&](int g) {                        // taps 2g, 2g+1 (g<14)
        const ushort* wgrp = wb + g * 8192;
        char* wdst0 = wsh + (g & 1) * 16384;
        #pragma unroll
        for (int i = 0; i < 2; ++i) {
            int idx = i * 8 + wid;                       // [0,16)
            int c = idx * 64 + lane;                     // chunk [0,1024)
            int row = c >> 3, off = c & 7;               // row [0,128)
            const ushort* gsrc = wgrp + (((row << 3) + (off ^ (row & 7))) << 3);
            char* ldst = wdst0 + (idx << 10);
            __builtin_amdgcn_global_load_lds(
                (const __attribute__((address_space(1))) void*)gsrc,
                (__attribute__((address_space(3))) void*)ldst, 16, 0, 0);
        }
    };

    float sc8[8], sf8[8];
    if (MODE == 1) {
        int c0 = (lane & 7) * 8;                         // thread's chunk channel group
        #pragma unroll
        for (int j = 0; j < 8; ++j) { sc8[j] = scl[c0 + j]; sf8[j] = sft[c0 + j]; }
    }

    // halo: 1000 rows x 8 chunks of 16B = 8000 chunks; 125 wave-groups of 64
    #pragma unroll
    for (int it = 0; it < 16; ++it) {
        int idx = it * 8 + wid;
        if (idx < 125) {
            int c = idx * 64 + lane;
            int row = c >> 3, off = c & 7;
            int dz = row / 100, rem = row - dz * 100;
            int hz = rem / 10, wz = rem - hz * 10;
            int gd = d0 - 1 + dz, gh = h0 - 1 + hz, gw = w0 - 1 + wz;
            bool inb = ((unsigned)gd < 32u) && ((unsigned)gh < 32u) && ((unsigned)gw < 32u);
            if (MODE == 0) {
                int srcoff = off ^ (row & 7);
                const ushort* gsrc = inb
                    ? src + ((((size_t)((b << 15) | (gd << 10) | (gh << 5) | gw)) << 6) + srcoff * 8)
                    : zg;
                char* ldst = sh + (idx << 10);
                __builtin_amdgcn_global_load_lds(
                    (const __attribute__((address_space(1))) void*)gsrc,
                    (__attribute__((address_space(3))) void*)ldst, 16, 0, 0);
            } else {
                u16x8 v = {0, 0, 0, 0, 0, 0, 0, 0};
                if (inb) {
                    v = *reinterpret_cast<const u16x8*>(
                        src + ((((size_t)((b << 15) | (gd << 10) | (gh << 5) | gw)) << 6) + off * 8));
                    #pragma unroll
                    for (int j = 0; j < 8; ++j) {
                        float f = fmaf(b2f(v[j]), sc8[j], sf8[j]);
                        f = f > 0.f ? f : 0.1f * f;
                        v[j] = f2b(f);
                    }
                }
                int la = ((row << 7) + (off << 4)) ^ ((row & 7) << 4);
                *reinterpret_cast<u16x8*>(sh + la) = v;
            }
        }
    }
    stage_wgt(0);

    int nl = lane & 15, kg = lane >> 4;
    int rbase = wid * 100 + (nl >> 3) * 10 + (nl & 7);
    int bswz = (nl & 7) << 4;

    f32x4 acc[4][4];
    #pragma unroll
    for (int mi = 0; mi < 4; ++mi)
        #pragma unroll
        for (int cb = 0; cb < 4; ++cb) acc[mi][cb] = (f32x4){0.f, 0.f, 0.f, 0.f};

    __syncthreads();                                     // halo + wgt0 ready

    #pragma unroll 1
    for (int g = 0; g < 14; ++g) {
        if (g < 13) stage_wgt(g + 1);
        const char* wlds = wsh + (g & 1) * 16384;
        #pragma unroll
        for (int tl = 0; tl < 2; ++tl) {
            int t = g * 2 + tl;
            if (t < 27) {
                int kd = t / 9, rm = t - kd * 9;
                int kh = rm / 3, kw = rm - kh * 3;
                int rt = rbase + kd * 100 + kh * 10 + kw;
                bf16x8 a[4][2];
                #pragma unroll
                for (int mi = 0; mi < 4; ++mi) {
                    int r = rt + mi * 20;
                    int ba = ((r << 7) + (kg << 4)) ^ ((r & 7) << 4);
                    a[mi][0] = *reinterpret_cast<const bf16x8*>(sh + ba);
                    a[mi][1] = *reinterpret_cast<const bf16x8*>(sh + (ba ^ 64));
                }
                bf16x8 bf[4][2];
                #pragma unroll
                for (int cb = 0; cb < 4; ++cb) {
                    int rowb = tl * 64 + cb * 16 + nl;
                    int bb0 = ((rowb << 7) + (kg << 4)) ^ bswz;
                    bf[cb][0] = *reinterpret_cast<const bf16x8*>(wlds + bb0);
                    bf[cb][1] = *reinterpret_cast<const bf16x8*>(wlds + (bb0 ^ 64));
                }
                __builtin_amdgcn_s_setprio(1);
                #pragma unroll
                for (int ks = 0; ks < 2; ++ks)
                    #pragma unroll
                    for (int mi = 0; mi < 4; ++mi)
                        #pragma unroll
                        for (int cb = 0; cb < 4; ++cb)
                            acc[mi][cb] = __builtin_amdgcn_mfma_f32_16x16x32_bf16(
                                a[mi][ks], bf[cb][ks], acc[mi][cb], 0, 0, 0);
                __builtin_amdgcn_s_setprio(0);
            }
        }
        __syncthreads();                                 // drains wgt DMA g+1; flip
    }

    int d = d0 + wid;
    float bs[4];
    #pragma unroll
    for (int cb = 0; cb < 4; ++cb) bs[cb] = bias[cb * 16 + nl];
    float ss[4] = {0.f, 0.f, 0.f, 0.f}, qq[4] = {0.f, 0.f, 0.f, 0.f};
    #pragma unroll
    for (int mi = 0; mi < 4; ++mi) {
        int h = h0 + mi * 2 + (kg >> 1);
        int w = w0 + (kg & 1) * 4;
        size_t vox = (size_t)((b << 15) | (d << 10) | (h << 5) | w);
        #pragma unroll
        for (int cb = 0; cb < 4; ++cb) {
            int co = cb * 16 + nl;
            #pragma unroll
            for (int r = 0; r < 4; ++r) {
                float yv = acc[mi][cb][r] + bs[cb];
                y[((vox + r) << 6) + co] = f2b(yv);
                ss[cb] += yv; qq[cb] += yv * yv;
            }
        }
    }
    #pragma unroll
    for (int cb = 0; cb < 4; ++cb) {
        ss[cb] += __shfl_xor(ss[cb], 16); ss[cb] += __shfl_xor(ss[cb], 32);
        qq[cb] += __shfl_xor(qq[cb], 16); qq[cb] += __shfl_xor(qq[cb], 32);
    }
    float* sf2 = (float*)sh;                             // halo dead; reuse
    __syncthreads();
    if (lane < 16) {
        #pragma unroll
        for (int cb = 0; cb < 4; ++cb) {
            sf2[wid * 128 + cb * 16 + nl] = ss[cb];
            sf2[wid * 128 + 64 + cb * 16 + nl] = qq[cb];
        }
    }
    __syncthreads();
    if (tid < 128) {
        float t = sf2[tid] + sf2[128 + tid] + sf2[256 + tid] + sf2[384 + tid]
                + sf2[512 + tid] + sf2[640 + tid] + sf2[768 + tid] + sf2[896 + tid];
        part[tid * 512 + blockIdx.x] = t;
    }
}

// reduce partials -> BN affine (scl, sft). 64 blocks, block = one channel.
__global__ void k_redbn(const float* __restrict__ part, const float* __restrict__ g,
                        const float* __restrict__ bb, float* __restrict__ scl,
                        float* __restrict__ sft, int cnt) {
    int c = blockIdx.x;
    float s = 0.f, q = 0.f;
    for (int i = threadIdx.x; i < cnt; i += 256) {
        s += part[(size_t)c * cnt + i];
        q += part[(size_t)(64 + c) * cnt + i];
    }
    __shared__ float rs[256], rq[256];
    rs[threadIdx.x] = s; rq[threadIdx.x] = q; __syncthreads();
    for (int w = 128; w > 0; w >>= 1) {
        if (threadIdx.x < w) { rs[threadIdx.x] += rs[threadIdx.x + w]; rq[threadIdx.x] += rq[threadIdx.x + w]; }
        __syncthreads();
    }
    if (threadIdx.x == 0) {
        float mu = rs[0] * (1.0f / MTOT);
        float var = rq[0] * (1.0f / MTOT) - mu * mu;
        float sc = g[c] * rsqrtf(var + EPSV);
        scl[c] = sc; sft[c] = bb[c] - mu * sc;
    }
}

// y2 bf16 NDHWC -> v f32 NCDHW with BN2 affine + leaky fused
__global__ void k_transpose(const ushort* __restrict__ in, const float* __restrict__ scl,
                            const float* __restrict__ sft, float* __restrict__ out) {
    __shared__ float t[64 * 65];
    size_t base = (size_t)blockIdx.x * 4096;
    int gv0 = blockIdx.x * 64;
    int b = gv0 >> 15;
    int vox0 = gv0 & 32767;
    int chl = threadIdx.x & 63;
    float sc = scl[chl], sf = sft[chl];
    #pragma unroll
    for (int k = 0; k < 16; ++k) {
        int idx = k * 256 + threadIdx.x;
        float v = fmaf(b2f(in[base + idx]), sc, sf);
        t[(idx >> 6) * 65 + (idx & 63)] = v > 0.f ? v : 0.1f * v;
    }
    __syncthreads();
    #pragma unroll
    for (int k = 0; k < 16; ++k) {
        int idx = k * 256 + threadIdx.x;
        int ch = idx >> 6, voxl = idx & 63;
        out[((size_t)(b * 64 + ch)) * RV + vox0 + voxl] = t[voxl * 65 + ch];
    }
}

// fused: phase1 per point = trilinear(y2 bf16 w/ BN2+leaky) + leaky(BNp(pb)); phase2 coalesced write.
__global__ __launch_bounds__(256) void k_final(
    float* __restrict__ out, const ushort* __restrict__ pbuf,
    const ushort* __restrict__ vraw, const float* __restrict__ norm,
    const float* __restrict__ scl, const float* __restrict__ sft,
    const float* __restrict__ sclp, const float* __restrict__ sftp) {
    __shared__ float smp[64 * 65];
    int b = blockIdx.x >> 9;                 // 512 tiles per batch
    int n0 = (blockIdx.x & 511) * 64;
    int wid = threadIdx.x >> 6, lane = threadIdx.x & 63;
    const ushort* gb = vraw + (((size_t)b) << 15) * CC;
    const float* nrm0 = norm + ((size_t)(b * 3)) * NPTS;
    float sc = scl[lane], sf = sft[lane];
    float scp = sclp[lane], sfp = sftp[lane];

    #pragma unroll 2
    for (int i = 0; i < 16; ++i) {
        int pl = wid * 16 + i;
        int n = n0 + pl;
        float v0 = nrm0[n];
        float v1 = nrm0[NPTS + n];
        float v2 = nrm0[2 * NPTS + n];
        int lx = (int)floorf(v0), ly = (int)floorf(v1), lz = (int)floorf(v2);
        float fx = v0 - (float)lx, fy = v1 - (float)ly, fz = v2 - (float)lz;
        int hx = min(lx + 1, 31), hy = min(ly + 1, 31), hz = min(lz + 1, 31);
        float gx = 1.f - fx, gy = 1.f - fy, gz = 1.f - fz;

        int i000 = ((lx * 32 + ly) * 32 + lz) << 6;
        int i001 = ((lx * 32 + ly) * 32 + hz) << 6;
        int i010 = ((lx * 32 + hy) * 32 + lz) << 6;
        int i011 = ((lx * 32 + hy) * 32 + hz) << 6;
        int i100 = ((hx * 32 + ly) * 32 + lz) << 6;
        int i101 = ((hx * 32 + ly) * 32 + hz) << 6;
        int i110 = ((hx * 32 + hy) * 32 + lz) << 6;
        int i111 = ((hx * 32 + hy) * 32 + hz) << 6;

        float w000 = gx * gy * gz, w001 = gx * gy * fz;
        float w010 = gx * fy * gz, w011 = gx * fy * fz;
        float w100 = fx * gy * gz, w101 = fx * gy * fz;
        float w110 = fx * fy * gz, w111 = fx * fy * fz;

        float r0 = fmaf(b2f(gb[i000 + lane]), sc, sf); r0 = r0 > 0.f ? r0 : 0.1f * r0;
        float r1 = fmaf(b2f(gb[i001 + lane]), sc, sf); r1 = r1 > 0.f ? r1 : 0.1f * r1;
        float r2 = fmaf(b2f(gb[i010 + lane]), sc, sf); r2 = r2 > 0.f ? r2 : 0.1f * r2;
        float r3 = fmaf(b2f(gb[i011 + lane]), sc, sf); r3 = r3 > 0.f ? r3 : 0.1f * r3;
        float r4 = fmaf(b2f(gb[i100 + lane]), sc, sf); r4 = r4 > 0.f ? r4 : 0.1f * r4;
        float r5 = fmaf(b2f(gb[i101 + lane]), sc, sf); r5 = r5 > 0.f ? r5 : 0.1f * r5;
        float r6 = fmaf(b2f(gb[i110 + lane]), sc, sf); r6 = r6 > 0.f ? r6 : 0.1f * r6;
        float r7 = fmaf(b2f(gb[i111 + lane]), sc, sf); r7 = r7 > 0.f ? r7 : 0.1f * r7;

        float s = r0 * w000 + r1 * w001 + r2 * w010 + r3 * w011
                + r4 * w100 + r5 * w101 + r6 * w110 + r7 * w111;

        float pv = fmaf(b2f(pbuf[(((size_t)((b << 15) + n)) << 6) + lane]), scp, sfp);
        pv = pv > 0.f ? pv : 0.1f * pv;
        smp[pl * 65 + lane] = s + pv;
    }
    __syncthreads();

    #pragma unroll 4
    for (int i = 0; i < 16; ++i) {
        int co = i * 4 + wid;
        out[((size_t)(b * 64 + co)) * NPTS + n0 + lane] = smp[lane * 65 + co];
    }
}

extern "C" void kernel_launch(void* const* d_in, const int* in_sizes, int n_in,
                              void* d_out, int out_size, void* d_ws, size_t ws_size,
                              hipStream_t stream) {
    const float* features = (const float*)d_in[0];
    const float* coords   = (const float*)d_in[1];
    const float* conv1_w  = (const float*)d_in[2];
    const float* conv1_b  = (const float*)d_in[3];
    const float* bn1_g    = (const float*)d_in[4];
    const float* bn1_b    = (const float*)d_in[5];
    const float* conv2_w  = (const float*)d_in[6];
    const float* conv2_b  = (const float*)d_in[7];
    const float* bn2_g    = (const float*)d_in[8];
    const float* bn2_b    = (const float*)d_in[9];
    const float* mlp_w    = (const float*)d_in[10];
    const float* mlp_b    = (const float*)d_in[11];
    const float* bnp_g    = (const float*)d_in[12];
    const float* bnp_b    = (const float*)d_in[13];

    float* ws    = (float*)d_ws;
    ushort* fsort  = (ushort*)(ws + OFF_BUFA);           // dead after k_gather
    ushort* y2b    = (ushort*)(ws + OFF_BUFA);           // conv2 out (reuses fsort region)
    __hip_bfloat16* xb  = (__hip_bfloat16*)(ws + OFF_BUFB);
    __hip_bfloat16* wb1 = (__hip_bfloat16*)(ws + OFF_WB1);
    __hip_bfloat16* wb2 = (__hip_bfloat16*)(ws + OFF_WB2);
    ushort* zg   = (ushort*)(ws + OFF_ZG);
    unsigned* base    = (unsigned*)(ws + OFF_BASE);
    unsigned* aux     = (unsigned*)(ws + OFF_AUX);
    int* cellid       = (int*)(ws + OFF_CELL);
    unsigned* cnt     = (unsigned*)(ws + OFF_CNT);
    float* mean  = ws + OFF_MEAN;
    float* part1 = ws + OFF_PART1;
    float* part2 = ws + OFF_PART2;
    float* scl1  = ws + OFF_SCL1;
    float* sft1  = ws + OFF_SFT1;
    float* scl2  = ws + OFF_SCL2;
    float* sft2  = ws + OFF_SFT2;
    ushort* wmb  = (ushort*)(ws + OFF_WM);
    float* partp = ws + OFF_PARTP;
    float* sclp  = ws + OFF_SCLP;
    float* sftp  = ws + OFF_SFTP;
    float* nrm   = ws + OFF_NORM;

    float* outF  = (float*)d_out;                       // fused output
    float* outV  = (float*)d_out + (size_t)16777216;    // v output region
    ushort* y1b  = (ushort*)outV;                       // y1 bf16 scratch: outV float-slots [0 .. 8.4M)
    ushort* pbuf = (ushort*)(outV + (size_t)8388608);   // pb bf16: outV float-slots [8.4M .. 16.7M)

    hipMemsetAsync(cnt, 0, 262144 * 4, stream);
    hipMemsetAsync(zg, 0, 256, stream);
    hipMemsetAsync(mean, 0, 24 * 4, stream);

    k_coord_mean<<<192, 256, 0, stream>>>(coords, mean);
    k_cellid<<<1024, 256, 0, stream>>>(coords, mean, nrm, cellid, cnt);
    k_scan1<<<256, 256, 0, stream>>>(cnt, base, aux);
    k_scan2<<<1, 256, 0, stream>>>(aux);
    k_scan3<<<1024, 256, 0, stream>>>(base, aux);

    k_wb<<<432, 256, 0, stream>>>(conv1_w, wb1);
    k_wb<<<432, 256, 0, stream>>>(conv2_w, wb2);
    k_wm<<<16, 256, 0, stream>>>(mlp_w, wmb);

    // fused: sort features + point-MLP (pb -> d_out scratch) + BN-p partials
    k_scatfeat<<<4096, 256, 0, stream>>>(features, cellid, base, fsort,
                                         wmb, mlp_b, pbuf, partp);
    k_redbn<<<64, 256, 0, stream>>>(partp, bnp_g, bnp_b, sclp, sftp, 4096);
    k_gather<<<65536, 256, 0, stream>>>(fsort, base, cnt, xb);

    // conv1: xb -> y1b (raw y1 bf16) + partials (DMA halo)
    k_conv_mfma<0><<<512, 512, 0, stream>>>((const ushort*)xb, (const ushort*)wb1, conv1_b,
                                            nullptr, nullptr, y1b, part1, zg);
    k_redbn<<<64, 256, 0, stream>>>(part1, bn1_g, bn1_b, scl1, sft1, 512);

    // conv2: raw y1 + BN1 affine + leaky fused into staging -> y2b + partials
    k_conv_mfma<1><<<512, 512, 0, stream>>>(y1b, (const ushort*)wb2, conv2_b,
                                            scl1, sft1, y2b, part2, zg);
    k_redbn<<<64, 256, 0, stream>>>(part2, bn2_g, bn2_b, scl2, sft2, 512);

    // fuse -> outF (reads pbuf from outV scratch; must run BEFORE k_transpose)
    k_final<<<4096, 256, 0, stream>>>(outF, pbuf, y2b, nrm, scl2, sft2, sclp, sftp);

    // v = leaky(bn2(y2)) -> d_out NCDHW f32 (overwrites y1b + pbuf scratch)
    k_transpose<<<4096, 256, 0, stream>>>(y2b, scl2, sft2, outV);
}

// Round 17
// 357.834 us; speedup vs baseline: 1.1147x; 1.0168x over previous
//
#include <hip/hip_runtime.h>
#include <hip/hip_bf16.h>

#define BB 8
#define CC 64
#define NPTS 32768
#define RR 32
#define RV 32768            // 32^3
#define MTOT (BB*RV)        // 262144
#define EPSV 1e-4f

// ws float offsets
#define OFF_BUFA 0u               // fsort bf16 [0:8.4M) -> y2b bf16
#define OFF_BUFB 16777216u        // xb bf16 (x1 grid)
#define OFF_WB1  25165824u        // 55296 float-slots = 110592 bf16
#define OFF_WB2  25221120u        // 55296
#define OFF_ZG   25276416u        // 64 floats zero guard
#define OFF_BASE 25276480u        // 262144 uint
#define OFF_AUX  25800768u        // 256 uint
#define OFF_CELL 25801024u        // 262144 int
#define OFF_CNT  26063168u        // 262144 uint
#define OFF_MEAN 26325312u        // 24
#define OFF_PART1 26325504u       // 128 x 1024 (using 128 x 512)
#define OFF_PART2 26456576u       // 128 x 1024 (using 128 x 512)
#define OFF_SCL1 26587648u        // 64
#define OFF_SFT1 26587712u        // 64
#define OFF_SCL2 26587776u        // 64
#define OFF_SFT2 26587840u        // 64
#define OFF_WM   26587904u        // 2048 float-slots = 4096 bf16
#define OFF_PARTP 26590208u       // 128 x 4096 floats -> ends 27114496
#define OFF_SCLP 27114496u        // 64
#define OFF_SFTP 27114560u        // 64
#define OFF_NORM 33554432u        // 786432 (survives to k_final)

typedef __attribute__((ext_vector_type(8))) __bf16 bf16x8;
typedef __attribute__((ext_vector_type(8))) unsigned short u16x8;
typedef __attribute__((ext_vector_type(4))) float f32x4;

__device__ __forceinline__ float b2f(ushort u) {
    union { unsigned u; float f; } x; x.u = ((unsigned)u) << 16; return x.f;
}
__device__ __forceinline__ ushort f2b(float f) {
    __hip_bfloat16 h = __float2bfloat16(f);
    return *reinterpret_cast<ushort*>(&h);
}

// 192 blocks: (b*3+axis)*8 + chunk; partial sums via f32 atomics into mean[24]
__global__ void k_coord_mean(const float* __restrict__ coords, float* __restrict__ mean) {
    int ba = blockIdx.x >> 3, ch = blockIdx.x & 7;
    const float* src = coords + (size_t)ba * NPTS + ch * 4096;
    float s = 0.f;
    for (int i = threadIdx.x; i < 4096; i += 256) s += src[i];
    __shared__ float red[256];
    red[threadIdx.x] = s; __syncthreads();
    for (int w = 128; w > 0; w >>= 1) {
        if (threadIdx.x < w) red[threadIdx.x] += red[threadIdx.x + w];
        __syncthreads();
    }
    if (threadIdx.x == 0) atomicAdd(&mean[ba], red[0]);
}

// per point: norm, cell id, count (mean arrives as raw sums; scale by 1/NPTS here)
__global__ void k_cellid(const float* __restrict__ coords, const float* __restrict__ mean,
                         float* __restrict__ norm, int* __restrict__ cellid,
                         unsigned* __restrict__ cnt) {
    int idx = blockIdx.x * 256 + threadIdx.x;      // b*NPTS + n
    int b = idx >> 15, n = idx & (NPTS - 1);
    int flat = 0;
    #pragma unroll
    for (int a = 0; a < 3; ++a) {
        float c = coords[((size_t)(b * 3 + a)) * NPTS + n];
        float nm = (c - mean[b * 3 + a] * (1.0f / NPTS) + 1.0f) * (0.5f * RR);
        nm = fminf(fmaxf(nm, 0.0f), (float)(RR - 1));
        norm[((size_t)(b * 3 + a)) * NPTS + n] = nm;
        flat = flat * RR + (int)rintf(nm);
    }
    int cell = b * RV + flat;
    cellid[idx] = cell;
    atomicAdd(&cnt[cell], 1u);
}

// block-local exclusive scan: 256 blocks x 1024 cells
__global__ void k_scan1(const unsigned* __restrict__ cnt, unsigned* __restrict__ base,
                        unsigned* __restrict__ aux) {
    int tid = threadIdx.x;
    int c0 = blockIdx.x * 1024 + tid * 4;
    unsigned v0 = cnt[c0], v1 = cnt[c0 + 1], v2 = cnt[c0 + 2], v3 = cnt[c0 + 3];
    unsigned tot = v0 + v1 + v2 + v3;
    __shared__ unsigned sc[256];
    sc[tid] = tot; __syncthreads();
    for (int off = 1; off < 256; off <<= 1) {
        unsigned t = (tid >= off) ? sc[tid - off] : 0u;
        __syncthreads();
        sc[tid] += t;
        __syncthreads();
    }
    unsigned excl = sc[tid] - tot;
    base[c0] = excl;
    base[c0 + 1] = excl + v0;
    base[c0 + 2] = excl + v0 + v1;
    base[c0 + 3] = excl + v0 + v1 + v2;
    if (tid == 255) aux[blockIdx.x] = sc[255];
}

__global__ void k_scan2(unsigned* __restrict__ aux) {
    int tid = threadIdx.x;
    unsigned own = aux[tid];
    __shared__ unsigned sc[256];
    sc[tid] = own; __syncthreads();
    for (int off = 1; off < 256; off <<= 1) {
        unsigned t = (tid >= off) ? sc[tid - off] : 0u;
        __syncthreads();
        sc[tid] += t;
        __syncthreads();
    }
    aux[tid] = sc[tid] - own;
}

__global__ void k_scan3(unsigned* __restrict__ base, const unsigned* __restrict__ aux) {
    int i = blockIdx.x * 256 + threadIdx.x;
    base[i] += aux[i >> 10];
}

// fused transpose + feature-sort + point-MLP (MFMA) + BN-p moment partials.
__global__ __launch_bounds__(256) void k_scatfeat(
    const float* __restrict__ feats, const int* __restrict__ cellid,
    unsigned* __restrict__ base, ushort* __restrict__ fsort,
    const ushort* __restrict__ wmb, const float* __restrict__ mbias,
    ushort* __restrict__ pb, float* __restrict__ partp) {
    __shared__ float t[64 * 65];
    __shared__ unsigned spos[64];
    __shared__ float sf[512];
    int b = blockIdx.x >> 9;
    int n0 = (blockIdx.x & 511) * 64;
    int tid = threadIdx.x;
    #pragma unroll
    for (int k = 0; k < 16; ++k) {
        int idx = k * 256 + tid;
        int c = idx >> 6, nl = idx & 63;
        t[c * 65 + nl] = feats[((size_t)(b * 64 + c)) * NPTS + n0 + nl];
    }
    if (tid < 64) {
        int cell = cellid[(b << 15) + n0 + tid];
        spos[tid] = atomicAdd(&base[cell], 1u);
    }
    __syncthreads();
    // scatter sorted bf16 rows
    #pragma unroll
    for (int it = 0; it < 2; ++it) {
        int pl = it * 32 + (tid >> 3);
        int j = tid & 7;
        unsigned pos = spos[pl];
        u16x8 v;
        #pragma unroll
        for (int k = 0; k < 8; ++k) v[k] = f2b(t[(j * 8 + k) * 65 + pl]);
        *reinterpret_cast<u16x8*>(fsort + (((size_t)pos) << 6) + j * 8) = v;
    }
    // MLP: wave w handles points w*16..w*16+15
    int w = tid >> 6, l = tid & 63;
    int nl = l & 15, kg = l >> 4;
    bf16x8 Af[2];
    #pragma unroll
    for (int ks = 0; ks < 2; ++ks) {
        union { u16x8 u; bf16x8 h; } cv;
        #pragma unroll
        for (int j = 0; j < 8; ++j)
            cv.u[j] = f2b(t[(ks * 32 + kg * 8 + j) * 65 + w * 16 + nl]);
        Af[ks] = cv.h;
    }
    f32x4 acc[4];
    #pragma unroll
    for (int cb = 0; cb < 4; ++cb) acc[cb] = (f32x4){0.f, 0.f, 0.f, 0.f};
    #pragma unroll
    for (int ks = 0; ks < 2; ++ks)
        #pragma unroll
        for (int cb = 0; cb < 4; ++cb) {
            bf16x8 Bf = *reinterpret_cast<const bf16x8*>(wmb + (cb * 16 + nl) * 64 + ks * 32 + kg * 8);
            acc[cb] = __builtin_amdgcn_mfma_f32_16x16x32_bf16(Af[ks], Bf, acc[cb], 0, 0, 0);
        }
    float ss[4] = {0.f, 0.f, 0.f, 0.f}, qq[4] = {0.f, 0.f, 0.f, 0.f};
    #pragma unroll
    for (int cb = 0; cb < 4; ++cb) {
        float bsv = mbias[cb * 16 + nl];
        #pragma unroll
        for (int r = 0; r < 4; ++r) {
            float yv = acc[cb][r] + bsv;
            int pt = w * 16 + kg * 4 + r;
            pb[(((size_t)((b << 15) + n0 + pt)) << 6) + cb * 16 + nl] = f2b(yv);
            ss[cb] += yv; qq[cb] += yv * yv;
        }
    }
    #pragma unroll
    for (int cb = 0; cb < 4; ++cb) {
        ss[cb] += __shfl_xor(ss[cb], 16); ss[cb] += __shfl_xor(ss[cb], 32);
        qq[cb] += __shfl_xor(qq[cb], 16); qq[cb] += __shfl_xor(qq[cb], 32);
    }
    if (l < 16) {
        #pragma unroll
        for (int cb = 0; cb < 4; ++cb) {
            sf[w * 128 + cb * 16 + nl] = ss[cb];
            sf[w * 128 + 64 + cb * 16 + nl] = qq[cb];
        }
    }
    __syncthreads();
    if (tid < 128)
        partp[(size_t)tid * 4096 + blockIdx.x] =
            sf[tid] + sf[128 + tid] + sf[256 + tid] + sf[384 + tid];
}

// one wave per cell: rows contiguous [start, start+n), unroll x8
__global__ __launch_bounds__(256) void k_gather(
    const ushort* __restrict__ fsort, const unsigned* __restrict__ base,
    const unsigned* __restrict__ cnt, __hip_bfloat16* __restrict__ xb) {
    int cell = blockIdx.x * 4 + (threadIdx.x >> 6);
    int lane = threadIdx.x & 63;
    unsigned n = cnt[cell];
    unsigned start = base[cell] - n;
    const ushort* rows = fsort + (((size_t)start) << 6) + lane;
    float acc = 0.f;
    unsigned i = 0;
    for (; i + 8 <= n; i += 8) {
        float f0 = b2f(rows[((size_t)(i + 0)) << 6]);
        float f1 = b2f(rows[((size_t)(i + 1)) << 6]);
        float f2 = b2f(rows[((size_t)(i + 2)) << 6]);
        float f3 = b2f(rows[((size_t)(i + 3)) << 6]);
        float f4 = b2f(rows[((size_t)(i + 4)) << 6]);
        float f5 = b2f(rows[((size_t)(i + 5)) << 6]);
        float f6 = b2f(rows[((size_t)(i + 6)) << 6]);
        float f7 = b2f(rows[((size_t)(i + 7)) << 6]);
        acc += ((f0 + f1) + (f2 + f3)) + ((f4 + f5) + (f6 + f7));
    }
    for (; i < n; ++i) acc += b2f(rows[((size_t)i) << 6]);
    float inv = (n > 0) ? (1.0f / (float)n) : 0.f;
    xb[((size_t)cell << 6) + lane] = __float2bfloat16(acc * inv);
}

// conv_w (co,ci,kd,kh,kw) -> wb[half][tap][co][ci32] bf16 (ci-split layout)
__global__ void k_wb(const float* __restrict__ w, __hip_bfloat16* __restrict__ wb) {
    int i = blockIdx.x * 256 + threadIdx.x;              // CC*CC*27
    if (i >= CC * CC * 27) return;
    int tap = i % 27, t = i / 27;
    int ci = t & 63, co = t >> 6;
    int half = ci >> 5;
    wb[(((size_t)((half * 27 + tap) * 64 + co)) << 5) + (ci & 31)] = __float2bfloat16(w[i]);
}

// mlp_w (co,ci) f32 -> bf16
__global__ void k_wm(const float* __restrict__ w, ushort* __restrict__ wmb) {
    int i = blockIdx.x * 256 + threadIdx.x;
    if (i < 4096) wmb[i] = f2b(w[i]);
}

// implicit-GEMM conv, ci-split two-pass, both operands in LDS, 2 blocks/CU (4 w/SIMD).
// block: 8x8x8 tile x 64 co, 512 threads; wave = 1 d-slice (mi=4).
// Per ci-half: halo 1000 rows x 64B (62.5KB); weights 2-taphalf double-buffered 2x8KB.
// LDS 80384 B. Swizzle: 4-slot involution (slot ^= row&3), both sides.
// MODE 0: halo via global_load_lds DMA (pre-swizzled source).
// MODE 1: halo reg-staged from raw y1 with BN1 affine + leaky (write-side swizzle).
template<int MODE>
__global__ __launch_bounds__(512, 4) void k_conv_mfma(
    const ushort* __restrict__ src, const ushort* __restrict__ wb,
    const float* __restrict__ bias, const float* __restrict__ scl,
    const float* __restrict__ sft, ushort* __restrict__ y,
    float* __restrict__ part, const ushort* __restrict__ zg) {
    __shared__ __align__(16) char sh[64000 + 16384];     // 80384 B
    char* wsh = sh + 64000;
    int tid = threadIdx.x;
    int lane = tid & 63, wid = tid >> 6;                 // wid in [0,8)
    int tile = ((blockIdx.x & 7) << 6) | (blockIdx.x >> 3);  // XCD-swizzled, 512 blocks
    int twi = tile & 3, thi = (tile >> 2) & 3;
    int tdi = (tile >> 4) & 3, b = tile >> 6;
    int d0 = tdi * 8, h0 = thi * 8, w0 = twi * 8;

    auto stage_wgt = [&](int half, int g) {              // tap-halves 2g,2g+1 (8KB)
        const ushort* wgrp = wb + (((half * 27 + g * 2)) << 11);
        char* wdst = wsh + (g & 1) * 8192;
        int c = (wid << 6) + lane;                       // [0,512)
        int row = c >> 2, off = c & 3;
        const ushort* gsrc = wgrp + (((row << 2) + (off ^ (row & 3))) << 3);
        __builtin_amdgcn_global_load_lds(
            (const __attribute__((address_space(1))) void*)gsrc,
            (__attribute__((address_space(3))) void*)(wdst + (wid << 10)), 16, 0, 0);
    };

    auto stage_halo = [&](int half) {
        float sc8[8], sf8[8];
        if (MODE == 1) {
            int c0 = half * 32 + (lane & 3) * 8;
            #pragma unroll
            for (int j = 0; j < 8; ++j) { sc8[j] = scl[c0 + j]; sf8[j] = sft[c0 + j]; }
        }
        #pragma unroll
        for (int it = 0; it < 8; ++it) {
            int idx = it * 8 + wid;
            int c = (idx << 6) + lane;                   // [0,4096), valid < 4000
            if (c < 4000) {
                int row = c >> 2, off = c & 3;
                int dz = row / 100, rem = row - dz * 100;
                int hz = rem / 10, wz = rem - hz * 10;
                int gd = d0 - 1 + dz, gh = h0 - 1 + hz, gw = w0 - 1 + wz;
                bool inb = ((unsigned)gd < 32u) && ((unsigned)gh < 32u) && ((unsigned)gw < 32u);
                size_t vbase = (((size_t)((b << 15) | (gd << 10) | (gh << 5) | gw)) << 6) + half * 32;
                if (MODE == 0) {
                    int soff = off ^ (row & 3);
                    const ushort* gsrc = inb ? src + vbase + soff * 8 : zg;
                    __builtin_amdgcn_global_load_lds(
                        (const __attribute__((address_space(1))) void*)gsrc,
                        (__attribute__((address_space(3))) void*)(sh + (idx << 10)), 16, 0, 0);
                } else {
                    u16x8 v = {0, 0, 0, 0, 0, 0, 0, 0};
                    if (inb) {
                        v = *reinterpret_cast<const u16x8*>(src + vbase + off * 8);
                        #pragma unroll
                        for (int j = 0; j < 8; ++j) {
                            float f = fmaf(b2f(v[j]), sc8[j], sf8[j]);
                            f = f > 0.f ? f : 0.1f * f;
                            v[j] = f2b(f);
                        }
                    }
                    *reinterpret_cast<u16x8*>(sh + (row << 6) + ((off ^ (row & 3)) << 4)) = v;
                }
            }
        }
    };

    int nl = lane & 15, kg = lane >> 4;                  // kg in [0,4): 8-ci group
    int rbase = wid * 100 + (nl >> 3) * 10 + (nl & 7);

    f32x4 acc[4][4];
    #pragma unroll
    for (int mi = 0; mi < 4; ++mi)
        #pragma unroll
        for (int cb = 0; cb < 4; ++cb) acc[mi][cb] = (f32x4){0.f, 0.f, 0.f, 0.f};

    auto compute = [&](int g) {
        const char* wlds = wsh + (g & 1) * 8192;
        #pragma unroll
        for (int tl = 0; tl < 2; ++tl) {
            int t = g * 2 + tl;
            if (t < 27) {
                int kd = t / 9, rm = t - kd * 9;
                int kh = rm / 3, kw = rm - kh * 3;
                int rt = rbase + kd * 100 + kh * 10 + kw;
                bf16x8 a[4];
                #pragma unroll
                for (int mi = 0; mi < 4; ++mi) {
                    int r = rt + mi * 20;
                    a[mi] = *reinterpret_cast<const bf16x8*>(
                        sh + (r << 6) + ((kg ^ (r & 3)) << 4));
                }
                bf16x8 bf[4];
                #pragma unroll
                for (int cb = 0; cb < 4; ++cb) {
                    int rowb = tl * 64 + cb * 16 + nl;
                    bf[cb] = *reinterpret_cast<const bf16x8*>(
                        wlds + (rowb << 6) + ((kg ^ (rowb & 3)) << 4));
                }
                __builtin_amdgcn_s_setprio(1);
                #pragma unroll
                for (int mi = 0; mi < 4; ++mi)
                    #pragma unroll
                    for (int cb = 0; cb < 4; ++cb)
                        acc[mi][cb] = __builtin_amdgcn_mfma_f32_16x16x32_bf16(
                            a[mi], bf[cb], acc[mi][cb], 0, 0, 0);
                __builtin_amdgcn_s_setprio(0);
            }
        }
    };

    stage_halo(0);
    stage_wgt(0, 0);
    __syncthreads();
    #pragma unroll 1
    for (int g = 0; g < 14; ++g) {
        if (g < 13) stage_wgt(0, g + 1);
        compute(g);
        __syncthreads();
    }
    stage_halo(1);
    stage_wgt(1, 0);
    __syncthreads();
    #pragma unroll 1
    for (int g = 0; g < 14; ++g) {
        if (g < 13) stage_wgt(1, g + 1);
        compute(g);
        __syncthreads();
    }

    int d = d0 + wid;
    float bs[4];
    #pragma unroll
    for (int cb = 0; cb < 4; ++cb) bs[cb] = bias[cb * 16 + nl];
    float ss[4] = {0.f, 0.f, 0.f, 0.f}, qq[4] = {0.f, 0.f, 0.f, 0.f};
    #pragma unroll
    for (int mi = 0; mi < 4; ++mi) {
        int h = h0 + mi * 2 + (kg >> 1);
        int w = w0 + (kg & 1) * 4;
        size_t vox = (size_t)((b << 15) | (d << 10) | (h << 5) | w);
        #pragma unroll
        for (int cb = 0; cb < 4; ++cb) {
            int co = cb * 16 + nl;
            #pragma unroll
            for (int r = 0; r < 4; ++r) {
                float yv = acc[mi][cb][r] + bs[cb];
                y[((vox + r) << 6) + co] = f2b(yv);
                ss[cb] += yv; qq[cb] += yv * yv;
            }
        }
    }
    #pragma unroll
    for (int cb = 0; cb < 4; ++cb) {
        ss[cb] += __shfl_xor(ss[cb], 16); ss[cb] += __shfl_xor(ss[cb], 32);
        qq[cb] += __shfl_xor(qq[cb], 16); qq[cb] += __shfl_xor(qq[cb], 32);
    }
    float* sf2 = (float*)sh;                             // halo dead; reuse
    __syncthreads();
    if (lane < 16) {
        #pragma unroll
        for (int cb = 0; cb < 4; ++cb) {
            sf2[wid * 128 + cb * 16 + nl] = ss[cb];
            sf2[wid * 128 + 64 + cb * 16 + nl] = qq[cb];
        }
    }
    __syncthreads();
    if (tid < 128) {
        float t = sf2[tid] + sf2[128 + tid] + sf2[256 + tid] + sf2[384 + tid]
                + sf2[512 + tid] + sf2[640 + tid] + sf2[768 + tid] + sf2[896 + tid];
        part[tid * 512 + blockIdx.x] = t;
    }
}

// reduce partials -> BN affine (scl, sft). 64 blocks, block = one channel.
__global__ void k_redbn(const float* __restrict__ part, const float* __restrict__ g,
                        const float* __restrict__ bb, float* __restrict__ scl,
                        float* __restrict__ sft, int cnt) {
    int c = blockIdx.x;
    float s = 0.f, q = 0.f;
    for (int i = threadIdx.x; i < cnt; i += 256) {
        s += part[(size_t)c * cnt + i];
        q += part[(size_t)(64 + c) * cnt + i];
    }
    __shared__ float rs[256], rq[256];
    rs[threadIdx.x] = s; rq[threadIdx.x] = q; __syncthreads();
    for (int w = 128; w > 0; w >>= 1) {
        if (threadIdx.x < w) { rs[threadIdx.x] += rs[threadIdx.x + w]; rq[threadIdx.x] += rq[threadIdx.x + w]; }
        __syncthreads();
    }
    if (threadIdx.x == 0) {
        float mu = rs[0] * (1.0f / MTOT);
        float var = rq[0] * (1.0f / MTOT) - mu * mu;
        float sc = g[c] * rsqrtf(var + EPSV);
        scl[c] = sc; sft[c] = bb[c] - mu * sc;
    }
}

// y2 bf16 NDHWC -> v f32 NCDHW with BN2 affine + leaky fused
__global__ void k_transpose(const ushort* __restrict__ in, const float* __restrict__ scl,
                            const float* __restrict__ sft, float* __restrict__ out) {
    __shared__ float t[64 * 65];
    size_t base = (size_t)blockIdx.x * 4096;
    int gv0 = blockIdx.x * 64;
    int b = gv0 >> 15;
    int vox0 = gv0 & 32767;
    int chl = threadIdx.x & 63;
    float sc = scl[chl], sf = sft[chl];
    #pragma unroll
    for (int k = 0; k < 16; ++k) {
        int idx = k * 256 + threadIdx.x;
        float v = fmaf(b2f(in[base + idx]), sc, sf);
        t[(idx >> 6) * 65 + (idx & 63)] = v > 0.f ? v : 0.1f * v;
    }
    __syncthreads();
    #pragma unroll
    for (int k = 0; k < 16; ++k) {
        int idx = k * 256 + threadIdx.x;
        int ch = idx >> 6, voxl = idx & 63;
        out[((size_t)(b * 64 + ch)) * RV + vox0 + voxl] = t[voxl * 65 + ch];
    }
}

// fused: phase1 per point = trilinear(y2 bf16 w/ BN2+leaky) + leaky(BNp(pb)); phase2 coalesced write.
__global__ __launch_bounds__(256) void k_final(
    float* __restrict__ out, const ushort* __restrict__ pbuf,
    const ushort* __restrict__ vraw, const float* __restrict__ norm,
    const float* __restrict__ scl, const float* __restrict__ sft,
    const float* __restrict__ sclp, const float* __restrict__ sftp) {
    __shared__ float smp[64 * 65];
    int b = blockIdx.x >> 9;                 // 512 tiles per batch
    int n0 = (blockIdx.x & 511) * 64;
    int wid = threadIdx.x >> 6, lane = threadIdx.x & 63;
    const ushort* gb = vraw + (((size_t)b) << 15) * CC;
    const float* nrm0 = norm + ((size_t)(b * 3)) * NPTS;
    float sc = scl[lane], sf = sft[lane];
    float scp = sclp[lane], sfp = sftp[lane];

    #pragma unroll 2
    for (int i = 0; i < 16; ++i) {
        int pl = wid * 16 + i;
        int n = n0 + pl;
        float v0 = nrm0[n];
        float v1 = nrm0[NPTS + n];
        float v2 = nrm0[2 * NPTS + n];
        int lx = (int)floorf(v0), ly = (int)floorf(v1), lz = (int)floorf(v2);
        float fx = v0 - (float)lx, fy = v1 - (float)ly, fz = v2 - (float)lz;
        int hx = min(lx + 1, 31), hy = min(ly + 1, 31), hz = min(lz + 1, 31);
        float gx = 1.f - fx, gy = 1.f - fy, gz = 1.f - fz;

        int i000 = ((lx * 32 + ly) * 32 + lz) << 6;
        int i001 = ((lx * 32 + ly) * 32 + hz) << 6;
        int i010 = ((lx * 32 + hy) * 32 + lz) << 6;
        int i011 = ((lx * 32 + hy) * 32 + hz) << 6;
        int i100 = ((hx * 32 + ly) * 32 + lz) << 6;
        int i101 = ((hx * 32 + ly) * 32 + hz) << 6;
        int i110 = ((hx * 32 + hy) * 32 + lz) << 6;
        int i111 = ((hx * 32 + hy) * 32 + hz) << 6;

        float w000 = gx * gy * gz, w001 = gx * gy * fz;
        float w010 = gx * fy * gz, w011 = gx * fy * fz;
        float w100 = fx * gy * gz, w101 = fx * gy * fz;
        float w110 = fx * fy * gz, w111 = fx * fy * fz;

        float r0 = fmaf(b2f(gb[i000 + lane]), sc, sf); r0 = r0 > 0.f ? r0 : 0.1f * r0;
        float r1 = fmaf(b2f(gb[i001 + lane]), sc, sf); r1 = r1 > 0.f ? r1 : 0.1f * r1;
        float r2 = fmaf(b2f(gb[i010 + lane]), sc, sf); r2 = r2 > 0.f ? r2 : 0.1f * r2;
        float r3 = fmaf(b2f(gb[i011 + lane]), sc, sf); r3 = r3 > 0.f ? r3 : 0.1f * r3;
        float r4 = fmaf(b2f(gb[i100 + lane]), sc, sf); r4 = r4 > 0.f ? r4 : 0.1f * r4;
        float r5 = fmaf(b2f(gb[i101 + lane]), sc, sf); r5 = r5 > 0.f ? r5 : 0.1f * r5;
        float r6 = fmaf(b2f(gb[i110 + lane]), sc, sf); r6 = r6 > 0.f ? r6 : 0.1f * r6;
        float r7 = fmaf(b2f(gb[i111 + lane]), sc, sf); r7 = r7 > 0.f ? r7 : 0.1f * r7;

        float s = r0 * w000 + r1 * w001 + r2 * w010 + r3 * w011
                + r4 * w100 + r5 * w101 + r6 * w110 + r7 * w111;

        float pv = fmaf(b2f(pbuf[(((size_t)((b << 15) + n)) << 6) + lane]), scp, sfp);
        pv = pv > 0.f ? pv : 0.1f * pv;
        smp[pl * 65 + lane] = s + pv;
    }
    __syncthreads();

    #pragma unroll 4
    for (int i = 0; i < 16; ++i) {
        int co = i * 4 + wid;
        out[((size_t)(b * 64 + co)) * NPTS + n0 + lane] = smp[lane * 65 + co];
    }
}

extern "C" void kernel_launch(void* const* d_in, const int* in_sizes, int n_in,
                              void* d_out, int out_size, void* d_ws, size_t ws_size,
                              hipStream_t stream) {
    const float* features = (const float*)d_in[0];
    const float* coords   = (const float*)d_in[1];
    const float* conv1_w  = (const float*)d_in[2];
    const float* conv1_b  = (const float*)d_in[3];
    const float* bn1_g    = (const float*)d_in[4];
    const float* bn1_b    = (const float*)d_in[5];
    const float* conv2_w  = (const float*)d_in[6];
    const float* conv2_b  = (const float*)d_in[7];
    const float* bn2_g    = (const float*)d_in[8];
    const float* bn2_b    = (const float*)d_in[9];
    const float* mlp_w    = (const float*)d_in[10];
    const float* mlp_b    = (const float*)d_in[11];
    const float* bnp_g    = (const float*)d_in[12];
    const float* bnp_b    = (const float*)d_in[13];

    float* ws    = (float*)d_ws;
    ushort* fsort  = (ushort*)(ws + OFF_BUFA);           // dead after k_gather
    ushort* y2b    = (ushort*)(ws + OFF_BUFA);           // conv2 out (reuses fsort region)
    __hip_bfloat16* xb  = (__hip_bfloat16*)(ws + OFF_BUFB);
    __hip_bfloat16* wb1 = (__hip_bfloat16*)(ws + OFF_WB1);
    __hip_bfloat16* wb2 = (__hip_bfloat16*)(ws + OFF_WB2);
    ushort* zg   = (ushort*)(ws + OFF_ZG);
    unsigned* base    = (unsigned*)(ws + OFF_BASE);
    unsigned* aux     = (unsigned*)(ws + OFF_AUX);
    int* cellid       = (int*)(ws + OFF_CELL);
    unsigned* cnt     = (unsigned*)(ws + OFF_CNT);
    float* mean  = ws + OFF_MEAN;
    float* part1 = ws + OFF_PART1;
    float* part2 = ws + OFF_PART2;
    float* scl1  = ws + OFF_SCL1;
    float* sft1  = ws + OFF_SFT1;
    float* scl2  = ws + OFF_SCL2;
    float* sft2  = ws + OFF_SFT2;
    ushort* wmb  = (ushort*)(ws + OFF_WM);
    float* partp = ws + OFF_PARTP;
    float* sclp  = ws + OFF_SCLP;
    float* sftp  = ws + OFF_SFTP;
    float* nrm   = ws + OFF_NORM;

    float* outF  = (float*)d_out;                       // fused output
    float* outV  = (float*)d_out + (size_t)16777216;    // v output region
    ushort* y1b  = (ushort*)outV;                       // y1 bf16 scratch: outV float-slots [0 .. 8.4M)
    ushort* pbuf = (ushort*)(outV + (size_t)8388608);   // pb bf16: outV float-slots [8.4M .. 16.7M)

    hipMemsetAsync(cnt, 0, 262144 * 4, stream);
    hipMemsetAsync(zg, 0, 256, stream);
    hipMemsetAsync(mean, 0, 24 * 4, stream);

    k_coord_mean<<<192, 256, 0, stream>>>(coords, mean);
    k_cellid<<<1024, 256, 0, stream>>>(coords, mean, nrm, cellid, cnt);
    k_scan1<<<256, 256, 0, stream>>>(cnt, base, aux);
    k_scan2<<<1, 256, 0, stream>>>(aux);
    k_scan3<<<1024, 256, 0, stream>>>(base, aux);

    k_wb<<<432, 256, 0, stream>>>(conv1_w, wb1);
    k_wb<<<432, 256, 0, stream>>>(conv2_w, wb2);
    k_wm<<<16, 256, 0, stream>>>(mlp_w, wmb);

    // fused: sort features + point-MLP (pb -> d_out scratch) + BN-p partials
    k_scatfeat<<<4096, 256, 0, stream>>>(features, cellid, base, fsort,
                                         wmb, mlp_b, pbuf, partp);
    k_redbn<<<64, 256, 0, stream>>>(partp, bnp_g, bnp_b, sclp, sftp, 4096);
    k_gather<<<65536, 256, 0, stream>>>(fsort, base, cnt, xb);

    // conv1: xb -> y1b (raw y1 bf16) + partials (DMA halo)
    k_conv_mfma<0><<<512, 512, 0, stream>>>((const ushort*)xb, (const ushort*)wb1, conv1_b,
                                            nullptr, nullptr, y1b, part1, zg);
    k_redbn<<<64, 256, 0, stream>>>(part1, bn1_g, bn1_b, scl1, sft1, 512);

    // conv2: raw y1 + BN1 affine + leaky fused into staging -> y2b + partials
    k_conv_mfma<1><<<512, 512, 0, stream>>>(y1b, (const ushort*)wb2, conv2_b,
                                            scl1, sft1, y2b, part2, zg);
    k_redbn<<<64, 256, 0, stream>>>(part2, bn2_g, bn2_b, scl2, sft2, 512);

    // fuse -> outF (reads pbuf from outV scratch; must run BEFORE k_transpose)
    k_final<<<4096, 256, 0, stream>>>(outF, pbuf, y2b, nrm, scl2, sft2, sclp, sftp);

    // v = leaky(bn2(y2)) -> d_out NCDHW f32 (overwrites y1b + pbuf scratch)
    k_transpose<<<4096, 256, 0, stream>>>(y2b, scl2, sft2, outV);
}

// Round 18
// 354.059 us; speedup vs baseline: 1.1266x; 1.0107x over previous
//
#include <hip/hip_runtime.h>
#include <hip/hip_bf16.h>

#define BB 8
#define CC 64
#define NPTS 32768
#define RR 32
#define RV 32768            // 32^3
#define MTOT (BB*RV)        // 262144
#define EPSV 1e-4f

// ws float offsets
#define OFF_BUFA 0u               // fsort bf16 [0:8.4M) -> y2b bf16
#define OFF_BUFB 16777216u        // xb bf16 (x1 grid)
#define OFF_WB1  25165824u        // 55296 float-slots = 110592 bf16
#define OFF_WB2  25221120u        // 55296
#define OFF_ZG   25276416u        // 64 floats zero guard
#define OFF_BASE 25276480u        // 262144 uint
#define OFF_AUX  25800768u        // 256 uint
#define OFF_CELL 25801024u        // 262144 int
#define OFF_CNT  26063168u        // 262144 uint
#define OFF_MEAN 26325312u        // 24
#define OFF_PART1 26325504u       // 128 x 1024 (using 128 x 512)
#define OFF_PART2 26456576u       // 128 x 1024 (using 128 x 512)
#define OFF_SCL1 26587648u        // 64
#define OFF_SFT1 26587712u        // 64
#define OFF_SCL2 26587776u        // 64
#define OFF_SFT2 26587840u        // 64
#define OFF_WM   26587904u        // 2048 float-slots = 4096 bf16
#define OFF_PARTP 26590208u       // 128 x 4096 floats -> ends 27114496
#define OFF_SCLP 27114496u        // 64
#define OFF_SFTP 27114560u        // 64
#define OFF_NORM 33554432u        // 786432 (survives to k_final)

typedef __attribute__((ext_vector_type(8))) __bf16 bf16x8;
typedef __attribute__((ext_vector_type(8))) unsigned short u16x8;
typedef __attribute__((ext_vector_type(4))) float f32x4;

__device__ __forceinline__ float b2f(ushort u) {
    union { unsigned u; float f; } x; x.u = ((unsigned)u) << 16; return x.f;
}
__device__ __forceinline__ ushort f2b(float f) {
    __hip_bfloat16 h = __float2bfloat16(f);
    return *reinterpret_cast<ushort*>(&h);
}

// 192 blocks: (b*3+axis)*8 + chunk; partial sums via f32 atomics into mean[24]
__global__ void k_coord_mean(const float* __restrict__ coords, float* __restrict__ mean) {
    int ba = blockIdx.x >> 3, ch = blockIdx.x & 7;
    const float* src = coords + (size_t)ba * NPTS + ch * 4096;
    float s = 0.f;
    for (int i = threadIdx.x; i < 4096; i += 256) s += src[i];
    __shared__ float red[256];
    red[threadIdx.x] = s; __syncthreads();
    for (int w = 128; w > 0; w >>= 1) {
        if (threadIdx.x < w) red[threadIdx.x] += red[threadIdx.x + w];
        __syncthreads();
    }
    if (threadIdx.x == 0) atomicAdd(&mean[ba], red[0]);
}

// per point: norm, cell id, count (mean arrives as raw sums; scale by 1/NPTS here)
__global__ void k_cellid(const float* __restrict__ coords, const float* __restrict__ mean,
                         float* __restrict__ norm, int* __restrict__ cellid,
                         unsigned* __restrict__ cnt) {
    int idx = blockIdx.x * 256 + threadIdx.x;      // b*NPTS + n
    int b = idx >> 15, n = idx & (NPTS - 1);
    int flat = 0;
    #pragma unroll
    for (int a = 0; a < 3; ++a) {
        float c = coords[((size_t)(b * 3 + a)) * NPTS + n];
        float nm = (c - mean[b * 3 + a] * (1.0f / NPTS) + 1.0f) * (0.5f * RR);
        nm = fminf(fmaxf(nm, 0.0f), (float)(RR - 1));
        norm[((size_t)(b * 3 + a)) * NPTS + n] = nm;
        flat = flat * RR + (int)rintf(nm);
    }
    int cell = b * RV + flat;
    cellid[idx] = cell;
    atomicAdd(&cnt[cell], 1u);
}

// block-local exclusive scan: 256 blocks x 1024 cells
__global__ void k_scan1(const unsigned* __restrict__ cnt, unsigned* __restrict__ base,
                        unsigned* __restrict__ aux) {
    int tid = threadIdx.x;
    int c0 = blockIdx.x * 1024 + tid * 4;
    unsigned v0 = cnt[c0], v1 = cnt[c0 + 1], v2 = cnt[c0 + 2], v3 = cnt[c0 + 3];
    unsigned tot = v0 + v1 + v2 + v3;
    __shared__ unsigned sc[256];
    sc[tid] = tot; __syncthreads();
    for (int off = 1; off < 256; off <<= 1) {
        unsigned t = (tid >= off) ? sc[tid - off] : 0u;
        __syncthreads();
        sc[tid] += t;
        __syncthreads();
    }
    unsigned excl = sc[tid] - tot;
    base[c0] = excl;
    base[c0 + 1] = excl + v0;
    base[c0 + 2] = excl + v0 + v1;
    base[c0 + 3] = excl + v0 + v1 + v2;
    if (tid == 255) aux[blockIdx.x] = sc[255];
}

__global__ void k_scan2(unsigned* __restrict__ aux) {
    int tid = threadIdx.x;
    unsigned own = aux[tid];
    __shared__ unsigned sc[256];
    sc[tid] = own; __syncthreads();
    for (int off = 1; off < 256; off <<= 1) {
        unsigned t = (tid >= off) ? sc[tid - off] : 0u;
        __syncthreads();
        sc[tid] += t;
        __syncthreads();
    }
    aux[tid] = sc[tid] - own;
}

__global__ void k_scan3(unsigned* __restrict__ base, const unsigned* __restrict__ aux) {
    int i = blockIdx.x * 256 + threadIdx.x;
    base[i] += aux[i >> 10];
}

// fused transpose + feature-sort + point-MLP (MFMA) + BN-p moment partials.
__global__ __launch_bounds__(256) void k_scatfeat(
    const float* __restrict__ feats, const int* __restrict__ cellid,
    unsigned* __restrict__ base, ushort* __restrict__ fsort,
    const ushort* __restrict__ wmb, const float* __restrict__ mbias,
    ushort* __restrict__ pb, float* __restrict__ partp) {
    __shared__ float t[64 * 65];
    __shared__ unsigned spos[64];
    __shared__ float sf[512];
    int b = blockIdx.x >> 9;
    int n0 = (blockIdx.x & 511) * 64;
    int tid = threadIdx.x;
    // phase 1: 1024 float4 loads (G13), 4 per thread
    #pragma unroll
    for (int k = 0; k < 4; ++k) {
        int li = k * 256 + tid;                          // [0,1024)
        int c = li >> 4, n4 = (li & 15) * 4;
        float4 v = *reinterpret_cast<const float4*>(
            &feats[((size_t)(b * 64 + c)) * NPTS + n0 + n4]);
        t[c * 65 + n4 + 0] = v.x;
        t[c * 65 + n4 + 1] = v.y;
        t[c * 65 + n4 + 2] = v.z;
        t[c * 65 + n4 + 3] = v.w;
    }
    if (tid < 64) {
        int cell = cellid[(b << 15) + n0 + tid];
        spos[tid] = atomicAdd(&base[cell], 1u);
    }
    __syncthreads();
    // scatter sorted bf16 rows
    #pragma unroll
    for (int it = 0; it < 2; ++it) {
        int pl = it * 32 + (tid >> 3);
        int j = tid & 7;
        unsigned pos = spos[pl];
        u16x8 v;
        #pragma unroll
        for (int k = 0; k < 8; ++k) v[k] = f2b(t[(j * 8 + k) * 65 + pl]);
        *reinterpret_cast<u16x8*>(fsort + (((size_t)pos) << 6) + j * 8) = v;
    }
    // MLP: wave w handles points w*16..w*16+15
    int w = tid >> 6, l = tid & 63;
    int nl = l & 15, kg = l >> 4;
    bf16x8 Af[2];
    #pragma unroll
    for (int ks = 0; ks < 2; ++ks) {
        union { u16x8 u; bf16x8 h; } cv;
        #pragma unroll
        for (int j = 0; j < 8; ++j)
            cv.u[j] = f2b(t[(ks * 32 + kg * 8 + j) * 65 + w * 16 + nl]);
        Af[ks] = cv.h;
    }
    f32x4 acc[4];
    #pragma unroll
    for (int cb = 0; cb < 4; ++cb) acc[cb] = (f32x4){0.f, 0.f, 0.f, 0.f};
    #pragma unroll
    for (int ks = 0; ks < 2; ++ks)
        #pragma unroll
        for (int cb = 0; cb < 4; ++cb) {
            bf16x8 Bf = *reinterpret_cast<const bf16x8*>(wmb + (cb * 16 + nl) * 64 + ks * 32 + kg * 8);
            acc[cb] = __builtin_amdgcn_mfma_f32_16x16x32_bf16(Af[ks], Bf, acc[cb], 0, 0, 0);
        }
    float ss[4] = {0.f, 0.f, 0.f, 0.f}, qq[4] = {0.f, 0.f, 0.f, 0.f};
    #pragma unroll
    for (int cb = 0; cb < 4; ++cb) {
        float bsv = mbias[cb * 16 + nl];
        #pragma unroll
        for (int r = 0; r < 4; ++r) {
            float yv = acc[cb][r] + bsv;
            int pt = w * 16 + kg * 4 + r;
            pb[(((size_t)((b << 15) + n0 + pt)) << 6) + cb * 16 + nl] = f2b(yv);
            ss[cb] += yv; qq[cb] += yv * yv;
        }
    }
    #pragma unroll
    for (int cb = 0; cb < 4; ++cb) {
        ss[cb] += __shfl_xor(ss[cb], 16); ss[cb] += __shfl_xor(ss[cb], 32);
        qq[cb] += __shfl_xor(qq[cb], 16); qq[cb] += __shfl_xor(qq[cb], 32);
    }
    if (l < 16) {
        #pragma unroll
        for (int cb = 0; cb < 4; ++cb) {
            sf[w * 128 + cb * 16 + nl] = ss[cb];
            sf[w * 128 + 64 + cb * 16 + nl] = qq[cb];
        }
    }
    __syncthreads();
    if (tid < 128)
        partp[(size_t)tid * 4096 + blockIdx.x] =
            sf[tid] + sf[128 + tid] + sf[256 + tid] + sf[384 + tid];
}

// one wave per cell: rows contiguous [start, start+n), unroll x8
__global__ __launch_bounds__(256) void k_gather(
    const ushort* __restrict__ fsort, const unsigned* __restrict__ base,
    const unsigned* __restrict__ cnt, __hip_bfloat16* __restrict__ xb) {
    int cell = blockIdx.x * 4 + (threadIdx.x >> 6);
    int lane = threadIdx.x & 63;
    unsigned n = cnt[cell];
    unsigned start = base[cell] - n;
    const ushort* rows = fsort + (((size_t)start) << 6) + lane;
    float acc = 0.f;
    unsigned i = 0;
    for (; i + 8 <= n; i += 8) {
        float f0 = b2f(rows[((size_t)(i + 0)) << 6]);
        float f1 = b2f(rows[((size_t)(i + 1)) << 6]);
        float f2 = b2f(rows[((size_t)(i + 2)) << 6]);
        float f3 = b2f(rows[((size_t)(i + 3)) << 6]);
        float f4 = b2f(rows[((size_t)(i + 4)) << 6]);
        float f5 = b2f(rows[((size_t)(i + 5)) << 6]);
        float f6 = b2f(rows[((size_t)(i + 6)) << 6]);
        float f7 = b2f(rows[((size_t)(i + 7)) << 6]);
        acc += ((f0 + f1) + (f2 + f3)) + ((f4 + f5) + (f6 + f7));
    }
    for (; i < n; ++i) acc += b2f(rows[((size_t)i) << 6]);
    float inv = (n > 0) ? (1.0f / (float)n) : 0.f;
    xb[((size_t)cell << 6) + lane] = __float2bfloat16(acc * inv);
}

// conv_w (co,ci,kd,kh,kw) -> wb[half][tap][co][ci32] bf16 (ci-split layout)
__global__ void k_wb(const float* __restrict__ w, __hip_bfloat16* __restrict__ wb) {
    int i = blockIdx.x * 256 + threadIdx.x;              // CC*CC*27
    if (i >= CC * CC * 27) return;
    int tap = i % 27, t = i / 27;
    int ci = t & 63, co = t >> 6;
    int half = ci >> 5;
    wb[(((size_t)((half * 27 + tap) * 64 + co)) << 5) + (ci & 31)] = __float2bfloat16(w[i]);
}

// mlp_w (co,ci) f32 -> bf16
__global__ void k_wm(const float* __restrict__ w, ushort* __restrict__ wmb) {
    int i = blockIdx.x * 256 + threadIdx.x;
    if (i < 4096) wmb[i] = f2b(w[i]);
}

// implicit-GEMM conv, ci-split two-pass, both operands in LDS, 2 blocks/CU (4 w/SIMD).
// block: 8x8x8 tile x 64 co, 512 threads; wave = 1 d-slice (mi=4).
// Per ci-half: halo 1000 rows x 64B (62.5KB); weights 2-taphalf double-buffered 2x8KB.
// LDS 80384 B. Swizzle: 4-slot involution (slot ^= row&3), both sides.
// MODE 0: halo via global_load_lds DMA (pre-swizzled source).
// MODE 1: halo reg-staged from raw y1 with BN1 affine + leaky (write-side swizzle).
template<int MODE>
__global__ __launch_bounds__(512, 4) void k_conv_mfma(
    const ushort* __restrict__ src, const ushort* __restrict__ wb,
    const float* __restrict__ bias, const float* __restrict__ scl,
    const float* __restrict__ sft, ushort* __restrict__ y,
    float* __restrict__ part, const ushort* __restrict__ zg) {
    __shared__ __align__(16) char sh[64000 + 16384];     // 80384 B
    char* wsh = sh + 64000;
    int tid = threadIdx.x;
    int lane = tid & 63, wid = tid >> 6;                 // wid in [0,8)
    int tile = ((blockIdx.x & 7) << 6) | (blockIdx.x >> 3);  // XCD-swizzled, 512 blocks
    int twi = tile & 3, thi = (tile >> 2) & 3;
    int tdi = (tile >> 4) & 3, b = tile >> 6;
    int d0 = tdi * 8, h0 = thi * 8, w0 = twi * 8;

    auto stage_wgt = [&](int half, int g) {              // tap-halves 2g,2g+1 (8KB)
        const ushort* wgrp = wb + (((half * 27 + g * 2)) << 11);
        char* wdst = wsh + (g & 1) * 8192;
        int c = (wid << 6) + lane;                       // [0,512)
        int row = c >> 2, off = c & 3;
        const ushort* gsrc = wgrp + (((row << 2) + (off ^ (row & 3))) << 3);
        __builtin_amdgcn_global_load_lds(
            (const __attribute__((address_space(1))) void*)gsrc,
            (__attribute__((address_space(3))) void*)(wdst + (wid << 10)), 16, 0, 0);
    };

    auto stage_halo = [&](int half) {
        float sc8[8], sf8[8];
        if (MODE == 1) {
            int c0 = half * 32 + (lane & 3) * 8;
            #pragma unroll
            for (int j = 0; j < 8; ++j) { sc8[j] = scl[c0 + j]; sf8[j] = sft[c0 + j]; }
        }
        #pragma unroll
        for (int it = 0; it < 8; ++it) {
            int idx = it * 8 + wid;
            int c = (idx << 6) + lane;                   // [0,4096), valid < 4000
            if (c < 4000) {
                int row = c >> 2, off = c & 3;
                int dz = row / 100, rem = row - dz * 100;
                int hz = rem / 10, wz = rem - hz * 10;
                int gd = d0 - 1 + dz, gh = h0 - 1 + hz, gw = w0 - 1 + wz;
                bool inb = ((unsigned)gd < 32u) && ((unsigned)gh < 32u) && ((unsigned)gw < 32u);
                size_t vbase = (((size_t)((b << 15) | (gd << 10) | (gh << 5) | gw)) << 6) + half * 32;
                if (MODE == 0) {
                    int soff = off ^ (row & 3);
                    const ushort* gsrc = inb ? src + vbase + soff * 8 : zg;
                    __builtin_amdgcn_global_load_lds(
                        (const __attribute__((address_space(1))) void*)gsrc,
                        (__attribute__((address_space(3))) void*)(sh + (idx << 10)), 16, 0, 0);
                } else {
                    u16x8 v = {0, 0, 0, 0, 0, 0, 0, 0};
                    if (inb) {
                        v = *reinterpret_cast<const u16x8*>(src + vbase + off * 8);
                        #pragma unroll
                        for (int j = 0; j < 8; ++j) {
                            float f = fmaf(b2f(v[j]), sc8[j], sf8[j]);
                            f = f > 0.f ? f : 0.1f * f;
                            v[j] = f2b(f);
                        }
                    }
                    *reinterpret_cast<u16x8*>(sh + (row << 6) + ((off ^ (row & 3)) << 4)) = v;
                }
            }
        }
    };

    int nl = lane & 15, kg = lane >> 4;                  // kg in [0,4): 8-ci group
    int rbase = wid * 100 + (nl >> 3) * 10 + (nl & 7);

    f32x4 acc[4][4];
    #pragma unroll
    for (int mi = 0; mi < 4; ++mi)
        #pragma unroll
        for (int cb = 0; cb < 4; ++cb) acc[mi][cb] = (f32x4){0.f, 0.f, 0.f, 0.f};

    auto compute = [&](int g) {
        const char* wlds = wsh + (g & 1) * 8192;
        #pragma unroll
        for (int tl = 0; tl < 2; ++tl) {
            int t = g * 2 + tl;
            if (t < 27) {
                int kd = t / 9, rm = t - kd * 9;
                int kh = rm / 3, kw = rm - kh * 3;
                int rt = rbase + kd * 100 + kh * 10 + kw;
                bf16x8 a[4];
                #pragma unroll
                for (int mi = 0; mi < 4; ++mi) {
                    int r = rt + mi * 20;
                    a[mi] = *reinterpret_cast<const bf16x8*>(
                        sh + (r << 6) + ((kg ^ (r & 3)) << 4));
                }
                bf16x8 bf[4];
                #pragma unroll
                for (int cb = 0; cb < 4; ++cb) {
                    int rowb = tl * 64 + cb * 16 + nl;
                    bf[cb] = *reinterpret_cast<const bf16x8*>(
                        wlds + (rowb << 6) + ((kg ^ (rowb & 3)) << 4));
                }
                __builtin_amdgcn_s_setprio(1);
                #pragma unroll
                for (int mi = 0; mi < 4; ++mi)
                    #pragma unroll
                    for (int cb = 0; cb < 4; ++cb)
                        acc[mi][cb] = __builtin_amdgcn_mfma_f32_16x16x32_bf16(
                            a[mi], bf[cb], acc[mi][cb], 0, 0, 0);
                __builtin_amdgcn_s_setprio(0);
            }
        }
    };

    stage_halo(0);
    stage_wgt(0, 0);
    __syncthreads();
    #pragma unroll 1
    for (int g = 0; g < 14; ++g) {
        if (g < 13) stage_wgt(0, g + 1);
        compute(g);
        __syncthreads();
    }
    stage_halo(1);
    stage_wgt(1, 0);
    __syncthreads();
    #pragma unroll 1
    for (int g = 0; g < 14; ++g) {
        if (g < 13) stage_wgt(1, g + 1);
        compute(g);
        __syncthreads();
    }

    int d = d0 + wid;
    float bs[4];
    #pragma unroll
    for (int cb = 0; cb < 4; ++cb) bs[cb] = bias[cb * 16 + nl];
    float ss[4] = {0.f, 0.f, 0.f, 0.f}, qq[4] = {0.f, 0.f, 0.f, 0.f};
    #pragma unroll
    for (int mi = 0; mi < 4; ++mi) {
        int h = h0 + mi * 2 + (kg >> 1);
        int w = w0 + (kg & 1) * 4;
        size_t vox = (size_t)((b << 15) | (d << 10) | (h << 5) | w);
        #pragma unroll
        for (int cb = 0; cb < 4; ++cb) {
            int co = cb * 16 + nl;
            #pragma unroll
            for (int r = 0; r < 4; ++r) {
                float yv = acc[mi][cb][r] + bs[cb];
                y[((vox + r) << 6) + co] = f2b(yv);
                ss[cb] += yv; qq[cb] += yv * yv;
            }
        }
    }
    #pragma unroll
    for (int cb = 0; cb < 4; ++cb) {
        ss[cb] += __shfl_xor(ss[cb], 16); ss[cb] += __shfl_xor(ss[cb], 32);
        qq[cb] += __shfl_xor(qq[cb], 16); qq[cb] += __shfl_xor(qq[cb], 32);
    }
    float* sf2 = (float*)sh;                             // halo dead; reuse
    __syncthreads();
    if (lane < 16) {
        #pragma unroll
        for (int cb = 0; cb < 4; ++cb) {
            sf2[wid * 128 + cb * 16 + nl] = ss[cb];
            sf2[wid * 128 + 64 + cb * 16 + nl] = qq[cb];
        }
    }
    __syncthreads();
    if (tid < 128) {
        float t = sf2[tid] + sf2[128 + tid] + sf2[256 + tid] + sf2[384 + tid]
                + sf2[512 + tid] + sf2[640 + tid] + sf2[768 + tid] + sf2[896 + tid];
        part[tid * 512 + blockIdx.x] = t;
    }
}

// reduce partials -> BN affine (scl, sft). 64 blocks, block = one channel.
__global__ void k_redbn(const float* __restrict__ part, const float* __restrict__ g,
                        const float* __restrict__ bb, float* __restrict__ scl,
                        float* __restrict__ sft, int cnt) {
    int c = blockIdx.x;
    float s = 0.f, q = 0.f;
    for (int i = threadIdx.x; i < cnt; i += 256) {
        s += part[(size_t)c * cnt + i];
        q += part[(size_t)(64 + c) * cnt + i];
    }
    __shared__ float rs[256], rq[256];
    rs[threadIdx.x] = s; rq[threadIdx.x] = q; __syncthreads();
    for (int w = 128; w > 0; w >>= 1) {
        if (threadIdx.x < w) { rs[threadIdx.x] += rs[threadIdx.x + w]; rq[threadIdx.x] += rq[threadIdx.x + w]; }
        __syncthreads();
    }
    if (threadIdx.x == 0) {
        float mu = rs[0] * (1.0f / MTOT);
        float var = rq[0] * (1.0f / MTOT) - mu * mu;
        float sc = g[c] * rsqrtf(var + EPSV);
        scl[c] = sc; sft[c] = bb[c] - mu * sc;
    }
}

// y2 bf16 NDHWC -> v f32 NCDHW with BN2 affine + leaky fused.
// phase 1: vectorized u16x8 loads (raw bf16 -> LDS f32); phase 2: affine+leaky + float4 writes.
__global__ void k_transpose(const ushort* __restrict__ in, const float* __restrict__ scl,
                            const float* __restrict__ sft, float* __restrict__ out) {
    __shared__ float t[64 * 65];
    size_t base = (size_t)blockIdx.x * 4096;
    int gv0 = blockIdx.x * 64;
    int b = gv0 >> 15;
    int vox0 = gv0 & 32767;
    int tid = threadIdx.x;
    #pragma unroll
    for (int k = 0; k < 2; ++k) {
        int li = k * 256 + tid;                          // [0,512)
        int vox = li >> 3, c0 = (li & 7) * 8;
        u16x8 v = *reinterpret_cast<const u16x8*>(in + base + vox * 64 + c0);
        #pragma unroll
        for (int j = 0; j < 8; ++j)
            t[(c0 + j) * 65 + vox] = b2f(v[j]);
    }
    __syncthreads();
    #pragma unroll
    for (int k = 0; k < 4; ++k) {
        int li = k * 256 + tid;                          // [0,1024)
        int ch = li >> 4, v4 = (li & 15) * 4;
        float sc = scl[ch], sf = sft[ch];
        float4 o;
        float a0 = fmaf(t[ch * 65 + v4 + 0], sc, sf); o.x = a0 > 0.f ? a0 : 0.1f * a0;
        float a1 = fmaf(t[ch * 65 + v4 + 1], sc, sf); o.y = a1 > 0.f ? a1 : 0.1f * a1;
        float a2 = fmaf(t[ch * 65 + v4 + 2], sc, sf); o.z = a2 > 0.f ? a2 : 0.1f * a2;
        float a3 = fmaf(t[ch * 65 + v4 + 3], sc, sf); o.w = a3 > 0.f ? a3 : 0.1f * a3;
        *reinterpret_cast<float4*>(&out[((size_t)(b * 64 + ch)) * RV + vox0 + v4]) = o;
    }
}

// fused: phase1 per point = trilinear(y2 bf16 w/ BN2+leaky) + leaky(BNp(pb)); phase2 coalesced write.
__global__ __launch_bounds__(256) void k_final(
    float* __restrict__ out, const ushort* __restrict__ pbuf,
    const ushort* __restrict__ vraw, const float* __restrict__ norm,
    const float* __restrict__ scl, const float* __restrict__ sft,
    const float* __restrict__ sclp, const float* __restrict__ sftp) {
    __shared__ float smp[64 * 65];
    int b = blockIdx.x >> 9;                 // 512 tiles per batch
    int n0 = (blockIdx.x & 511) * 64;
    int wid = threadIdx.x >> 6, lane = threadIdx.x & 63;
    const ushort* gb = vraw + (((size_t)b) << 15) * CC;
    const float* nrm0 = norm + ((size_t)(b * 3)) * NPTS;
    float sc = scl[lane], sf = sft[lane];
    float scp = sclp[lane], sfp = sftp[lane];

    #pragma unroll 2
    for (int i = 0; i < 16; ++i) {
        int pl = wid * 16 + i;
        int n = n0 + pl;
        float v0 = nrm0[n];
        float v1 = nrm0[NPTS + n];
        float v2 = nrm0[2 * NPTS + n];
        int lx = (int)floorf(v0), ly = (int)floorf(v1), lz = (int)floorf(v2);
        float fx = v0 - (float)lx, fy = v1 - (float)ly, fz = v2 - (float)lz;
        int hx = min(lx + 1, 31), hy = min(ly + 1, 31), hz = min(lz + 1, 31);
        float gx = 1.f - fx, gy = 1.f - fy, gz = 1.f - fz;

        int i000 = ((lx * 32 + ly) * 32 + lz) << 6;
        int i001 = ((lx * 32 + ly) * 32 + hz) << 6;
        int i010 = ((lx * 32 + hy) * 32 + lz) << 6;
        int i011 = ((lx * 32 + hy) * 32 + hz) << 6;
        int i100 = ((hx * 32 + ly) * 32 + lz) << 6;
        int i101 = ((hx * 32 + ly) * 32 + hz) << 6;
        int i110 = ((hx * 32 + hy) * 32 + lz) << 6;
        int i111 = ((hx * 32 + hy) * 32 + hz) << 6;

        float w000 = gx * gy * gz, w001 = gx * gy * fz;
        float w010 = gx * fy * gz, w011 = gx * fy * fz;
        float w100 = fx * gy * gz, w101 = fx * gy * fz;
        float w110 = fx * fy * gz, w111 = fx * fy * fz;

        float r0 = fmaf(b2f(gb[i000 + lane]), sc, sf); r0 = r0 > 0.f ? r0 : 0.1f * r0;
        float r1 = fmaf(b2f(gb[i001 + lane]), sc, sf); r1 = r1 > 0.f ? r1 : 0.1f * r1;
        float r2 = fmaf(b2f(gb[i010 + lane]), sc, sf); r2 = r2 > 0.f ? r2 : 0.1f * r2;
        float r3 = fmaf(b2f(gb[i011 + lane]), sc, sf); r3 = r3 > 0.f ? r3 : 0.1f * r3;
        float r4 = fmaf(b2f(gb[i100 + lane]), sc, sf); r4 = r4 > 0.f ? r4 : 0.1f * r4;
        float r5 = fmaf(b2f(gb[i101 + lane]), sc, sf); r5 = r5 > 0.f ? r5 : 0.1f * r5;
        float r6 = fmaf(b2f(gb[i110 + lane]), sc, sf); r6 = r6 > 0.f ? r6 : 0.1f * r6;
        float r7 = fmaf(b2f(gb[i111 + lane]), sc, sf); r7 = r7 > 0.f ? r7 : 0.1f * r7;

        float s = r0 * w000 + r1 * w001 + r2 * w010 + r3 * w011
                + r4 * w100 + r5 * w101 + r6 * w110 + r7 * w111;

        float pv = fmaf(b2f(pbuf[(((size_t)((b << 15) + n)) << 6) + lane]), scp, sfp);
        pv = pv > 0.f ? pv : 0.1f * pv;
        smp[pl * 65 + lane] = s + pv;
    }
    __syncthreads();

    #pragma unroll 4
    for (int i = 0; i < 16; ++i) {
        int co = i * 4 + wid;
        out[((size_t)(b * 64 + co)) * NPTS + n0 + lane] = smp[lane * 65 + co];
    }
}

extern "C" void kernel_launch(void* const* d_in, const int* in_sizes, int n_in,
                              void* d_out, int out_size, void* d_ws, size_t ws_size,
                              hipStream_t stream) {
    const float* features = (const float*)d_in[0];
    const float* coords   = (const float*)d_in[1];
    const float* conv1_w  = (const float*)d_in[2];
    const float* conv1_b  = (const float*)d_in[3];
    const float* bn1_g    = (const float*)d_in[4];
    const float* bn1_b    = (const float*)d_in[5];
    const float* conv2_w  = (const float*)d_in[6];
    const float* conv2_b  = (const float*)d_in[7];
    const float* bn2_g    = (const float*)d_in[8];
    const float* bn2_b    = (const float*)d_in[9];
    const float* mlp_w    = (const float*)d_in[10];
    const float* mlp_b    = (const float*)d_in[11];
    const float* bnp_g    = (const float*)d_in[12];
    const float* bnp_b    = (const float*)d_in[13];

    float* ws    = (float*)d_ws;
    ushort* fsort  = (ushort*)(ws + OFF_BUFA);           // dead after k_gather
    ushort* y2b    = (ushort*)(ws + OFF_BUFA);           // conv2 out (reuses fsort region)
    __hip_bfloat16* xb  = (__hip_bfloat16*)(ws + OFF_BUFB);
    __hip_bfloat16* wb1 = (__hip_bfloat16*)(ws + OFF_WB1);
    __hip_bfloat16* wb2 = (__hip_bfloat16*)(ws + OFF_WB2);
    ushort* zg   = (ushort*)(ws + OFF_ZG);
    unsigned* base    = (unsigned*)(ws + OFF_BASE);
    unsigned* aux     = (unsigned*)(ws + OFF_AUX);
    int* cellid       = (int*)(ws + OFF_CELL);
    unsigned* cnt     = (unsigned*)(ws + OFF_CNT);
    float* mean  = ws + OFF_MEAN;
    float* part1 = ws + OFF_PART1;
    float* part2 = ws + OFF_PART2;
    float* scl1  = ws + OFF_SCL1;
    float* sft1  = ws + OFF_SFT1;
    float* scl2  = ws + OFF_SCL2;
    float* sft2  = ws + OFF_SFT2;
    ushort* wmb  = (ushort*)(ws + OFF_WM);
    float* partp = ws + OFF_PARTP;
    float* sclp  = ws + OFF_SCLP;
    float* sftp  = ws + OFF_SFTP;
    float* nrm   = ws + OFF_NORM;

    float* outF  = (float*)d_out;                       // fused output
    float* outV  = (float*)d_out + (size_t)16777216;    // v output region
    ushort* y1b  = (ushort*)outV;                       // y1 bf16 scratch: outV float-slots [0 .. 8.4M)
    ushort* pbuf = (ushort*)(outV + (size_t)8388608);   // pb bf16: outV float-slots [8.4M .. 16.7M)

    hipMemsetAsync(cnt, 0, 262144 * 4, stream);
    hipMemsetAsync(zg, 0, 256, stream);
    hipMemsetAsync(mean, 0, 24 * 4, stream);

    k_coord_mean<<<192, 256, 0, stream>>>(coords, mean);
    k_cellid<<<1024, 256, 0, stream>>>(coords, mean, nrm, cellid, cnt);
    k_scan1<<<256, 256, 0, stream>>>(cnt, base, aux);
    k_scan2<<<1, 256, 0, stream>>>(aux);
    k_scan3<<<1024, 256, 0, stream>>>(base, aux);

    k_wb<<<432, 256, 0, stream>>>(conv1_w, wb1);
    k_wb<<<432, 256, 0, stream>>>(conv2_w, wb2);
    k_wm<<<16, 256, 0, stream>>>(mlp_w, wmb);

    // fused: sort features + point-MLP (pb -> d_out scratch) + BN-p partials
    k_scatfeat<<<4096, 256, 0, stream>>>(features, cellid, base, fsort,
                                         wmb, mlp_b, pbuf, partp);
    k_redbn<<<64, 256, 0, stream>>>(partp, bnp_g, bnp_b, sclp, sftp, 4096);
    k_gather<<<65536, 256, 0, stream>>>(fsort, base, cnt, xb);

    // conv1: xb -> y1b (raw y1 bf16) + partials (DMA halo)
    k_conv_mfma<0><<<512, 512, 0, stream>>>((const ushort*)xb, (const ushort*)wb1, conv1_b,
                                            nullptr, nullptr, y1b, part1, zg);
    k_redbn<<<64, 256, 0, stream>>>(part1, bn1_g, bn1_b, scl1, sft1, 512);

    // conv2: raw y1 + BN1 affine + leaky fused into staging -> y2b + partials
    k_conv_mfma<1><<<512, 512, 0, stream>>>(y1b, (const ushort*)wb2, conv2_b,
                                            scl1, sft1, y2b, part2, zg);
    k_redbn<<<64, 256, 0, stream>>>(part2, bn2_g, bn2_b, scl2, sft2, 512);

    // fuse -> outF (reads pbuf from outV scratch; must run BEFORE k_transpose)
    k_final<<<4096, 256, 0, stream>>>(outF, pbuf, y2b, nrm, scl2, sft2, sclp, sftp);

    // v = leaky(bn2(y2)) -> d_out NCDHW f32 (overwrites y1b + pbuf scratch)
    k_transpose<<<4096, 256, 0, stream>>>(y2b, scl2, sft2, outV);
}

// Round 19
// 338.747 us; speedup vs baseline: 1.1775x; 1.0452x over previous
//
#include <hip/hip_runtime.h>
#include <hip/hip_bf16.h>

#define BB 8
#define CC 64
#define NPTS 32768
#define RR 32
#define RV 32768            // 32^3
#define MTOT (BB*RV)        // 262144
#define EPSV 1e-4f

// ws float offsets
#define OFF_BUFA 0u               // fsort bf16 [0:8.4M) -> y2b bf16; pbuf bf16 [8.4M:16.7M)
#define OFF_BUFB 16777216u        // xb bf16 (x1 grid)
#define OFF_WB1  25165824u        // 55296 float-slots = 110592 bf16
#define OFF_WB2  25221120u        // 55296
#define OFF_ZG   25276416u        // 64 floats zero guard
#define OFF_BASE 25276480u        // 262144 uint
#define OFF_AUX  25800768u        // 256 uint
#define OFF_CELL 25801024u        // 262144 int
#define OFF_CNT  26063168u        // 262144 uint
#define OFF_MEAN 26325312u        // 24
#define OFF_PART1 26325504u       // 128 x 1024 (using 128 x 512)
#define OFF_PART2 26456576u       // 128 x 1024 (using 128 x 512)
#define OFF_SCL1 26587648u        // 64
#define OFF_SFT1 26587712u        // 64
#define OFF_SCL2 26587776u        // 64
#define OFF_SFT2 26587840u        // 64
#define OFF_WM   26587904u        // 2048 float-slots = 4096 bf16
#define OFF_PARTP 26590208u       // 128 x 4096 floats -> ends 27114496
#define OFF_SCLP 27114496u        // 64
#define OFF_SFTP 27114560u        // 64
#define OFF_NORM 33554432u        // 786432 (survives to epilogue)

typedef __attribute__((ext_vector_type(8))) __bf16 bf16x8;
typedef __attribute__((ext_vector_type(8))) unsigned short u16x8;
typedef __attribute__((ext_vector_type(4))) float f32x4;

__device__ __forceinline__ float b2f(ushort u) {
    union { unsigned u; float f; } x; x.u = ((unsigned)u) << 16; return x.f;
}
__device__ __forceinline__ ushort f2b(float f) {
    __hip_bfloat16 h = __float2bfloat16(f);
    return *reinterpret_cast<ushort*>(&h);
}

// 192 blocks: (b*3+axis)*8 + chunk; partial sums via f32 atomics into mean[24]
__global__ void k_coord_mean(const float* __restrict__ coords, float* __restrict__ mean) {
    int ba = blockIdx.x >> 3, ch = blockIdx.x & 7;
    const float* src = coords + (size_t)ba * NPTS + ch * 4096;
    float s = 0.f;
    for (int i = threadIdx.x; i < 4096; i += 256) s += src[i];
    __shared__ float red[256];
    red[threadIdx.x] = s; __syncthreads();
    for (int w = 128; w > 0; w >>= 1) {
        if (threadIdx.x < w) red[threadIdx.x] += red[threadIdx.x + w];
        __syncthreads();
    }
    if (threadIdx.x == 0) atomicAdd(&mean[ba], red[0]);
}

// per point: norm, cell id, count (mean arrives as raw sums; scale by 1/NPTS here)
__global__ void k_cellid(const float* __restrict__ coords, const float* __restrict__ mean,
                         float* __restrict__ norm, int* __restrict__ cellid,
                         unsigned* __restrict__ cnt) {
    int idx = blockIdx.x * 256 + threadIdx.x;      // b*NPTS + n
    int b = idx >> 15, n = idx & (NPTS - 1);
    int flat = 0;
    #pragma unroll
    for (int a = 0; a < 3; ++a) {
        float c = coords[((size_t)(b * 3 + a)) * NPTS + n];
        float nm = (c - mean[b * 3 + a] * (1.0f / NPTS) + 1.0f) * (0.5f * RR);
        nm = fminf(fmaxf(nm, 0.0f), (float)(RR - 1));
        norm[((size_t)(b * 3 + a)) * NPTS + n] = nm;
        flat = flat * RR + (int)rintf(nm);
    }
    int cell = b * RV + flat;
    cellid[idx] = cell;
    atomicAdd(&cnt[cell], 1u);
}

// block-local exclusive scan: 256 blocks x 1024 cells
__global__ void k_scan1(const unsigned* __restrict__ cnt, unsigned* __restrict__ base,
                        unsigned* __restrict__ aux) {
    int tid = threadIdx.x;
    int c0 = blockIdx.x * 1024 + tid * 4;
    unsigned v0 = cnt[c0], v1 = cnt[c0 + 1], v2 = cnt[c0 + 2], v3 = cnt[c0 + 3];
    unsigned tot = v0 + v1 + v2 + v3;
    __shared__ unsigned sc[256];
    sc[tid] = tot; __syncthreads();
    for (int off = 1; off < 256; off <<= 1) {
        unsigned t = (tid >= off) ? sc[tid - off] : 0u;
        __syncthreads();
        sc[tid] += t;
        __syncthreads();
    }
    unsigned excl = sc[tid] - tot;
    base[c0] = excl;
    base[c0 + 1] = excl + v0;
    base[c0 + 2] = excl + v0 + v1;
    base[c0 + 3] = excl + v0 + v1 + v2;
    if (tid == 255) aux[blockIdx.x] = sc[255];
}

__global__ void k_scan2(unsigned* __restrict__ aux) {
    int tid = threadIdx.x;
    unsigned own = aux[tid];
    __shared__ unsigned sc[256];
    sc[tid] = own; __syncthreads();
    for (int off = 1; off < 256; off <<= 1) {
        unsigned t = (tid >= off) ? sc[tid - off] : 0u;
        __syncthreads();
        sc[tid] += t;
        __syncthreads();
    }
    aux[tid] = sc[tid] - own;
}

// merged weight prep: blocks [0,432) conv1, [432,864) conv2, [864,880) mlp
__global__ void k_prep(const float* __restrict__ w1, const float* __restrict__ w2,
                       const float* __restrict__ wm, __hip_bfloat16* __restrict__ wb1,
                       __hip_bfloat16* __restrict__ wb2, ushort* __restrict__ wmb) {
    int bid = blockIdx.x;
    if (bid < 864) {
        const float* w = (bid < 432) ? w1 : w2;
        __hip_bfloat16* wb = (bid < 432) ? wb1 : wb2;
        int i = (bid % 432) * 256 + threadIdx.x;         // CC*CC*27
        if (i >= CC * CC * 27) return;
        int tap = i % 27, t = i / 27;
        int ci = t & 63, co = t >> 6;
        int half = ci >> 5;
        wb[(((size_t)((half * 27 + tap) * 64 + co)) << 5) + (ci & 31)] = __float2bfloat16(w[i]);
    } else {
        int i = (bid - 864) * 256 + threadIdx.x;
        if (i < 4096) wmb[i] = f2b(wm[i]);
    }
}

// fused transpose + feature-sort + point-MLP (MFMA) + BN-p moment partials.
// scan3 folded in: global pos = local atomic + aux[cell>>10].
__global__ __launch_bounds__(256) void k_scatfeat(
    const float* __restrict__ feats, const int* __restrict__ cellid,
    unsigned* __restrict__ base, const unsigned* __restrict__ aux,
    ushort* __restrict__ fsort,
    const ushort* __restrict__ wmb, const float* __restrict__ mbias,
    ushort* __restrict__ pb, float* __restrict__ partp) {
    __shared__ float t[64 * 65];
    __shared__ unsigned spos[64];
    __shared__ float sf[512];
    int b = blockIdx.x >> 9;
    int n0 = (blockIdx.x & 511) * 64;
    int tid = threadIdx.x;
    #pragma unroll
    for (int k = 0; k < 4; ++k) {
        int li = k * 256 + tid;                          // [0,1024)
        int c = li >> 4, n4 = (li & 15) * 4;
        float4 v = *reinterpret_cast<const float4*>(
            &feats[((size_t)(b * 64 + c)) * NPTS + n0 + n4]);
        t[c * 65 + n4 + 0] = v.x;
        t[c * 65 + n4 + 1] = v.y;
        t[c * 65 + n4 + 2] = v.z;
        t[c * 65 + n4 + 3] = v.w;
    }
    if (tid < 64) {
        int cell = cellid[(b << 15) + n0 + tid];
        spos[tid] = atomicAdd(&base[cell], 1u) + aux[cell >> 10];
    }
    __syncthreads();
    // scatter sorted bf16 rows
    #pragma unroll
    for (int it = 0; it < 2; ++it) {
        int pl = it * 32 + (tid >> 3);
        int j = tid & 7;
        unsigned pos = spos[pl];
        u16x8 v;
        #pragma unroll
        for (int k = 0; k < 8; ++k) v[k] = f2b(t[(j * 8 + k) * 65 + pl]);
        *reinterpret_cast<u16x8*>(fsort + (((size_t)pos) << 6) + j * 8) = v;
    }
    // MLP: wave w handles points w*16..w*16+15
    int w = tid >> 6, l = tid & 63;
    int nl = l & 15, kg = l >> 4;
    bf16x8 Af[2];
    #pragma unroll
    for (int ks = 0; ks < 2; ++ks) {
        union { u16x8 u; bf16x8 h; } cv;
        #pragma unroll
        for (int j = 0; j < 8; ++j)
            cv.u[j] = f2b(t[(ks * 32 + kg * 8 + j) * 65 + w * 16 + nl]);
        Af[ks] = cv.h;
    }
    f32x4 acc[4];
    #pragma unroll
    for (int cb = 0; cb < 4; ++cb) acc[cb] = (f32x4){0.f, 0.f, 0.f, 0.f};
    #pragma unroll
    for (int ks = 0; ks < 2; ++ks)
        #pragma unroll
        for (int cb = 0; cb < 4; ++cb) {
            bf16x8 Bf = *reinterpret_cast<const bf16x8*>(wmb + (cb * 16 + nl) * 64 + ks * 32 + kg * 8);
            acc[cb] = __builtin_amdgcn_mfma_f32_16x16x32_bf16(Af[ks], Bf, acc[cb], 0, 0, 0);
        }
    float ss[4] = {0.f, 0.f, 0.f, 0.f}, qq[4] = {0.f, 0.f, 0.f, 0.f};
    #pragma unroll
    for (int cb = 0; cb < 4; ++cb) {
        float bsv = mbias[cb * 16 + nl];
        #pragma unroll
        for (int r = 0; r < 4; ++r) {
            float yv = acc[cb][r] + bsv;
            int pt = w * 16 + kg * 4 + r;
            pb[(((size_t)((b << 15) + n0 + pt)) << 6) + cb * 16 + nl] = f2b(yv);
            ss[cb] += yv; qq[cb] += yv * yv;
        }
    }
    #pragma unroll
    for (int cb = 0; cb < 4; ++cb) {
        ss[cb] += __shfl_xor(ss[cb], 16); ss[cb] += __shfl_xor(ss[cb], 32);
        qq[cb] += __shfl_xor(qq[cb], 16); qq[cb] += __shfl_xor(qq[cb], 32);
    }
    if (l < 16) {
        #pragma unroll
        for (int cb = 0; cb < 4; ++cb) {
            sf[w * 128 + cb * 16 + nl] = ss[cb];
            sf[w * 128 + 64 + cb * 16 + nl] = qq[cb];
        }
    }
    __syncthreads();
    if (tid < 128)
        partp[(size_t)tid * 4096 + blockIdx.x] =
            sf[tid] + sf[128 + tid] + sf[256 + tid] + sf[384 + tid];
}

// one wave per cell: rows contiguous, global start = base - n + aux. unroll x8
__global__ __launch_bounds__(256) void k_gather(
    const ushort* __restrict__ fsort, const unsigned* __restrict__ base,
    const unsigned* __restrict__ aux, const unsigned* __restrict__ cnt,
    __hip_bfloat16* __restrict__ xb) {
    int cell = blockIdx.x * 4 + (threadIdx.x >> 6);
    int lane = threadIdx.x & 63;
    unsigned n = cnt[cell];
    unsigned start = base[cell] - n + aux[cell >> 10];
    const ushort* rows = fsort + (((size_t)start) << 6) + lane;
    float acc = 0.f;
    unsigned i = 0;
    for (; i + 8 <= n; i += 8) {
        float f0 = b2f(rows[((size_t)(i + 0)) << 6]);
        float f1 = b2f(rows[((size_t)(i + 1)) << 6]);
        float f2 = b2f(rows[((size_t)(i + 2)) << 6]);
        float f3 = b2f(rows[((size_t)(i + 3)) << 6]);
        float f4 = b2f(rows[((size_t)(i + 4)) << 6]);
        float f5 = b2f(rows[((size_t)(i + 5)) << 6]);
        float f6 = b2f(rows[((size_t)(i + 6)) << 6]);
        float f7 = b2f(rows[((size_t)(i + 7)) << 6]);
        acc += ((f0 + f1) + (f2 + f3)) + ((f4 + f5) + (f6 + f7));
    }
    for (; i < n; ++i) acc += b2f(rows[((size_t)i) << 6]);
    float inv = (n > 0) ? (1.0f / (float)n) : 0.f;
    xb[((size_t)cell << 6) + lane] = __float2bfloat16(acc * inv);
}

// implicit-GEMM conv, ci-split two-pass, both operands in LDS, 2 blocks/CU (4 w/SIMD).
// block: 8x8x8 tile x 64 co, 512 threads; wave = 1 d-slice (mi=4).
// Per ci-half: halo 1000 rows x 64B (62.5KB); weights 2-taphalf double-buffered 2x8KB.
// LDS 80384 B. Swizzle: 4-slot involution (slot ^= row&3), both sides.
template<int MODE>
__global__ __launch_bounds__(512, 4) void k_conv_mfma(
    const ushort* __restrict__ src, const ushort* __restrict__ wb,
    const float* __restrict__ bias, const float* __restrict__ scl,
    const float* __restrict__ sft, ushort* __restrict__ y,
    float* __restrict__ part, const ushort* __restrict__ zg) {
    __shared__ __align__(16) char sh[64000 + 16384];     // 80384 B
    char* wsh = sh + 64000;
    int tid = threadIdx.x;
    int lane = tid & 63, wid = tid >> 6;                 // wid in [0,8)
    int tile = ((blockIdx.x & 7) << 6) | (blockIdx.x >> 3);  // XCD-swizzled, 512 blocks
    int twi = tile & 3, thi = (tile >> 2) & 3;
    int tdi = (tile >> 4) & 3, b = tile >> 6;
    int d0 = tdi * 8, h0 = thi * 8, w0 = twi * 8;

    auto stage_wgt = [&](int half, int g) {              // tap-halves 2g,2g+1 (8KB)
        const ushort* wgrp = wb + (((half * 27 + g * 2)) << 11);
        char* wdst = wsh + (g & 1) * 8192;
        int c = (wid << 6) + lane;                       // [0,512)
        int row = c >> 2, off = c & 3;
        const ushort* gsrc = wgrp + (((row << 2) + (off ^ (row & 3))) << 3);
        __builtin_amdgcn_global_load_lds(
            (const __attribute__((address_space(1))) void*)gsrc,
            (__attribute__((address_space(3))) void*)(wdst + (wid << 10)), 16, 0, 0);
    };

    auto stage_halo = [&](int half) {
        float sc8[8], sf8[8];
        if (MODE == 1) {
            int c0 = half * 32 + (lane & 3) * 8;
            #pragma unroll
            for (int j = 0; j < 8; ++j) { sc8[j] = scl[c0 + j]; sf8[j] = sft[c0 + j]; }
        }
        #pragma unroll
        for (int it = 0; it < 8; ++it) {
            int idx = it * 8 + wid;
            int c = (idx << 6) + lane;                   // [0,4096), valid < 4000
            if (c < 4000) {
                int row = c >> 2, off = c & 3;
                int dz = row / 100, rem = row - dz * 100;
                int hz = rem / 10, wz = rem - hz * 10;
                int gd = d0 - 1 + dz, gh = h0 - 1 + hz, gw = w0 - 1 + wz;
                bool inb = ((unsigned)gd < 32u) && ((unsigned)gh < 32u) && ((unsigned)gw < 32u);
                size_t vbase = (((size_t)((b << 15) | (gd << 10) | (gh << 5) | gw)) << 6) + half * 32;
                if (MODE == 0) {
                    int soff = off ^ (row & 3);
                    const ushort* gsrc = inb ? src + vbase + soff * 8 : zg;
                    __builtin_amdgcn_global_load_lds(
                        (const __attribute__((address_space(1))) void*)gsrc,
                        (__attribute__((address_space(3))) void*)(sh + (idx << 10)), 16, 0, 0);
                } else {
                    u16x8 v = {0, 0, 0, 0, 0, 0, 0, 0};
                    if (inb) {
                        v = *reinterpret_cast<const u16x8*>(src + vbase + off * 8);
                        #pragma unroll
                        for (int j = 0; j < 8; ++j) {
                            float f = fmaf(b2f(v[j]), sc8[j], sf8[j]);
                            f = f > 0.f ? f : 0.1f * f;
                            v[j] = f2b(f);
                        }
                    }
                    *reinterpret_cast<u16x8*>(sh + (row << 6) + ((off ^ (row & 3)) << 4)) = v;
                }
            }
        }
    };

    int nl = lane & 15, kg = lane >> 4;                  // kg in [0,4): 8-ci group
    int rbase = wid * 100 + (nl >> 3) * 10 + (nl & 7);

    f32x4 acc[4][4];
    #pragma unroll
    for (int mi = 0; mi < 4; ++mi)
        #pragma unroll
        for (int cb = 0; cb < 4; ++cb) acc[mi][cb] = (f32x4){0.f, 0.f, 0.f, 0.f};

    auto compute = [&](int g) {
        const char* wlds = wsh + (g & 1) * 8192;
        #pragma unroll
        for (int tl = 0; tl < 2; ++tl) {
            int t = g * 2 + tl;
            if (t < 27) {
                int kd = t / 9, rm = t - kd * 9;
                int kh = rm / 3, kw = rm - kh * 3;
                int rt = rbase + kd * 100 + kh * 10 + kw;
                bf16x8 a[4];
                #pragma unroll
                for (int mi = 0; mi < 4; ++mi) {
                    int r = rt + mi * 20;
                    a[mi] = *reinterpret_cast<const bf16x8*>(
                        sh + (r << 6) + ((kg ^ (r & 3)) << 4));
                }
                bf16x8 bf[4];
                #pragma unroll
                for (int cb = 0; cb < 4; ++cb) {
                    int rowb = tl * 64 + cb * 16 + nl;
                    bf[cb] = *reinterpret_cast<const bf16x8*>(
                        wlds + (rowb << 6) + ((kg ^ (rowb & 3)) << 4));
                }
                __builtin_amdgcn_s_setprio(1);
                #pragma unroll
                for (int mi = 0; mi < 4; ++mi)
                    #pragma unroll
                    for (int cb = 0; cb < 4; ++cb)
                        acc[mi][cb] = __builtin_amdgcn_mfma_f32_16x16x32_bf16(
                            a[mi], bf[cb], acc[mi][cb], 0, 0, 0);
                __builtin_amdgcn_s_setprio(0);
            }
        }
    };

    stage_halo(0);
    stage_wgt(0, 0);
    __syncthreads();
    #pragma unroll 1
    for (int g = 0; g < 14; ++g) {
        if (g < 13) stage_wgt(0, g + 1);
        compute(g);
        __syncthreads();
    }
    stage_halo(1);
    stage_wgt(1, 0);
    __syncthreads();
    #pragma unroll 1
    for (int g = 0; g < 14; ++g) {
        if (g < 13) stage_wgt(1, g + 1);
        compute(g);
        __syncthreads();
    }

    int d = d0 + wid;
    float bs[4];
    #pragma unroll
    for (int cb = 0; cb < 4; ++cb) bs[cb] = bias[cb * 16 + nl];
    float ss[4] = {0.f, 0.f, 0.f, 0.f}, qq[4] = {0.f, 0.f, 0.f, 0.f};
    #pragma unroll
    for (int mi = 0; mi < 4; ++mi) {
        int h = h0 + mi * 2 + (kg >> 1);
        int w = w0 + (kg & 1) * 4;
        size_t vox = (size_t)((b << 15) | (d << 10) | (h << 5) | w);
        #pragma unroll
        for (int cb = 0; cb < 4; ++cb) {
            int co = cb * 16 + nl;
            #pragma unroll
            for (int r = 0; r < 4; ++r) {
                float yv = acc[mi][cb][r] + bs[cb];
                y[((vox + r) << 6) + co] = f2b(yv);
                ss[cb] += yv; qq[cb] += yv * yv;
            }
        }
    }
    #pragma unroll
    for (int cb = 0; cb < 4; ++cb) {
        ss[cb] += __shfl_xor(ss[cb], 16); ss[cb] += __shfl_xor(ss[cb], 32);
        qq[cb] += __shfl_xor(qq[cb], 16); qq[cb] += __shfl_xor(qq[cb], 32);
    }
    float* sf2 = (float*)sh;                             // halo dead; reuse
    __syncthreads();
    if (lane < 16) {
        #pragma unroll
        for (int cb = 0; cb < 4; ++cb) {
            sf2[wid * 128 + cb * 16 + nl] = ss[cb];
            sf2[wid * 128 + 64 + cb * 16 + nl] = qq[cb];
        }
    }
    __syncthreads();
    if (tid < 128) {
        float t = sf2[tid] + sf2[128 + tid] + sf2[256 + tid] + sf2[384 + tid]
                + sf2[512 + tid] + sf2[640 + tid] + sf2[768 + tid] + sf2[896 + tid];
        part[tid * 512 + blockIdx.x] = t;
    }
}

// reduce partials -> BN affine (scl, sft). 64 blocks, block = one channel.
__global__ void k_redbn(const float* __restrict__ part, const float* __restrict__ g,
                        const float* __restrict__ bb, float* __restrict__ scl,
                        float* __restrict__ sft, int cnt) {
    int c = blockIdx.x;
    float s = 0.f, q = 0.f;
    for (int i = threadIdx.x; i < cnt; i += 256) {
        s += part[(size_t)c * cnt + i];
        q += part[(size_t)(64 + c) * cnt + i];
    }
    __shared__ float rs[256], rq[256];
    rs[threadIdx.x] = s; rq[threadIdx.x] = q; __syncthreads();
    for (int w = 128; w > 0; w >>= 1) {
        if (threadIdx.x < w) { rs[threadIdx.x] += rs[threadIdx.x + w]; rq[threadIdx.x] += rq[threadIdx.x + w]; }
        __syncthreads();
    }
    if (threadIdx.x == 0) {
        float mu = rs[0] * (1.0f / MTOT);
        float var = rq[0] * (1.0f / MTOT) - mu * mu;
        float sc = g[c] * rsqrtf(var + EPSV);
        scl[c] = sc; sft[c] = bb[c] - mu * sc;
    }
}

// epilogue: blocks [0,4096) = fused BN(p)+trilinear+add -> outF;
//           blocks [4096,8192) = y2 NDHWC -> v NCDHW (BN2+leaky) -> outV.
// Disjoint d_out regions; pbuf lives in ws (no race with outV writes).
__global__ __launch_bounds__(256) void k_epilogue(
    float* __restrict__ outF, float* __restrict__ outV,
    const ushort* __restrict__ pbuf, const ushort* __restrict__ vraw,
    const float* __restrict__ norm,
    const float* __restrict__ scl, const float* __restrict__ sft,
    const float* __restrict__ sclp, const float* __restrict__ sftp) {
    __shared__ float smp[64 * 65];
    int tid = threadIdx.x;
    if (blockIdx.x < 4096) {
        int bid = blockIdx.x;
        int b = bid >> 9;
        int n0 = (bid & 511) * 64;
        int wid = tid >> 6, lane = tid & 63;
        const ushort* gb = vraw + (((size_t)b) << 15) * CC;
        const float* nrm0 = norm + ((size_t)(b * 3)) * NPTS;
        float sc = scl[lane], sf = sft[lane];
        float scp = sclp[lane], sfp = sftp[lane];

        #pragma unroll 2
        for (int i = 0; i < 16; ++i) {
            int pl = wid * 16 + i;
            int n = n0 + pl;
            float v0 = nrm0[n];
            float v1 = nrm0[NPTS + n];
            float v2 = nrm0[2 * NPTS + n];
            int lx = (int)floorf(v0), ly = (int)floorf(v1), lz = (int)floorf(v2);
            float fx = v0 - (float)lx, fy = v1 - (float)ly, fz = v2 - (float)lz;
            int hx = min(lx + 1, 31), hy = min(ly + 1, 31), hz = min(lz + 1, 31);
            float gx = 1.f - fx, gy = 1.f - fy, gz = 1.f - fz;

            int i000 = ((lx * 32 + ly) * 32 + lz) << 6;
            int i001 = ((lx * 32 + ly) * 32 + hz) << 6;
            int i010 = ((lx * 32 + hy) * 32 + lz) << 6;
            int i011 = ((lx * 32 + hy) * 32 + hz) << 6;
            int i100 = ((hx * 32 + ly) * 32 + lz) << 6;
            int i101 = ((hx * 32 + ly) * 32 + hz) << 6;
            int i110 = ((hx * 32 + hy) * 32 + lz) << 6;
            int i111 = ((hx * 32 + hy) * 32 + hz) << 6;

            float w000 = gx * gy * gz, w001 = gx * gy * fz;
            float w010 = gx * fy * gz, w011 = gx * fy * fz;
            float w100 = fx * gy * gz, w101 = fx * gy * fz;
            float w110 = fx * fy * gz, w111 = fx * fy * fz;

            float r0 = fmaf(b2f(gb[i000 + lane]), sc, sf); r0 = r0 > 0.f ? r0 : 0.1f * r0;
            float r1 = fmaf(b2f(gb[i001 + lane]), sc, sf); r1 = r1 > 0.f ? r1 : 0.1f * r1;
            float r2 = fmaf(b2f(gb[i010 + lane]), sc, sf); r2 = r2 > 0.f ? r2 : 0.1f * r2;
            float r3 = fmaf(b2f(gb[i011 + lane]), sc, sf); r3 = r3 > 0.f ? r3 : 0.1f * r3;
            float r4 = fmaf(b2f(gb[i100 + lane]), sc, sf); r4 = r4 > 0.f ? r4 : 0.1f * r4;
            float r5 = fmaf(b2f(gb[i101 + lane]), sc, sf); r5 = r5 > 0.f ? r5 : 0.1f * r5;
            float r6 = fmaf(b2f(gb[i110 + lane]), sc, sf); r6 = r6 > 0.f ? r6 : 0.1f * r6;
            float r7 = fmaf(b2f(gb[i111 + lane]), sc, sf); r7 = r7 > 0.f ? r7 : 0.1f * r7;

            float s = r0 * w000 + r1 * w001 + r2 * w010 + r3 * w011
                    + r4 * w100 + r5 * w101 + r6 * w110 + r7 * w111;

            float pv = fmaf(b2f(pbuf[(((size_t)((b << 15) + n)) << 6) + lane]), scp, sfp);
            pv = pv > 0.f ? pv : 0.1f * pv;
            smp[pl * 65 + lane] = s + pv;
        }
        __syncthreads();

        #pragma unroll 4
        for (int i = 0; i < 16; ++i) {
            int co = i * 4 + wid;
            outF[((size_t)(b * 64 + co)) * NPTS + n0 + lane] = smp[lane * 65 + co];
        }
    } else {
        int bid = blockIdx.x - 4096;
        size_t base = (size_t)bid * 4096;
        int gv0 = bid * 64;
        int b = gv0 >> 15;
        int vox0 = gv0 & 32767;
        #pragma unroll
        for (int k = 0; k < 2; ++k) {
            int li = k * 256 + tid;                      // [0,512)
            int vox = li >> 3, c0 = (li & 7) * 8;
            u16x8 v = *reinterpret_cast<const u16x8*>(vraw + base + vox * 64 + c0);
            #pragma unroll
            for (int j = 0; j < 8; ++j)
                smp[(c0 + j) * 65 + vox] = b2f(v[j]);
        }
        __syncthreads();
        #pragma unroll
        for (int k = 0; k < 4; ++k) {
            int li = k * 256 + tid;                      // [0,1024)
            int ch = li >> 4, v4 = (li & 15) * 4;
            float sc = scl[ch], sf = sft[ch];
            float4 o;
            float a0 = fmaf(smp[ch * 65 + v4 + 0], sc, sf); o.x = a0 > 0.f ? a0 : 0.1f * a0;
            float a1 = fmaf(smp[ch * 65 + v4 + 1], sc, sf); o.y = a1 > 0.f ? a1 : 0.1f * a1;
            float a2 = fmaf(smp[ch * 65 + v4 + 2], sc, sf); o.z = a2 > 0.f ? a2 : 0.1f * a2;
            float a3 = fmaf(smp[ch * 65 + v4 + 3], sc, sf); o.w = a3 > 0.f ? a3 : 0.1f * a3;
            *reinterpret_cast<float4*>(&outV[((size_t)(b * 64 + ch)) * RV + vox0 + v4]) = o;
        }
    }
}

extern "C" void kernel_launch(void* const* d_in, const int* in_sizes, int n_in,
                              void* d_out, int out_size, void* d_ws, size_t ws_size,
                              hipStream_t stream) {
    const float* features = (const float*)d_in[0];
    const float* coords   = (const float*)d_in[1];
    const float* conv1_w  = (const float*)d_in[2];
    const float* conv1_b  = (const float*)d_in[3];
    const float* bn1_g    = (const float*)d_in[4];
    const float* bn1_b    = (const float*)d_in[5];
    const float* conv2_w  = (const float*)d_in[6];
    const float* conv2_b  = (const float*)d_in[7];
    const float* bn2_g    = (const float*)d_in[8];
    const float* bn2_b    = (const float*)d_in[9];
    const float* mlp_w    = (const float*)d_in[10];
    const float* mlp_b    = (const float*)d_in[11];
    const float* bnp_g    = (const float*)d_in[12];
    const float* bnp_b    = (const float*)d_in[13];

    float* ws    = (float*)d_ws;
    ushort* fsort  = (ushort*)(ws + OFF_BUFA);           // dead after k_gather
    ushort* y2b    = (ushort*)(ws + OFF_BUFA);           // conv2 out (reuses fsort region)
    ushort* pbuf   = (ushort*)(ws + OFF_BUFA) + (size_t)16777216;  // pb bf16 [8.4M:16.7M) slots
    __hip_bfloat16* xb  = (__hip_bfloat16*)(ws + OFF_BUFB);
    __hip_bfloat16* wb1 = (__hip_bfloat16*)(ws + OFF_WB1);
    __hip_bfloat16* wb2 = (__hip_bfloat16*)(ws + OFF_WB2);
    ushort* zg   = (ushort*)(ws + OFF_ZG);
    unsigned* base    = (unsigned*)(ws + OFF_BASE);
    unsigned* aux     = (unsigned*)(ws + OFF_AUX);
    int* cellid       = (int*)(ws + OFF_CELL);
    unsigned* cnt     = (unsigned*)(ws + OFF_CNT);
    float* mean  = ws + OFF_MEAN;
    float* part1 = ws + OFF_PART1;
    float* part2 = ws + OFF_PART2;
    float* scl1  = ws + OFF_SCL1;
    float* sft1  = ws + OFF_SFT1;
    float* scl2  = ws + OFF_SCL2;
    float* sft2  = ws + OFF_SFT2;
    ushort* wmb  = (ushort*)(ws + OFF_WM);
    float* partp = ws + OFF_PARTP;
    float* sclp  = ws + OFF_SCLP;
    float* sftp  = ws + OFF_SFTP;
    float* nrm   = ws + OFF_NORM;

    float* outF  = (float*)d_out;                       // fused output
    float* outV  = (float*)d_out + (size_t)16777216;    // v output region
    ushort* y1b  = (ushort*)outV;                       // y1 bf16 scratch (overwritten by v)

    hipMemsetAsync(cnt, 0, 262144 * 4, stream);
    hipMemsetAsync(zg, 0, 256, stream);
    hipMemsetAsync(mean, 0, 24 * 4, stream);

    k_coord_mean<<<192, 256, 0, stream>>>(coords, mean);
    k_cellid<<<1024, 256, 0, stream>>>(coords, mean, nrm, cellid, cnt);
    k_scan1<<<256, 256, 0, stream>>>(cnt, base, aux);
    k_scan2<<<1, 256, 0, stream>>>(aux);

    k_prep<<<880, 256, 0, stream>>>(conv1_w, conv2_w, mlp_w, wb1, wb2, wmb);

    // fused: sort features + point-MLP (pb -> ws) + BN-p partials (scan3 folded in)
    k_scatfeat<<<4096, 256, 0, stream>>>(features, cellid, base, aux, fsort,
                                         wmb, mlp_b, pbuf, partp);
    k_redbn<<<64, 256, 0, stream>>>(partp, bnp_g, bnp_b, sclp, sftp, 4096);
    k_gather<<<65536, 256, 0, stream>>>(fsort, base, aux, cnt, xb);

    // conv1: xb -> y1b (raw y1 bf16) + partials (DMA halo)
    k_conv_mfma<0><<<512, 512, 0, stream>>>((const ushort*)xb, (const ushort*)wb1, conv1_b,
                                            nullptr, nullptr, y1b, part1, zg);
    k_redbn<<<64, 256, 0, stream>>>(part1, bn1_g, bn1_b, scl1, sft1, 512);

    // conv2: raw y1 + BN1 affine + leaky fused into staging -> y2b + partials
    k_conv_mfma<1><<<512, 512, 0, stream>>>(y1b, (const ushort*)wb2, conv2_b,
                                            scl1, sft1, y2b, part2, zg);
    k_redbn<<<64, 256, 0, stream>>>(part2, bn2_g, bn2_b, scl2, sft2, 512);

    // fused epilogue: outF (final) + outV (v transpose) in one dispatch
    k_epilogue<<<8192, 256, 0, stream>>>(outF, outV, pbuf, y2b, nrm,
                                         scl2, sft2, sclp, sftp);
}

// Round 20
// 333.875 us; speedup vs baseline: 1.1947x; 1.0146x over previous
//
#include <hip/hip_runtime.h>
#include <hip/hip_bf16.h>

#define BB 8
#define CC 64
#define NPTS 32768
#define RR 32
#define RV 32768            // 32^3
#define MTOT (BB*RV)        // 262144
#define EPSV 1e-4f

// ws float offsets
#define OFF_BUFA 0u               // fsort bf16 [0:8.4M) -> y2b bf16; pbuf bf16 [8.4M:16.7M)
#define OFF_BUFB 16777216u        // xb bf16 (x1 grid)
#define OFF_WB1  25165824u        // 55296 float-slots = 110592 bf16
#define OFF_WB2  25221120u        // 55296
#define OFF_BASE 25276480u        // 262144 uint
#define OFF_AUX  25800768u        // 256 uint
#define OFF_CELL 25801024u        // 262144 int
#define OFF_CNT  26063168u        // 262144 uint
#define OFF_MEAN 26325312u        // 24
#define OFF_ZG   26325336u        // 32 float-slots = 64 ushorts zero guard (contig w/ cnt+mean)
#define OFF_PART1 26325504u       // 128 x 1024 (using 128 x 512)
#define OFF_PART2 26456576u       // 128 x 1024 (using 128 x 512)
#define OFF_SCL1 26587648u        // 64
#define OFF_SFT1 26587712u        // 64
#define OFF_SCL2 26587776u        // 64
#define OFF_SFT2 26587840u        // 64
#define OFF_WM   26587904u        // 2048 float-slots = 4096 bf16
#define OFF_PARTP 26590208u       // 128 x 4096 floats -> ends 27114496
#define OFF_SCLP 27114496u        // 64
#define OFF_SFTP 27114560u        // 64
#define OFF_NORM 33554432u        // 786432 (survives to epilogue)

typedef __attribute__((ext_vector_type(8))) __bf16 bf16x8;
typedef __attribute__((ext_vector_type(8))) unsigned short u16x8;
typedef __attribute__((ext_vector_type(4))) float f32x4;

__device__ __forceinline__ float b2f(ushort u) {
    union { unsigned u; float f; } x; x.u = ((unsigned)u) << 16; return x.f;
}
__device__ __forceinline__ ushort f2b(float f) {
    __hip_bfloat16 h = __float2bfloat16(f);
    return *reinterpret_cast<ushort*>(&h);
}

// 192 blocks: (b*3+axis)*8 + chunk; partial sums via f32 atomics into mean[24]
__global__ void k_coord_mean(const float* __restrict__ coords, float* __restrict__ mean) {
    int ba = blockIdx.x >> 3, ch = blockIdx.x & 7;
    const float* src = coords + (size_t)ba * NPTS + ch * 4096;
    float s = 0.f;
    for (int i = threadIdx.x; i < 4096; i += 256) s += src[i];
    __shared__ float red[256];
    red[threadIdx.x] = s; __syncthreads();
    for (int w = 128; w > 0; w >>= 1) {
        if (threadIdx.x < w) red[threadIdx.x] += red[threadIdx.x + w];
        __syncthreads();
    }
    if (threadIdx.x == 0) atomicAdd(&mean[ba], red[0]);
}

// per point: norm, cell id, count (mean arrives as raw sums; scale by 1/NPTS here)
__global__ void k_cellid(const float* __restrict__ coords, const float* __restrict__ mean,
                         float* __restrict__ norm, int* __restrict__ cellid,
                         unsigned* __restrict__ cnt) {
    int idx = blockIdx.x * 256 + threadIdx.x;      // b*NPTS + n
    int b = idx >> 15, n = idx & (NPTS - 1);
    int flat = 0;
    #pragma unroll
    for (int a = 0; a < 3; ++a) {
        float c = coords[((size_t)(b * 3 + a)) * NPTS + n];
        float nm = (c - mean[b * 3 + a] * (1.0f / NPTS) + 1.0f) * (0.5f * RR);
        nm = fminf(fmaxf(nm, 0.0f), (float)(RR - 1));
        norm[((size_t)(b * 3 + a)) * NPTS + n] = nm;
        flat = flat * RR + (int)rintf(nm);
    }
    int cell = b * RV + flat;
    cellid[idx] = cell;
    atomicAdd(&cnt[cell], 1u);
}

// block-local exclusive scan: 256 blocks x 1024 cells
__global__ void k_scan1(const unsigned* __restrict__ cnt, unsigned* __restrict__ base,
                        unsigned* __restrict__ aux) {
    int tid = threadIdx.x;
    int c0 = blockIdx.x * 1024 + tid * 4;
    unsigned v0 = cnt[c0], v1 = cnt[c0 + 1], v2 = cnt[c0 + 2], v3 = cnt[c0 + 3];
    unsigned tot = v0 + v1 + v2 + v3;
    __shared__ unsigned sc[256];
    sc[tid] = tot; __syncthreads();
    for (int off = 1; off < 256; off <<= 1) {
        unsigned t = (tid >= off) ? sc[tid - off] : 0u;
        __syncthreads();
        sc[tid] += t;
        __syncthreads();
    }
    unsigned excl = sc[tid] - tot;
    base[c0] = excl;
    base[c0 + 1] = excl + v0;
    base[c0 + 2] = excl + v0 + v1;
    base[c0 + 3] = excl + v0 + v1 + v2;
    if (tid == 255) aux[blockIdx.x] = sc[255];
}

__global__ void k_scan2(unsigned* __restrict__ aux) {
    int tid = threadIdx.x;
    unsigned own = aux[tid];
    __shared__ unsigned sc[256];
    sc[tid] = own; __syncthreads();
    for (int off = 1; off < 256; off <<= 1) {
        unsigned t = (tid >= off) ? sc[tid - off] : 0u;
        __syncthreads();
        sc[tid] += t;
        __syncthreads();
    }
    aux[tid] = sc[tid] - own;
}

// merged weight prep: blocks [0,432) conv1, [432,864) conv2, [864,880) mlp
__global__ void k_prep(const float* __restrict__ w1, const float* __restrict__ w2,
                       const float* __restrict__ wm, __hip_bfloat16* __restrict__ wb1,
                       __hip_bfloat16* __restrict__ wb2, ushort* __restrict__ wmb) {
    int bid = blockIdx.x;
    if (bid < 864) {
        const float* w = (bid < 432) ? w1 : w2;
        __hip_bfloat16* wb = (bid < 432) ? wb1 : wb2;
        int i = (bid % 432) * 256 + threadIdx.x;         // CC*CC*27
        if (i >= CC * CC * 27) return;
        int tap = i % 27, t = i / 27;
        int ci = t & 63, co = t >> 6;
        int half = ci >> 5;
        wb[(((size_t)((half * 27 + tap) * 64 + co)) << 5) + (ci & 31)] = __float2bfloat16(w[i]);
    } else {
        int i = (bid - 864) * 256 + threadIdx.x;
        if (i < 4096) wmb[i] = f2b(wm[i]);
    }
}

// fused transpose + feature-sort + point-MLP (MFMA) + BN-p moment partials.
// scan3 folded in: global pos = local atomic + aux[cell>>10].
__global__ __launch_bounds__(256) void k_scatfeat(
    const float* __restrict__ feats, const int* __restrict__ cellid,
    unsigned* __restrict__ base, const unsigned* __restrict__ aux,
    ushort* __restrict__ fsort,
    const ushort* __restrict__ wmb, const float* __restrict__ mbias,
    ushort* __restrict__ pb, float* __restrict__ partp) {
    __shared__ float t[64 * 65];
    __shared__ unsigned spos[64];
    __shared__ float sf[512];
    int b = blockIdx.x >> 9;
    int n0 = (blockIdx.x & 511) * 64;
    int tid = threadIdx.x;
    #pragma unroll
    for (int k = 0; k < 4; ++k) {
        int li = k * 256 + tid;                          // [0,1024)
        int c = li >> 4, n4 = (li & 15) * 4;
        float4 v = *reinterpret_cast<const float4*>(
            &feats[((size_t)(b * 64 + c)) * NPTS + n0 + n4]);
        t[c * 65 + n4 + 0] = v.x;
        t[c * 65 + n4 + 1] = v.y;
        t[c * 65 + n4 + 2] = v.z;
        t[c * 65 + n4 + 3] = v.w;
    }
    if (tid < 64) {
        int cell = cellid[(b << 15) + n0 + tid];
        spos[tid] = atomicAdd(&base[cell], 1u) + aux[cell >> 10];
    }
    __syncthreads();
    // scatter sorted bf16 rows
    #pragma unroll
    for (int it = 0; it < 2; ++it) {
        int pl = it * 32 + (tid >> 3);
        int j = tid & 7;
        unsigned pos = spos[pl];
        u16x8 v;
        #pragma unroll
        for (int k = 0; k < 8; ++k) v[k] = f2b(t[(j * 8 + k) * 65 + pl]);
        *reinterpret_cast<u16x8*>(fsort + (((size_t)pos) << 6) + j * 8) = v;
    }
    // MLP: wave w handles points w*16..w*16+15
    int w = tid >> 6, l = tid & 63;
    int nl = l & 15, kg = l >> 4;
    bf16x8 Af[2];
    #pragma unroll
    for (int ks = 0; ks < 2; ++ks) {
        union { u16x8 u; bf16x8 h; } cv;
        #pragma unroll
        for (int j = 0; j < 8; ++j)
            cv.u[j] = f2b(t[(ks * 32 + kg * 8 + j) * 65 + w * 16 + nl]);
        Af[ks] = cv.h;
    }
    f32x4 acc[4];
    #pragma unroll
    for (int cb = 0; cb < 4; ++cb) acc[cb] = (f32x4){0.f, 0.f, 0.f, 0.f};
    #pragma unroll
    for (int ks = 0; ks < 2; ++ks)
        #pragma unroll
        for (int cb = 0; cb < 4; ++cb) {
            bf16x8 Bf = *reinterpret_cast<const bf16x8*>(wmb + (cb * 16 + nl) * 64 + ks * 32 + kg * 8);
            acc[cb] = __builtin_amdgcn_mfma_f32_16x16x32_bf16(Af[ks], Bf, acc[cb], 0, 0, 0);
        }
    float ss[4] = {0.f, 0.f, 0.f, 0.f}, qq[4] = {0.f, 0.f, 0.f, 0.f};
    #pragma unroll
    for (int cb = 0; cb < 4; ++cb) {
        float bsv = mbias[cb * 16 + nl];
        #pragma unroll
        for (int r = 0; r < 4; ++r) {
            float yv = acc[cb][r] + bsv;
            int pt = w * 16 + kg * 4 + r;
            pb[(((size_t)((b << 15) + n0 + pt)) << 6) + cb * 16 + nl] = f2b(yv);
            ss[cb] += yv; qq[cb] += yv * yv;
        }
    }
    #pragma unroll
    for (int cb = 0; cb < 4; ++cb) {
        ss[cb] += __shfl_xor(ss[cb], 16); ss[cb] += __shfl_xor(ss[cb], 32);
        qq[cb] += __shfl_xor(qq[cb], 16); qq[cb] += __shfl_xor(qq[cb], 32);
    }
    if (l < 16) {
        #pragma unroll
        for (int cb = 0; cb < 4; ++cb) {
            sf[w * 128 + cb * 16 + nl] = ss[cb];
            sf[w * 128 + 64 + cb * 16 + nl] = qq[cb];
        }
    }
    __syncthreads();
    if (tid < 128)
        partp[(size_t)tid * 4096 + blockIdx.x] =
            sf[tid] + sf[128 + tid] + sf[256 + tid] + sf[384 + tid];
}

// one wave per cell: rows contiguous, global start = base - n + aux. unroll x8
__global__ __launch_bounds__(256) void k_gather(
    const ushort* __restrict__ fsort, const unsigned* __restrict__ base,
    const unsigned* __restrict__ aux, const unsigned* __restrict__ cnt,
    __hip_bfloat16* __restrict__ xb) {
    int cell = blockIdx.x * 4 + (threadIdx.x >> 6);
    int lane = threadIdx.x & 63;
    unsigned n = cnt[cell];
    unsigned start = base[cell] - n + aux[cell >> 10];
    const ushort* rows = fsort + (((size_t)start) << 6) + lane;
    float acc = 0.f;
    unsigned i = 0;
    for (; i + 8 <= n; i += 8) {
        float f0 = b2f(rows[((size_t)(i + 0)) << 6]);
        float f1 = b2f(rows[((size_t)(i + 1)) << 6]);
        float f2 = b2f(rows[((size_t)(i + 2)) << 6]);
        float f3 = b2f(rows[((size_t)(i + 3)) << 6]);
        float f4 = b2f(rows[((size_t)(i + 4)) << 6]);
        float f5 = b2f(rows[((size_t)(i + 5)) << 6]);
        float f6 = b2f(rows[((size_t)(i + 6)) << 6]);
        float f7 = b2f(rows[((size_t)(i + 7)) << 6]);
        acc += ((f0 + f1) + (f2 + f3)) + ((f4 + f5) + (f6 + f7));
    }
    for (; i < n; ++i) acc += b2f(rows[((size_t)i) << 6]);
    float inv = (n > 0) ? (1.0f / (float)n) : 0.f;
    xb[((size_t)cell << 6) + lane] = __float2bfloat16(acc * inv);
}

// implicit-GEMM conv, ci-split two-pass, both operands in LDS, 2 blocks/CU (4 w/SIMD).
// block: 8x8x8 tile x 64 co, 512 threads; wave = 1 d-slice (mi=4).
// Per ci-half: halo 1000 rows x 64B (62.5KB); weights 2-taphalf double-buffered 2x8KB.
// LDS 80384 B. Swizzle: 4-slot involution (slot ^= row&3), both sides.
template<int MODE>
__global__ __launch_bounds__(512, 4) void k_conv_mfma(
    const ushort* __restrict__ src, const ushort* __restrict__ wb,
    const float* __restrict__ bias, const float* __restrict__ scl,
    const float* __restrict__ sft, ushort* __restrict__ y,
    float* __restrict__ part, const ushort* __restrict__ zg) {
    __shared__ __align__(16) char sh[64000 + 16384];     // 80384 B
    char* wsh = sh + 64000;
    int tid = threadIdx.x;
    int lane = tid & 63, wid = tid >> 6;                 // wid in [0,8)
    int tile = ((blockIdx.x & 7) << 6) | (blockIdx.x >> 3);  // XCD-swizzled, 512 blocks
    int twi = tile & 3, thi = (tile >> 2) & 3;
    int tdi = (tile >> 4) & 3, b = tile >> 6;
    int d0 = tdi * 8, h0 = thi * 8, w0 = twi * 8;

    auto stage_wgt = [&](int half, int g) {              // tap-halves 2g,2g+1 (8KB)
        const ushort* wgrp = wb + (((half * 27 + g * 2)) << 11);
        char* wdst = wsh + (g & 1) * 8192;
        int c = (wid << 6) + lane;                       // [0,512)
        int row = c >> 2, off = c & 3;
        const ushort* gsrc = wgrp + (((row << 2) + (off ^ (row & 3))) << 3);
        __builtin_amdgcn_global_load_lds(
            (const __attribute__((address_space(1))) void*)gsrc,
            (__attribute__((address_space(3))) void*)(wdst + (wid << 10)), 16, 0, 0);
    };

    auto stage_halo = [&](int half) {
        float sc8[8], sf8[8];
        if (MODE == 1) {
            int c0 = half * 32 + (lane & 3) * 8;
            #pragma unroll
            for (int j = 0; j < 8; ++j) { sc8[j] = scl[c0 + j]; sf8[j] = sft[c0 + j]; }
        }
        #pragma unroll
        for (int it = 0; it < 8; ++it) {
            int idx = it * 8 + wid;
            int c = (idx << 6) + lane;                   // [0,4096), valid < 4000
            if (c < 4000) {
                int row = c >> 2, off = c & 3;
                int dz = row / 100, rem = row - dz * 100;
                int hz = rem / 10, wz = rem - hz * 10;
                int gd = d0 - 1 + dz, gh = h0 - 1 + hz, gw = w0 - 1 + wz;
                bool inb = ((unsigned)gd < 32u) && ((unsigned)gh < 32u) && ((unsigned)gw < 32u);
                size_t vbase = (((size_t)((b << 15) | (gd << 10) | (gh << 5) | gw)) << 6) + half * 32;
                if (MODE == 0) {
                    int soff = off ^ (row & 3);
                    const ushort* gsrc = inb ? src + vbase + soff * 8 : zg;
                    __builtin_amdgcn_global_load_lds(
                        (const __attribute__((address_space(1))) void*)gsrc,
                        (__attribute__((address_space(3))) void*)(sh + (idx << 10)), 16, 0, 0);
                } else {
                    u16x8 v = {0, 0, 0, 0, 0, 0, 0, 0};
                    if (inb) {
                        v = *reinterpret_cast<const u16x8*>(src + vbase + off * 8);
                        #pragma unroll
                        for (int j = 0; j < 8; ++j) {
                            float f = fmaf(b2f(v[j]), sc8[j], sf8[j]);
                            f = f > 0.f ? f : 0.1f * f;
                            v[j] = f2b(f);
                        }
                    }
                    *reinterpret_cast<u16x8*>(sh + (row << 6) + ((off ^ (row & 3)) << 4)) = v;
                }
            }
        }
    };

    int nl = lane & 15, kg = lane >> 4;                  // kg in [0,4): 8-ci group
    int rbase = wid * 100 + (nl >> 3) * 10 + (nl & 7);

    f32x4 acc[4][4];
    #pragma unroll
    for (int mi = 0; mi < 4; ++mi)
        #pragma unroll
        for (int cb = 0; cb < 4; ++cb) acc[mi][cb] = (f32x4){0.f, 0.f, 0.f, 0.f};

    auto compute = [&](int g) {
        const char* wlds = wsh + (g & 1) * 8192;
        #pragma unroll
        for (int tl = 0; tl < 2; ++tl) {
            int t = g * 2 + tl;
            if (t < 27) {
                int kd = t / 9, rm = t - kd * 9;
                int kh = rm / 3, kw = rm - kh * 3;
                int rt = rbase + kd * 100 + kh * 10 + kw;
                bf16x8 a[4];
                #pragma unroll
                for (int mi = 0; mi < 4; ++mi) {
                    int r = rt + mi * 20;
                    a[mi] = *reinterpret_cast<const bf16x8*>(
                        sh + (r << 6) + ((kg ^ (r & 3)) << 4));
                }
                bf16x8 bf[4];
                #pragma unroll
                for (int cb = 0; cb < 4; ++cb) {
                    int rowb = tl * 64 + cb * 16 + nl;
                    bf[cb] = *reinterpret_cast<const bf16x8*>(
                        wlds + (rowb << 6) + ((kg ^ (rowb & 3)) << 4));
                }
                __builtin_amdgcn_s_setprio(1);
                #pragma unroll
                for (int mi = 0; mi < 4; ++mi)
                    #pragma unroll
                    for (int cb = 0; cb < 4; ++cb)
                        acc[mi][cb] = __builtin_amdgcn_mfma_f32_16x16x32_bf16(
                            a[mi], bf[cb], acc[mi][cb], 0, 0, 0);
                __builtin_amdgcn_s_setprio(0);
            }
        }
    };

    stage_halo(0);
    stage_wgt(0, 0);
    __syncthreads();
    #pragma unroll 1
    for (int g = 0; g < 14; ++g) {
        if (g < 13) stage_wgt(0, g + 1);
        compute(g);
        __syncthreads();
    }
    stage_halo(1);
    stage_wgt(1, 0);
    __syncthreads();
    #pragma unroll 1
    for (int g = 0; g < 14; ++g) {
        if (g < 13) stage_wgt(1, g + 1);
        compute(g);
        __syncthreads();
    }

    int d = d0 + wid;
    float bs[4];
    #pragma unroll
    for (int cb = 0; cb < 4; ++cb) bs[cb] = bias[cb * 16 + nl];
    float ss[4] = {0.f, 0.f, 0.f, 0.f}, qq[4] = {0.f, 0.f, 0.f, 0.f};
    #pragma unroll
    for (int mi = 0; mi < 4; ++mi) {
        int h = h0 + mi * 2 + (kg >> 1);
        int w = w0 + (kg & 1) * 4;
        size_t vox = (size_t)((b << 15) | (d << 10) | (h << 5) | w);
        #pragma unroll
        for (int cb = 0; cb < 4; ++cb) {
            int co = cb * 16 + nl;
            #pragma unroll
            for (int r = 0; r < 4; ++r) {
                float yv = acc[mi][cb][r] + bs[cb];
                y[((vox + r) << 6) + co] = f2b(yv);
                ss[cb] += yv; qq[cb] += yv * yv;
            }
        }
    }
    #pragma unroll
    for (int cb = 0; cb < 4; ++cb) {
        ss[cb] += __shfl_xor(ss[cb], 16); ss[cb] += __shfl_xor(ss[cb], 32);
        qq[cb] += __shfl_xor(qq[cb], 16); qq[cb] += __shfl_xor(qq[cb], 32);
    }
    float* sf2 = (float*)sh;                             // halo dead; reuse
    __syncthreads();
    if (lane < 16) {
        #pragma unroll
        for (int cb = 0; cb < 4; ++cb) {
            sf2[wid * 128 + cb * 16 + nl] = ss[cb];
            sf2[wid * 128 + 64 + cb * 16 + nl] = qq[cb];
        }
    }
    __syncthreads();
    if (tid < 128) {
        float t = sf2[tid] + sf2[128 + tid] + sf2[256 + tid] + sf2[384 + tid]
                + sf2[512 + tid] + sf2[640 + tid] + sf2[768 + tid] + sf2[896 + tid];
        part[tid * 512 + blockIdx.x] = t;
    }
}

// reduce partials -> BN affine (scl, sft). 64 blocks, block = one channel.
__global__ void k_redbn(const float* __restrict__ part, const float* __restrict__ g,
                        const float* __restrict__ bb, float* __restrict__ scl,
                        float* __restrict__ sft, int cnt) {
    int c = blockIdx.x;
    float s = 0.f, q = 0.f;
    for (int i = threadIdx.x; i < cnt; i += 256) {
        s += part[(size_t)c * cnt + i];
        q += part[(size_t)(64 + c) * cnt + i];
    }
    __shared__ float rs[256], rq[256];
    rs[threadIdx.x] = s; rq[threadIdx.x] = q; __syncthreads();
    for (int w = 128; w > 0; w >>= 1) {
        if (threadIdx.x < w) { rs[threadIdx.x] += rs[threadIdx.x + w]; rq[threadIdx.x] += rq[threadIdx.x + w]; }
        __syncthreads();
    }
    if (threadIdx.x == 0) {
        float mu = rs[0] * (1.0f / MTOT);
        float var = rq[0] * (1.0f / MTOT) - mu * mu;
        float sc = g[c] * rsqrtf(var + EPSV);
        scl[c] = sc; sft[c] = bb[c] - mu * sc;
    }
}

// epilogue: blocks [0,4096) = fused BN(p)+trilinear+add -> outF;
//           blocks [4096,8192) = y2 NDHWC -> v NCDHW (BN2+leaky) -> outV.
__global__ __launch_bounds__(256) void k_epilogue(
    float* __restrict__ outF, float* __restrict__ outV,
    const ushort* __restrict__ pbuf, const ushort* __restrict__ vraw,
    const float* __restrict__ norm,
    const float* __restrict__ scl, const float* __restrict__ sft,
    const float* __restrict__ sclp, const float* __restrict__ sftp) {
    __shared__ float smp[64 * 65];
    int tid = threadIdx.x;
    if (blockIdx.x < 4096) {
        int bid = blockIdx.x;
        int b = bid >> 9;
        int n0 = (bid & 511) * 64;
        int wid = tid >> 6, lane = tid & 63;
        const ushort* gb = vraw + (((size_t)b) << 15) * CC;
        const float* nrm0 = norm + ((size_t)(b * 3)) * NPTS;
        float sc = scl[lane], sf = sft[lane];
        float scp = sclp[lane], sfp = sftp[lane];

        #pragma unroll 2
        for (int i = 0; i < 16; ++i) {
            int pl = wid * 16 + i;
            int n = n0 + pl;
            float v0 = nrm0[n];
            float v1 = nrm0[NPTS + n];
            float v2 = nrm0[2 * NPTS + n];
            int lx = (int)floorf(v0), ly = (int)floorf(v1), lz = (int)floorf(v2);
            float fx = v0 - (float)lx, fy = v1 - (float)ly, fz = v2 - (float)lz;
            int hx = min(lx + 1, 31), hy = min(ly + 1, 31), hz = min(lz + 1, 31);
            float gx = 1.f - fx, gy = 1.f - fy, gz = 1.f - fz;

            int i000 = ((lx * 32 + ly) * 32 + lz) << 6;
            int i001 = ((lx * 32 + ly) * 32 + hz) << 6;
            int i010 = ((lx * 32 + hy) * 32 + lz) << 6;
            int i011 = ((lx * 32 + hy) * 32 + hz) << 6;
            int i100 = ((hx * 32 + ly) * 32 + lz) << 6;
            int i101 = ((hx * 32 + ly) * 32 + hz) << 6;
            int i110 = ((hx * 32 + hy) * 32 + lz) << 6;
            int i111 = ((hx * 32 + hy) * 32 + hz) << 6;

            float w000 = gx * gy * gz, w001 = gx * gy * fz;
            float w010 = gx * fy * gz, w011 = gx * fy * fz;
            float w100 = fx * gy * gz, w101 = fx * gy * fz;
            float w110 = fx * fy * gz, w111 = fx * fy * fz;

            float r0 = fmaf(b2f(gb[i000 + lane]), sc, sf); r0 = r0 > 0.f ? r0 : 0.1f * r0;
            float r1 = fmaf(b2f(gb[i001 + lane]), sc, sf); r1 = r1 > 0.f ? r1 : 0.1f * r1;
            float r2 = fmaf(b2f(gb[i010 + lane]), sc, sf); r2 = r2 > 0.f ? r2 : 0.1f * r2;
            float r3 = fmaf(b2f(gb[i011 + lane]), sc, sf); r3 = r3 > 0.f ? r3 : 0.1f * r3;
            float r4 = fmaf(b2f(gb[i100 + lane]), sc, sf); r4 = r4 > 0.f ? r4 : 0.1f * r4;
            float r5 = fmaf(b2f(gb[i101 + lane]), sc, sf); r5 = r5 > 0.f ? r5 : 0.1f * r5;
            float r6 = fmaf(b2f(gb[i110 + lane]), sc, sf); r6 = r6 > 0.f ? r6 : 0.1f * r6;
            float r7 = fmaf(b2f(gb[i111 + lane]), sc, sf); r7 = r7 > 0.f ? r7 : 0.1f * r7;

            float s = r0 * w000 + r1 * w001 + r2 * w010 + r3 * w011
                    + r4 * w100 + r5 * w101 + r6 * w110 + r7 * w111;

            float pv = fmaf(b2f(pbuf[(((size_t)((b << 15) + n)) << 6) + lane]), scp, sfp);
            pv = pv > 0.f ? pv : 0.1f * pv;
            smp[pl * 65 + lane] = s + pv;
        }
        __syncthreads();

        #pragma unroll 4
        for (int i = 0; i < 16; ++i) {
            int co = i * 4 + wid;
            outF[((size_t)(b * 64 + co)) * NPTS + n0 + lane] = smp[lane * 65 + co];
        }
    } else {
        int bid = blockIdx.x - 4096;
        size_t base = (size_t)bid * 4096;
        int gv0 = bid * 64;
        int b = gv0 >> 15;
        int vox0 = gv0 & 32767;
        #pragma unroll
        for (int k = 0; k < 2; ++k) {
            int li = k * 256 + tid;                      // [0,512)
            int vox = li >> 3, c0 = (li & 7) * 8;
            u16x8 v = *reinterpret_cast<const u16x8*>(vraw + base + vox * 64 + c0);
            #pragma unroll
            for (int j = 0; j < 8; ++j)
                smp[(c0 + j) * 65 + vox] = b2f(v[j]);
        }
        __syncthreads();
        #pragma unroll
        for (int k = 0; k < 4; ++k) {
            int li = k * 256 + tid;                      // [0,1024)
            int ch = li >> 4, v4 = (li & 15) * 4;
            float sc = scl[ch], sf = sft[ch];
            float4 o;
            float a0 = fmaf(smp[ch * 65 + v4 + 0], sc, sf); o.x = a0 > 0.f ? a0 : 0.1f * a0;
            float a1 = fmaf(smp[ch * 65 + v4 + 1], sc, sf); o.y = a1 > 0.f ? a1 : 0.1f * a1;
            float a2 = fmaf(smp[ch * 65 + v4 + 2], sc, sf); o.z = a2 > 0.f ? a2 : 0.1f * a2;
            float a3 = fmaf(smp[ch * 65 + v4 + 3], sc, sf); o.w = a3 > 0.f ? a3 : 0.1f * a3;
            *reinterpret_cast<float4*>(&outV[((size_t)(b * 64 + ch)) * RV + vox0 + v4]) = o;
        }
    }
}

extern "C" void kernel_launch(void* const* d_in, const int* in_sizes, int n_in,
                              void* d_out, int out_size, void* d_ws, size_t ws_size,
                              hipStream_t stream) {
    const float* features = (const float*)d_in[0];
    const float* coords   = (const float*)d_in[1];
    const float* conv1_w  = (const float*)d_in[2];
    const float* conv1_b  = (const float*)d_in[3];
    const float* bn1_g    = (const float*)d_in[4];
    const float* bn1_b    = (const float*)d_in[5];
    const float* conv2_w  = (const float*)d_in[6];
    const float* conv2_b  = (const float*)d_in[7];
    const float* bn2_g    = (const float*)d_in[8];
    const float* bn2_b    = (const float*)d_in[9];
    const float* mlp_w    = (const float*)d_in[10];
    const float* mlp_b    = (const float*)d_in[11];
    const float* bnp_g    = (const float*)d_in[12];
    const float* bnp_b    = (const float*)d_in[13];

    float* ws    = (float*)d_ws;
    ushort* fsort  = (ushort*)(ws + OFF_BUFA);           // dead after k_gather
    ushort* y2b    = (ushort*)(ws + OFF_BUFA);           // conv2 out (reuses fsort region)
    ushort* pbuf   = (ushort*)(ws + OFF_BUFA) + (size_t)16777216;  // pb bf16 [8.4M:16.7M) slots
    __hip_bfloat16* xb  = (__hip_bfloat16*)(ws + OFF_BUFB);
    __hip_bfloat16* wb1 = (__hip_bfloat16*)(ws + OFF_WB1);
    __hip_bfloat16* wb2 = (__hip_bfloat16*)(ws + OFF_WB2);
    unsigned* base    = (unsigned*)(ws + OFF_BASE);
    unsigned* aux     = (unsigned*)(ws + OFF_AUX);
    int* cellid       = (int*)(ws + OFF_CELL);
    unsigned* cnt     = (unsigned*)(ws + OFF_CNT);
    float* mean  = ws + OFF_MEAN;
    ushort* zg   = (ushort*)(ws + OFF_ZG);
    float* part1 = ws + OFF_PART1;
    float* part2 = ws + OFF_PART2;
    float* scl1  = ws + OFF_SCL1;
    float* sft1  = ws + OFF_SFT1;
    float* scl2  = ws + OFF_SCL2;
    float* sft2  = ws + OFF_SFT2;
    ushort* wmb  = (ushort*)(ws + OFF_WM);
    float* partp = ws + OFF_PARTP;
    float* sclp  = ws + OFF_SCLP;
    float* sftp  = ws + OFF_SFTP;
    float* nrm   = ws + OFF_NORM;

    float* outF  = (float*)d_out;                       // fused output
    float* outV  = (float*)d_out + (size_t)16777216;    // v output region
    ushort* y1b  = (ushort*)outV;                       // y1 bf16 scratch (overwritten by v)

    // single contiguous memset: cnt (262144) + mean (24) + zg (32) float-slots
    hipMemsetAsync(cnt, 0, (size_t)(262144 + 24 + 32) * 4, stream);

    k_coord_mean<<<192, 256, 0, stream>>>(coords, mean);
    k_cellid<<<1024, 256, 0, stream>>>(coords, mean, nrm, cellid, cnt);
    k_scan1<<<256, 256, 0, stream>>>(cnt, base, aux);
    k_scan2<<<1, 256, 0, stream>>>(aux);

    k_prep<<<880, 256, 0, stream>>>(conv1_w, conv2_w, mlp_w, wb1, wb2, wmb);

    // fused: sort features + point-MLP (pb -> ws) + BN-p partials (scan3 folded in)
    k_scatfeat<<<4096, 256, 0, stream>>>(features, cellid, base, aux, fsort,
                                         wmb, mlp_b, pbuf, partp);
    k_redbn<<<64, 256, 0, stream>>>(partp, bnp_g, bnp_b, sclp, sftp, 4096);
    k_gather<<<65536, 256, 0, stream>>>(fsort, base, aux, cnt, xb);

    // conv1: xb -> y1b (raw y1 bf16) + partials (DMA halo)
    k_conv_mfma<0><<<512, 512, 0, stream>>>((const ushort*)xb, (const ushort*)wb1, conv1_b,
                                            nullptr, nullptr, y1b, part1, zg);
    k_redbn<<<64, 256, 0, stream>>>(part1, bn1_g, bn1_b, scl1, sft1, 512);

    // conv2: raw y1 + BN1 affine + leaky fused into staging -> y2b + partials
    k_conv_mfma<1><<<512, 512, 0, stream>>>(y1b, (const ushort*)wb2, conv2_b,
                                            scl1, sft1, y2b, part2, zg);
    k_redbn<<<64, 256, 0, stream>>>(part2, bn2_g, bn2_b, scl2, sft2, 512);

    // fused epilogue: outF (final) + outV (v transpose) in one dispatch
    k_epilogue<<<8192, 256, 0, stream>>>(outF, outV, pbuf, y2b, nrm,
                                         scl2, sft2, sclp, sftp);
}